// Round 1
// baseline (2440.947 us; speedup 1.0000x reference)
//
#include <hip/hip_runtime.h>
#include <math.h>

// Problem constants
#define B_    1024
#define IMG_  512
#define TXT_  300
#define NN_   14
#define FF_   2048
#define HID_  128
#define CC_   14
#define EE_   182
#define DD_   812
#define D3_   2436      // 3*D
#define BNR_  (B_*NN_)  // 14336

// ---------------------------------------------------------------------------
// Workspace layout (bytes). Region0 (offset 0) is time-multiplexed:
//   phase1: A(9.98M) | E(4.19M) | Avo(3.33M) | P''(46.56M)   (end 64.06M)
//   phase2: H = ffn hidden (117.44M)                          (A..P'' dead)
//   phase3: H1|G1|H2|Pool  (GCN buffers, H dead)
// X1 lives at 117.44M (disjoint from region0). Smalls at 164.00M.
// Total ws needed ~= 164.31 MB.
// ---------------------------------------------------------------------------
#define OFF_A    0
#define OFF_E    9977856
#define OFF_AVO  14172160
#define OFF_P    17498112
#define OFF_H    0
#define OFF_X1   117440512
#define OFF_SM   164003840
#define OFF_T    (OFF_SM + 0)        // 14*2436 f
#define OFF_EW   (OFF_SM + 137216)   // 14*1024 f
#define OFF_CO   (OFF_SM + 194560)   // 14*812  f
#define OFF_Z    (OFF_SM + 240128)   // 14336   f
#define OFF_ADJ  (OFF_SM + 297472)   // 196     f
#define OFF_H1   0
#define OFF_G1   7340032
#define OFF_H2   14680064
#define OFF_POOL 22020096

// ---------------------------------------------------------------------------
// Generic fp32 tiled GEMM: C[M,N] = scale * A[M,K] (row-major) x B  (+ epilogue)
// BLAYOUT 0: B is (K x N) row-major ("N").  BLAYOUT 1: B is (N x K) row-major ("T").
// EPI 0: C = v.  EPI 1: C = relu(v + bias[n]).  EPI 2: C = v + bias[n] + C (in-place resid).
// BROWSCALE: scale B row k by rs[z*rs_stride + k]; C column offset z*z_colstride
//   (batched attention: P''[l, z*812+d] = sum_m E[l,m] * ew[z,m] * Avo[m,d]).
// 64x64 tile, BK=16, 256 threads, 4x4 per thread. K and N must be %4 (all uses are).
// ---------------------------------------------------------------------------
template<int BLAYOUT, int EPI, int BROWSCALE>
__global__ __launch_bounds__(256)
void gemm_k(const float* __restrict__ A, int lda,
            const float* __restrict__ Bm, int ldb,
            float* __restrict__ C, int ldc,
            int M, int N, int K, float scale,
            const float* __restrict__ bias,
            const float* __restrict__ rs, int rs_stride, int z_colstride)
{
    __shared__ __align__(16) float As[16][68];
    __shared__ __align__(16) float Bs[16][68];
    const int tid  = threadIdx.x;
    const int tx   = tid & 15, ty = tid >> 4;
    const int row0 = blockIdx.y * 64;
    const int col0 = blockIdx.x * 64;
    const int zco  = blockIdx.z * z_colstride;
    const float* rsz = BROWSCALE ? (rs + (size_t)blockIdx.z * rs_stride) : nullptr;

    float acc[4][4];
    #pragma unroll
    for (int i = 0; i < 4; ++i)
        #pragma unroll
        for (int j = 0; j < 4; ++j) acc[i][j] = 0.f;

    const int ar = tid >> 2;          // 0..63  (A tile row)
    const int ac = (tid & 3) << 2;    // 0,4,8,12 (A tile k)

    for (int k0 = 0; k0 < K; k0 += 16) {
        // --- stage A tile (transposed into LDS: As[k][m]) ---
        float4 av = make_float4(0.f, 0.f, 0.f, 0.f);
        {
            int am = row0 + ar, ak = k0 + ac;
            if (am < M && ak < K)
                av = *(const float4*)(A + (size_t)am * lda + ak);
        }
        As[ac + 0][ar] = av.x; As[ac + 1][ar] = av.y;
        As[ac + 2][ar] = av.z; As[ac + 3][ar] = av.w;

        // --- stage B tile (Bs[k][n]) ---
        if (BLAYOUT == 0) {
            int bk = k0 + (tid >> 4);
            int bn = col0 + ((tid & 15) << 2);
            float4 bv = make_float4(0.f, 0.f, 0.f, 0.f);
            if (bk < K && bn < N)
                bv = *(const float4*)(Bm + (size_t)bk * ldb + bn);
            if (BROWSCALE) {
                float s = (bk < K) ? rsz[bk] : 0.f;
                bv.x *= s; bv.y *= s; bv.z *= s; bv.w *= s;
            }
            *(float4*)&Bs[tid >> 4][(tid & 15) << 2] = bv;
        } else {
            int bn = col0 + (tid >> 2);
            int bk = k0 + ((tid & 3) << 2);
            float4 bv = make_float4(0.f, 0.f, 0.f, 0.f);
            if (bn < N && bk < K)
                bv = *(const float4*)(Bm + (size_t)bn * ldb + bk);
            int c = (tid & 3) << 2;
            Bs[c + 0][tid >> 2] = bv.x; Bs[c + 1][tid >> 2] = bv.y;
            Bs[c + 2][tid >> 2] = bv.z; Bs[c + 3][tid >> 2] = bv.w;
        }
        __syncthreads();

        #pragma unroll
        for (int kk = 0; kk < 16; ++kk) {
            float4 a4 = *(const float4*)&As[kk][ty << 2];
            float4 b4 = *(const float4*)&Bs[kk][tx << 2];
            float rA[4] = {a4.x, a4.y, a4.z, a4.w};
            float rB[4] = {b4.x, b4.y, b4.z, b4.w};
            #pragma unroll
            for (int i = 0; i < 4; ++i)
                #pragma unroll
                for (int j = 0; j < 4; ++j)
                    acc[i][j] = fmaf(rA[i], rB[j], acc[i][j]);
        }
        __syncthreads();
    }

    #pragma unroll
    for (int i = 0; i < 4; ++i) {
        int rm = row0 + (ty << 2) + i;
        if (rm >= M) continue;
        #pragma unroll
        for (int j = 0; j < 4; ++j) {
            int cn = col0 + (tx << 2) + j;
            if (cn >= N) continue;
            size_t idx = (size_t)rm * ldc + zco + cn;
            float v = acc[i][j] * scale;
            if (EPI == 1) { v += bias[cn]; v = v > 0.f ? v : 0.f; }
            if (EPI == 2) { v += bias[cn] + C[idx]; }
            C[idx] = v;
        }
    }
}

// T[n,r] = in_proj_b[r] + word[n,:] . in_proj_w[r, 512:812]   (n-only part of qkv)
__global__ void kern_T(const float* __restrict__ word, const float* __restrict__ W,
                       const float* __restrict__ bias, float* __restrict__ T)
{
    int idx = blockIdx.x * 256 + threadIdx.x;
    if (idx >= NN_ * D3_) return;
    int n = idx / D3_, r = idx % D3_;
    const float* wr = word + n * TXT_;
    const float* Wr = W + (size_t)r * DD_ + IMG_;
    float s = bias[r];
    for (int c = 0; c < TXT_; ++c) s = fmaf(wr[c], Wr[c], s);
    T[idx] = s;
}

// Dense 14x14 GCN adjacency (self-loops + symmetric norm), serial on 1 thread.
__global__ void kern_adj(const int* __restrict__ ei, float* __restrict__ Adj)
{
    if (threadIdx.x != 0 || blockIdx.x != 0) return;
    float deg[NN_];
    for (int i = 0; i < NN_; ++i) deg[i] = 1.f;                 // self-loop
    for (int e = 0; e < EE_; ++e) deg[ei[EE_ + e]] += 1.f;      // in-degree (dst)
    float dinv[NN_];
    for (int i = 0; i < NN_; ++i) dinv[i] = rsqrtf(deg[i]);
    float adj[NN_ * NN_];
    for (int t = 0; t < NN_ * NN_; ++t) adj[t] = 0.f;
    for (int e = 0; e < EE_; ++e) {
        int s = ei[e], d = ei[EE_ + e];
        adj[d * NN_ + s] += dinv[s] * dinv[d];
    }
    for (int i = 0; i < NN_; ++i) adj[i * NN_ + i] += dinv[i] * dinv[i];
    for (int t = 0; t < NN_ * NN_; ++t) Adj[t] = adj[t];
}

// E[b,:] = exp(S0[b,:] - rowmax)  in-place, one block per row.
__global__ __launch_bounds__(256) void kern_exp_rows(float* __restrict__ S)
{
    __shared__ float red[256];
    float* row = S + (size_t)blockIdx.x * 1024;
    float m = -1e30f;
    for (int i = threadIdx.x; i < 1024; i += 256) m = fmaxf(m, row[i]);
    red[threadIdx.x] = m; __syncthreads();
    for (int s = 128; s > 0; s >>= 1) {
        if (threadIdx.x < s) red[threadIdx.x] = fmaxf(red[threadIdx.x], red[threadIdx.x + s]);
        __syncthreads();
    }
    m = red[0];
    for (int i = threadIdx.x; i < 1024; i += 256) row[i] = expf(row[i] - m);
}

// w[n,m] = scale * Tq[n,:] . Ak[m,:]; ew[n,m] = exp(w - max_m w). One block per n.
__global__ __launch_bounds__(256) void kern_w_ew(const float* __restrict__ T,
    const float* __restrict__ Abuf, float* __restrict__ EW, float scale)
{
    __shared__ float wrow[1024];
    __shared__ float red[256];
    int n = blockIdx.x;
    const float* Tq = T + n * D3_;
    for (int m = threadIdx.x; m < 1024; m += 256) {
        const float* Ak = Abuf + (size_t)m * D3_ + DD_;
        float s = 0.f;
        for (int c = 0; c < DD_; ++c) s = fmaf(Tq[c], Ak[c], s);
        wrow[m] = s * scale;
    }
    __syncthreads();
    float mx = -1e30f;
    for (int m = threadIdx.x; m < 1024; m += 256) mx = fmaxf(mx, wrow[m]);
    red[threadIdx.x] = mx; __syncthreads();
    for (int s = 128; s > 0; s >>= 1) {
        if (threadIdx.x < s) red[threadIdx.x] = fmaxf(red[threadIdx.x], red[threadIdx.x + s]);
        __syncthreads();
    }
    mx = red[0];
    for (int m = threadIdx.x; m < 1024; m += 256)
        EW[n * 1024 + m] = expf(wrow[m] - mx);
}

// co[n,d] = out_proj_b[d] + Tv[n,:] . Wo[d,:]   (n-only part of projected attn out)
__global__ void kern_co(const float* __restrict__ T, const float* __restrict__ Wo,
                        const float* __restrict__ bo, float* __restrict__ co)
{
    int idx = blockIdx.x * 256 + threadIdx.x;
    if (idx >= NN_ * DD_) return;
    int n = idx / DD_, d = idx % DD_;
    const float* Tv = T + n * D3_ + 2 * DD_;
    const float* wr = Wo + (size_t)d * DD_;
    float s = bo[d];
    for (int c = 0; c < DD_; ++c) s = fmaf(Tv[c], wr[c], s);
    co[idx] = s;
}

// Z[b,n] = sum_m E[b,m] * ew[n,m]   (softmax denominator)
__global__ void kern_Z(const float* __restrict__ E, const float* __restrict__ EW,
                       float* __restrict__ Z)
{
    int idx = blockIdx.x * 256 + threadIdx.x;
    if (idx >= BNR_) return;
    int b = idx / NN_, n = idx % NN_;
    const float* er = E + (size_t)b * 1024;
    const float* wr = EW + n * 1024;
    float s = 0.f;
    for (int m = 0; m < 1024; ++m) s = fmaf(er[m], wr[m], s);
    Z[idx] = s;
}

// x1[row,:] = LN( node[b,n,:] + P''[b, n*812+:]/Z[b,n] + co[n,:] ; ln1 ). row=b*14+n.
__global__ __launch_bounds__(256) void kern_ln1(
    const float* __restrict__ img, const float* __restrict__ word,
    const float* __restrict__ P, const float* __restrict__ Z,
    const float* __restrict__ co, const float* __restrict__ g,
    const float* __restrict__ bta, float* __restrict__ X)
{
    __shared__ float buf[DD_];
    __shared__ float red[256];
    __shared__ float stats[2];
    int row = blockIdx.x;
    int b = row / NN_, n = row % NN_;
    float invZ = 1.f / Z[row];
    const float* pr = P + (size_t)b * (NN_ * DD_) + n * DD_;
    const float* cr = co + n * DD_;
    float s = 0.f;
    for (int d = threadIdx.x; d < DD_; d += 256) {
        float v = (d < IMG_) ? img[(size_t)b * IMG_ + d] : word[n * TXT_ + d - IMG_];
        v += pr[d] * invZ + cr[d];
        buf[d] = v;
        s += v;
    }
    red[threadIdx.x] = s; __syncthreads();
    for (int t = 128; t > 0; t >>= 1) {
        if (threadIdx.x < t) red[threadIdx.x] += red[threadIdx.x + t];
        __syncthreads();
    }
    if (threadIdx.x == 0) stats[0] = red[0] / DD_;
    __syncthreads();
    float mu = stats[0], s2 = 0.f;
    for (int d = threadIdx.x; d < DD_; d += 256) { float t = buf[d] - mu; s2 += t * t; }
    red[threadIdx.x] = s2; __syncthreads();
    for (int t = 128; t > 0; t >>= 1) {
        if (threadIdx.x < t) red[threadIdx.x] += red[threadIdx.x + t];
        __syncthreads();
    }
    if (threadIdx.x == 0) stats[1] = rsqrtf(red[0] / DD_ + 1e-5f);
    __syncthreads();
    float rstd = stats[1];
    float* xr = X + (size_t)row * DD_;
    for (int d = threadIdx.x; d < DD_; d += 256)
        xr[d] = (buf[d] - mu) * rstd * g[d] + bta[d];
}

// In-place LayerNorm over last dim (ln2).
__global__ __launch_bounds__(256) void kern_ln2(float* __restrict__ X,
    const float* __restrict__ g, const float* __restrict__ bta)
{
    __shared__ float buf[DD_];
    __shared__ float red[256];
    __shared__ float stats[2];
    float* xr = X + (size_t)blockIdx.x * DD_;
    float s = 0.f;
    for (int d = threadIdx.x; d < DD_; d += 256) { float v = xr[d]; buf[d] = v; s += v; }
    red[threadIdx.x] = s; __syncthreads();
    for (int t = 128; t > 0; t >>= 1) {
        if (threadIdx.x < t) red[threadIdx.x] += red[threadIdx.x + t];
        __syncthreads();
    }
    if (threadIdx.x == 0) stats[0] = red[0] / DD_;
    __syncthreads();
    float mu = stats[0], s2 = 0.f;
    for (int d = threadIdx.x; d < DD_; d += 256) { float t = buf[d] - mu; s2 += t * t; }
    red[threadIdx.x] = s2; __syncthreads();
    for (int t = 128; t > 0; t >>= 1) {
        if (threadIdx.x < t) red[threadIdx.x] += red[threadIdx.x + t];
        __syncthreads();
    }
    if (threadIdx.x == 0) stats[1] = rsqrtf(red[0] / DD_ + 1e-5f);
    __syncthreads();
    float rstd = stats[1];
    for (int d = threadIdx.x; d < DD_; d += 256)
        xr[d] = (buf[d] - mu) * rstd * g[d] + bta[d];
}

// g1[b,j,f] = relu( sum_i Adj[j,i]*h1[b,i,f] + bias[f] )
__global__ __launch_bounds__(256) void kern_agg1(const float* __restrict__ H,
    const float* __restrict__ Adj, const float* __restrict__ bias, float* __restrict__ G)
{
    __shared__ float sA[NN_ * NN_];
    if (threadIdx.x < NN_ * NN_) sA[threadIdx.x] = Adj[threadIdx.x];
    __syncthreads();
    int t = blockIdx.x * 256 + threadIdx.x;   // grid sized exactly B_*HID_
    int b = t >> 7, f = t & 127;
    float v[NN_];
    #pragma unroll
    for (int i = 0; i < NN_; ++i) v[i] = H[((size_t)b * NN_ + i) * HID_ + f];
    float bb = bias[f];
    #pragma unroll
    for (int j = 0; j < NN_; ++j) {
        float s = bb;
        #pragma unroll
        for (int i = 0; i < NN_; ++i) s = fmaf(sA[j * NN_ + i], v[i], s);
        G[((size_t)b * NN_ + j) * HID_ + f] = s > 0.f ? s : 0.f;
    }
}

// pool[b,f] = relu( mean_j( sum_i Adj[j,i]*h2[b,i,f] + bias[f] ) )
__global__ __launch_bounds__(256) void kern_agg2_pool(const float* __restrict__ H,
    const float* __restrict__ Adj, const float* __restrict__ bias, float* __restrict__ P)
{
    __shared__ float sA[NN_ * NN_];
    if (threadIdx.x < NN_ * NN_) sA[threadIdx.x] = Adj[threadIdx.x];
    __syncthreads();
    int t = blockIdx.x * 256 + threadIdx.x;
    int b = t >> 7, f = t & 127;
    float v[NN_];
    #pragma unroll
    for (int i = 0; i < NN_; ++i) v[i] = H[((size_t)b * NN_ + i) * HID_ + f];
    float acc = 0.f;
    #pragma unroll
    for (int j = 0; j < NN_; ++j) {
        float s = 0.f;
        #pragma unroll
        for (int i = 0; i < NN_; ++i) s = fmaf(sA[j * NN_ + i], v[i], s);
        acc += s;
    }
    acc = acc / (float)NN_ + bias[f];
    P[(size_t)b * HID_ + f] = acc > 0.f ? acc : 0.f;
}

// out[b,c] = lin_b[c] + pool[b,:] . lin_w[:,c]
__global__ void kern_lin(const float* __restrict__ pool, const float* __restrict__ W,
                         const float* __restrict__ bias, float* __restrict__ out)
{
    int t = blockIdx.x * 256 + threadIdx.x;
    if (t >= B_ * CC_) return;
    int b = t / CC_, c = t % CC_;
    float s = bias[c];
    const float* pr = pool + (size_t)b * HID_;
    for (int f = 0; f < HID_; ++f) s = fmaf(pr[f], W[f * CC_ + c], s);
    out[t] = s;
}

extern "C" void kernel_launch(void* const* d_in, const int* in_sizes, int n_in,
                              void* d_out, int out_size, void* d_ws, size_t ws_size,
                              hipStream_t stream)
{
    const float* img  = (const float*)d_in[0];
    const float* word = (const float*)d_in[1];
    const int*   ei   = (const int*)d_in[2];
    const float* Wi   = (const float*)d_in[3];
    const float* bi   = (const float*)d_in[4];
    const float* Wo   = (const float*)d_in[5];
    const float* bo   = (const float*)d_in[6];
    const float* g1   = (const float*)d_in[7];
    const float* bt1  = (const float*)d_in[8];
    const float* g2   = (const float*)d_in[9];
    const float* bt2  = (const float*)d_in[10];
    const float* W1   = (const float*)d_in[11];
    const float* bf1  = (const float*)d_in[12];
    const float* W2   = (const float*)d_in[13];
    const float* bf2  = (const float*)d_in[14];
    const float* Wg1  = (const float*)d_in[15];
    const float* bg1  = (const float*)d_in[16];
    const float* Wg2  = (const float*)d_in[17];
    const float* bg2  = (const float*)d_in[18];
    const float* Wl   = (const float*)d_in[19];
    const float* bl   = (const float*)d_in[20];
    float* out = (float*)d_out;

    char* ws = (char*)d_ws;
    float* Abuf = (float*)(ws + OFF_A);
    float* Ebuf = (float*)(ws + OFF_E);
    float* Avo  = (float*)(ws + OFF_AVO);
    float* Pbuf = (float*)(ws + OFF_P);
    float* Hbuf = (float*)(ws + OFF_H);
    float* X1   = (float*)(ws + OFF_X1);
    float* Tbuf = (float*)(ws + OFF_T);
    float* EW   = (float*)(ws + OFF_EW);
    float* CO   = (float*)(ws + OFF_CO);
    float* Zb   = (float*)(ws + OFF_Z);
    float* Adj  = (float*)(ws + OFF_ADJ);
    float* H1   = (float*)(ws + OFF_H1);
    float* G1b  = (float*)(ws + OFF_G1);
    float* H2   = (float*)(ws + OFF_H2);
    float* Pool = (float*)(ws + OFF_POOL);

    const float scale = 1.0f / sqrtf((float)DD_);

    // n-only qkv part + GCN adjacency
    kern_T<<<(NN_ * D3_ + 255) / 256, 256, 0, stream>>>(word, Wi, bi, Tbuf);
    kern_adj<<<1, 64, 0, stream>>>(ei, Adj);

    // A[b,r] = img[b,:] . Wi[r, :512]          (1024 x 2436, K=512)
    gemm_k<1, 0, 0><<<dim3(39, 16, 1), 256, 0, stream>>>(
        img, IMG_, Wi, DD_, Abuf, D3_, B_, D3_, IMG_, 1.f, nullptr, nullptr, 0, 0);

    // S0 = scale * Aq @ Ak^T                    (1024 x 1024, K=812)
    gemm_k<1, 0, 0><<<dim3(16, 16, 1), 256, 0, stream>>>(
        Abuf, D3_, Abuf + DD_, D3_, Ebuf, 1024, 1024, 1024, DD_, scale, nullptr, nullptr, 0, 0);
    kern_exp_rows<<<1024, 256, 0, stream>>>(Ebuf);
    kern_w_ew<<<NN_, 256, 0, stream>>>(Tbuf, Abuf, EW, scale);

    // Avo = Av @ Wo^T  (out_proj folded into values); co = n-only part
    gemm_k<1, 0, 0><<<dim3(13, 16, 1), 256, 0, stream>>>(
        Abuf + 2 * DD_, D3_, Wo, DD_, Avo, DD_, B_, DD_, DD_, 1.f, nullptr, nullptr, 0, 0);
    kern_co<<<(NN_ * DD_ + 255) / 256, 256, 0, stream>>>(Tbuf, Wo, bo, CO);

    // P''[l, n*812+d] = sum_m E[l,m] * ew[n,m] * Avo[m,d]   (batched over n=z)
    gemm_k<0, 0, 1><<<dim3(13, 16, NN_), 256, 0, stream>>>(
        Ebuf, 1024, Avo, DD_, Pbuf, NN_ * DD_, B_, DD_, 1024, 1.f, nullptr, EW, 1024, DD_);
    kern_Z<<<BNR_ / 256, 256, 0, stream>>>(Ebuf, EW, Zb);

    // x1 = LN1(node + attn_out_projected)
    kern_ln1<<<BNR_, 256, 0, stream>>>(img, word, Pbuf, Zb, CO, g1, bt1, X1);

    // FFN: H = relu(x1@W1 + b1);  x1 += H@W2 + b2 (in-place epilogue); LN2
    gemm_k<0, 1, 0><<<dim3(32, 224, 1), 256, 0, stream>>>(
        X1, DD_, W1, FF_, Hbuf, FF_, BNR_, FF_, DD_, 1.f, bf1, nullptr, 0, 0);
    gemm_k<0, 2, 0><<<dim3(13, 224, 1), 256, 0, stream>>>(
        Hbuf, FF_, W2, DD_, X1, DD_, BNR_, DD_, FF_, 1.f, bf2, nullptr, 0, 0);
    kern_ln2<<<BNR_, 256, 0, stream>>>(X1, g2, bt2);

    // GCN1: H1 = x2 @ Wg1; aggregate+bias+relu
    gemm_k<0, 0, 0><<<dim3(2, 224, 1), 256, 0, stream>>>(
        X1, DD_, Wg1, HID_, H1, HID_, BNR_, HID_, DD_, 1.f, nullptr, nullptr, 0, 0);
    kern_agg1<<<(B_ * HID_) / 256, 256, 0, stream>>>(H1, Adj, bg1, G1b);

    // GCN2: H2 = g1 @ Wg2; aggregate+bias, mean over nodes, relu
    gemm_k<0, 0, 0><<<dim3(2, 224, 1), 256, 0, stream>>>(
        G1b, HID_, Wg2, HID_, H2, HID_, BNR_, HID_, HID_, 1.f, nullptr, nullptr, 0, 0);
    kern_agg2_pool<<<(B_ * HID_) / 256, 256, 0, stream>>>(H2, Adj, bg2, Pool);

    // Final linear
    kern_lin<<<(B_ * CC_) / 256, 256, 0, stream>>>(Pool, Wl, bl, out);
}

// Round 2
// 955.420 us; speedup vs baseline: 2.5548x; 2.5548x over previous
//
#include <hip/hip_runtime.h>
#include <math.h>

// Problem constants
#define B_    1024
#define IMG_  512
#define TXT_  300
#define NN_   14
#define FF_   2048
#define HID_  128
#define CC_   14
#define EE_   182
#define DD_   812
#define D3_   2436
#define BNR_  14336          // B_*NN_
#define KP_   832            // 812 padded to /32, keeps rows 16B-aligned

typedef __bf16 bf16x8 __attribute__((ext_vector_type(8)));
typedef float  f32x4  __attribute__((ext_vector_type(4)));
typedef unsigned short u16;

__device__ __forceinline__ u16 f2bf(float f) {
    union { float f; unsigned u; } v; v.f = f;
    unsigned r = v.u + 0x7FFFu + ((v.u >> 16) & 1u);   // round-to-nearest-even
    return (u16)(r >> 16);
}

// ---------------------------------------------------------------------------
// Workspace layout (bytes). Time-multiplexed overlays:
//  [0, 75.9M):  phase1 P fp32(46.56M) + Gb(29.36M) | phase2 Hb bf16(58.72M)
//               | phase3 GCN: H1|G1b|H2|Pool
//  [75.9M, 122.5M): X1 fp32
//  [122.5M, 146.3M): X1b / X2b bf16 (reused)
//  [146.3M, 153.6M): SCR union {Ebuf|Wob|AvoT} then {W1T|W2T}
//  [153.6M, ~162.8M): persistent smalls
// ---------------------------------------------------------------------------
#define OFF_P     0ULL
#define OFF_GB    46563328ULL
#define OFF_HB    0ULL
#define OFF_H1    0ULL
#define OFF_G1B   7340032ULL
#define OFF_H2    11010048ULL
#define OFF_POOL  18350080ULL
#define OFF_X1    75923456ULL
#define OFF_X1B   122486784ULL
#define OFF_SCR   146341888ULL
#define OFF_EBUF  (OFF_SCR)
#define OFF_WOB   (OFF_SCR + 4194304ULL)
#define OFF_AVOT  (OFF_SCR + 5545472ULL)
#define OFF_W1T   (OFF_SCR)
#define OFF_W2T   (OFF_SCR + 3407872ULL)
#define OFF_PERS  153550336ULL
#define OFF_AQB   (OFF_PERS)
#define OFF_AKB   (OFF_PERS + 1703936ULL)
#define OFF_AVB   (OFF_PERS + 3407872ULL)
#define OFF_IMGB  (OFF_PERS + 5111808ULL)
#define OFF_WIB   (OFF_PERS + 6160384ULL)
#define OFF_TBUF  (OFF_PERS + 8654848ULL)
#define OFF_TQB   (OFF_PERS + 8791296ULL)
#define OFF_WBUF  (OFF_PERS + 8814592ULL)
#define OFF_CO    (OFF_PERS + 8871936ULL)
#define OFF_Z     (OFF_PERS + 8917504ULL)
#define OFF_ADJ   (OFF_PERS + 8974848ULL)
#define OFF_WG1T  (OFF_PERS + 8975872ULL)
#define OFF_WG2T  (OFF_PERS + 9188864ULL)

// ---------------------------------------------------------------------------
// bf16 MFMA GEMM: C[M,N] = scale * A[M,K] @ B^T, B stored [N][K] bf16.
// 128x128 tile, BK=32, 256 threads (4 waves, 2x2 of 64x64), 16x16x32 MFMA.
// K-tail (K%32!=0) and M/N edges handled by zero-fill staging + masked store.
// EPI 0: Cf = v*scale (fp32).  EPI 1: Cb = bf16(relu(v+bias[n])).
// EPI 2: Cf += v + bias[n] (in-place resid).  EPI 3: Cb = bf16(v).
// EPI 4: split-3 bf16 store (A-proj -> Aq/Ak/Av, each [1024][832], contiguous).
// ---------------------------------------------------------------------------
template<int EPI>
__global__ __launch_bounds__(256)
void bgemm(const u16* __restrict__ A, int lda,
           const u16* __restrict__ Bm, int ldb,
           int M, int N, int K, float scale,
           float* __restrict__ Cf, int ldc,
           u16* __restrict__ Cb, int ldcb,
           const float* __restrict__ bias)
{
    __shared__ __align__(16) u16 As[128 * 40];   // +8 bf16 pad: conflict-free b128
    __shared__ __align__(16) u16 Bs[128 * 40];
    const int tid  = threadIdx.x;
    const int row0 = blockIdx.y * 128;
    const int col0 = blockIdx.x * 128;
    const int lane = tid & 63;
    const int wv   = tid >> 6;
    const int wm   = (wv >> 1) * 64, wn = (wv & 1) * 64;
    const int fr   = lane & 15, qd = lane >> 4;
    const int sr   = tid >> 2;            // staging row 0..63
    const int sk   = (tid & 3) * 8;       // staging k offset 0,8,16,24

    f32x4 acc[4][4] = {};

    for (int k0 = 0; k0 < K; k0 += 32) {
        #pragma unroll
        for (int p = 0; p < 2; ++p) {
            int r = sr + p * 64;
            int gk = k0 + sk;
            // A tile
            {
                int gr = row0 + r;
                uint4 val = make_uint4(0u, 0u, 0u, 0u);
                if (gr < M) {
                    if (gk + 8 <= K) val = *(const uint4*)(A + (size_t)gr * lda + gk);
                    else {
                        union { uint4 v; u16 h[8]; } u; u.v = make_uint4(0u,0u,0u,0u);
                        for (int j = 0; j < 8; ++j)
                            if (gk + j < K) u.h[j] = A[(size_t)gr * lda + gk + j];
                        val = u.v;
                    }
                }
                *(uint4*)&As[r * 40 + sk] = val;
            }
            // B tile (rows are output columns n)
            {
                int gn = col0 + r;
                uint4 val = make_uint4(0u, 0u, 0u, 0u);
                if (gn < N) {
                    if (gk + 8 <= K) val = *(const uint4*)(Bm + (size_t)gn * ldb + gk);
                    else {
                        union { uint4 v; u16 h[8]; } u; u.v = make_uint4(0u,0u,0u,0u);
                        for (int j = 0; j < 8; ++j)
                            if (gk + j < K) u.h[j] = Bm[(size_t)gn * ldb + gk + j];
                        val = u.v;
                    }
                }
                *(uint4*)&Bs[r * 40 + sk] = val;
            }
        }
        __syncthreads();

        bf16x8 af[4], bg[4];
        #pragma unroll
        for (int i = 0; i < 4; ++i) {
            af[i] = *(const bf16x8*)&As[(wm + i * 16 + fr) * 40 + qd * 8];
            bg[i] = *(const bf16x8*)&Bs[(wn + i * 16 + fr) * 40 + qd * 8];
        }
        #pragma unroll
        for (int mi = 0; mi < 4; ++mi)
            #pragma unroll
            for (int ni = 0; ni < 4; ++ni)
                acc[mi][ni] = __builtin_amdgcn_mfma_f32_16x16x32_bf16(
                    af[mi], bg[ni], acc[mi][ni], 0, 0, 0);
        __syncthreads();
    }

    #pragma unroll
    for (int mi = 0; mi < 4; ++mi) {
        #pragma unroll
        for (int i = 0; i < 4; ++i) {
            int rm = row0 + wm + mi * 16 + qd * 4 + i;
            if (rm >= M) continue;
            #pragma unroll
            for (int ni = 0; ni < 4; ++ni) {
                int cn = col0 + wn + ni * 16 + fr;
                if (cn >= N) continue;
                float v = acc[mi][ni][i] * scale;
                if (EPI == 0) Cf[(size_t)rm * ldc + cn] = v;
                if (EPI == 1) { v += bias[cn]; v = v > 0.f ? v : 0.f;
                                Cb[(size_t)rm * ldcb + cn] = f2bf(v); }
                if (EPI == 2) { size_t ix = (size_t)rm * ldc + cn;
                                Cf[ix] = v + bias[cn] + Cf[ix]; }
                if (EPI == 3) Cb[(size_t)rm * ldcb + cn] = f2bf(v);
                if (EPI == 4) { int bs = cn / DD_, cc = cn - bs * DD_;
                                Cb[(size_t)bs * (1024 * KP_) + (size_t)rm * KP_ + cc] = f2bf(v); }
            }
        }
    }
}

// fp32 -> bf16 cast-copy: dst[r*drs+c] = src[r*srs+c]
__global__ void kern_cast(const float* __restrict__ src, int srs,
                          u16* __restrict__ dst, int drs, int rows, int cols)
{
    int idx = blockIdx.x * 256 + threadIdx.x;
    if (idx >= rows * cols) return;
    int r = idx / cols, c = idx - r * cols;
    dst[(size_t)r * drs + c] = f2bf(src[(size_t)r * srs + c]);
}

// fp32 -> bf16 cast-transpose: dst[c*drs+r] = src[r*srs+c]  (writes coalesced in r)
__global__ void kern_castT(const float* __restrict__ src, int srs,
                           u16* __restrict__ dst, int drs, int rows, int cols)
{
    int idx = blockIdx.x * 256 + threadIdx.x;
    if (idx >= rows * cols) return;
    int c = idx / rows, r = idx - c * rows;
    dst[(size_t)c * drs + r] = f2bf(src[(size_t)r * srs + c]);
}

// T[n,r] = in_proj_b[r] + word[n,:] . in_proj_w[r, 512:812]
__global__ void kern_T(const float* __restrict__ word, const float* __restrict__ W,
                       const float* __restrict__ bias, float* __restrict__ T)
{
    int idx = blockIdx.x * 256 + threadIdx.x;
    if (idx >= NN_ * D3_) return;
    int n = idx / D3_, r = idx % D3_;
    const float* wr = word + n * TXT_;
    const float* Wr = W + (size_t)r * DD_ + IMG_;
    float s = bias[r];
    for (int c = 0; c < TXT_; ++c) s = fmaf(wr[c], Wr[c], s);
    T[idx] = s;
}

// Dense 14x14 GCN adjacency (self-loops + symmetric norm)
__global__ void kern_adj(const int* __restrict__ ei, float* __restrict__ Adj)
{
    if (threadIdx.x != 0 || blockIdx.x != 0) return;
    float deg[NN_];
    for (int i = 0; i < NN_; ++i) deg[i] = 1.f;
    for (int e = 0; e < EE_; ++e) deg[ei[EE_ + e]] += 1.f;
    float dinv[NN_];
    for (int i = 0; i < NN_; ++i) dinv[i] = rsqrtf(deg[i]);
    float adj[NN_ * NN_];
    for (int t = 0; t < NN_ * NN_; ++t) adj[t] = 0.f;
    for (int e = 0; e < EE_; ++e) {
        int s = ei[e], d = ei[EE_ + e];
        adj[d * NN_ + s] += dinv[s] * dinv[d];
    }
    for (int i = 0; i < NN_; ++i) adj[i * NN_ + i] += dinv[i] * dinv[i];
    for (int t = 0; t < NN_ * NN_; ++t) Adj[t] = adj[t];
}

// row -> exp(row - rowmax), rows of length 1024, in place
__global__ __launch_bounds__(256) void kern_exp_rows(float* __restrict__ S)
{
    __shared__ float red[256];
    float* row = S + (size_t)blockIdx.x * 1024;
    float m = -1e30f;
    for (int i = threadIdx.x; i < 1024; i += 256) m = fmaxf(m, row[i]);
    red[threadIdx.x] = m; __syncthreads();
    for (int s = 128; s > 0; s >>= 1) {
        if (threadIdx.x < s) red[threadIdx.x] = fmaxf(red[threadIdx.x], red[threadIdx.x + s]);
        __syncthreads();
    }
    m = red[0];
    for (int i = threadIdx.x; i < 1024; i += 256) row[i] = expf(row[i] - m);
}

// co[n,d] = out_proj_b[d] + Tv[n,:] . Wo[d,:]
__global__ void kern_co(const float* __restrict__ T, const float* __restrict__ Wo,
                        const float* __restrict__ bo, float* __restrict__ co)
{
    int idx = blockIdx.x * 256 + threadIdx.x;
    if (idx >= NN_ * DD_) return;
    int n = idx / DD_, d = idx % DD_;
    const float* Tv = T + n * D3_ + 2 * DD_;
    const float* wr = Wo + (size_t)d * DD_;
    float s = bo[d];
    for (int c = 0; c < DD_; ++c) s = fmaf(Tv[c], wr[c], s);
    co[idx] = s;
}

// G[row=l*14+z, m] = E[l,m]*ew[z,m] -> bf16; Z[row] = sum_m (fp32)
__global__ __launch_bounds__(256) void kern_G(const float* __restrict__ E,
    const float* __restrict__ EW, u16* __restrict__ Gb, float* __restrict__ Z)
{
    __shared__ float red[256];
    int row = blockIdx.x;
    int l = row / NN_, z = row - l * NN_;
    const float* er = E + (size_t)l * 1024;
    const float* wr = EW + (size_t)z * 1024;
    float s = 0.f;
    for (int m = threadIdx.x; m < 1024; m += 256) {
        float g = er[m] * wr[m];
        Gb[(size_t)row * 1024 + m] = f2bf(g);
        s += g;
    }
    red[threadIdx.x] = s; __syncthreads();
    for (int t = 128; t > 0; t >>= 1) {
        if (threadIdx.x < t) red[threadIdx.x] += red[threadIdx.x + t];
        __syncthreads();
    }
    if (threadIdx.x == 0) Z[row] = red[0];
}

// x1 = LN1(node + P/Z + co); writes fp32 X1 and bf16 X1b
__global__ __launch_bounds__(256) void kern_ln1(
    const float* __restrict__ img, const float* __restrict__ word,
    const float* __restrict__ P, const float* __restrict__ Z,
    const float* __restrict__ co, const float* __restrict__ g,
    const float* __restrict__ bta, float* __restrict__ X, u16* __restrict__ Xb)
{
    __shared__ float buf[DD_];
    __shared__ float red[256];
    __shared__ float stats[2];
    int row = blockIdx.x;
    int b = row / NN_, n = row - b * NN_;
    float invZ = 1.f / Z[row];
    const float* pr = P + (size_t)row * DD_;
    const float* cr = co + n * DD_;
    float s = 0.f;
    for (int d = threadIdx.x; d < DD_; d += 256) {
        float v = (d < IMG_) ? img[(size_t)b * IMG_ + d] : word[n * TXT_ + d - IMG_];
        v += pr[d] * invZ + cr[d];
        buf[d] = v; s += v;
    }
    red[threadIdx.x] = s; __syncthreads();
    for (int t = 128; t > 0; t >>= 1) {
        if (threadIdx.x < t) red[threadIdx.x] += red[threadIdx.x + t];
        __syncthreads();
    }
    if (threadIdx.x == 0) stats[0] = red[0] / DD_;
    __syncthreads();
    float mu = stats[0], s2 = 0.f;
    for (int d = threadIdx.x; d < DD_; d += 256) { float t = buf[d] - mu; s2 += t * t; }
    red[threadIdx.x] = s2; __syncthreads();
    for (int t = 128; t > 0; t >>= 1) {
        if (threadIdx.x < t) red[threadIdx.x] += red[threadIdx.x + t];
        __syncthreads();
    }
    if (threadIdx.x == 0) stats[1] = rsqrtf(red[0] / DD_ + 1e-5f);
    __syncthreads();
    float rstd = stats[1];
    float* xr = X + (size_t)row * DD_;
    u16* xb = Xb + (size_t)row * KP_;
    for (int d = threadIdx.x; d < DD_; d += 256) {
        float v = (buf[d] - mu) * rstd * g[d] + bta[d];
        xr[d] = v; xb[d] = f2bf(v);
    }
}

// in-place LN2 on fp32 X; also writes bf16 X2b
__global__ __launch_bounds__(256) void kern_ln2(float* __restrict__ X,
    const float* __restrict__ g, const float* __restrict__ bta, u16* __restrict__ Xb)
{
    __shared__ float buf[DD_];
    __shared__ float red[256];
    __shared__ float stats[2];
    float* xr = X + (size_t)blockIdx.x * DD_;
    float s = 0.f;
    for (int d = threadIdx.x; d < DD_; d += 256) { float v = xr[d]; buf[d] = v; s += v; }
    red[threadIdx.x] = s; __syncthreads();
    for (int t = 128; t > 0; t >>= 1) {
        if (threadIdx.x < t) red[threadIdx.x] += red[threadIdx.x + t];
        __syncthreads();
    }
    if (threadIdx.x == 0) stats[0] = red[0] / DD_;
    __syncthreads();
    float mu = stats[0], s2 = 0.f;
    for (int d = threadIdx.x; d < DD_; d += 256) { float t = buf[d] - mu; s2 += t * t; }
    red[threadIdx.x] = s2; __syncthreads();
    for (int t = 128; t > 0; t >>= 1) {
        if (threadIdx.x < t) red[threadIdx.x] += red[threadIdx.x + t];
        __syncthreads();
    }
    if (threadIdx.x == 0) stats[1] = rsqrtf(red[0] / DD_ + 1e-5f);
    __syncthreads();
    float rstd = stats[1];
    u16* xb = Xb + (size_t)blockIdx.x * KP_;
    for (int d = threadIdx.x; d < DD_; d += 256) {
        float v = (buf[d] - mu) * rstd * g[d] + bta[d];
        xr[d] = v; xb[d] = f2bf(v);
    }
}

// g1 = relu(Adj @ h1 + bias) -> bf16
__global__ __launch_bounds__(256) void kern_agg1(const float* __restrict__ H,
    const float* __restrict__ Adj, const float* __restrict__ bias, u16* __restrict__ G)
{
    __shared__ float sA[NN_ * NN_];
    if (threadIdx.x < NN_ * NN_) sA[threadIdx.x] = Adj[threadIdx.x];
    __syncthreads();
    int t = blockIdx.x * 256 + threadIdx.x;
    int b = t >> 7, f = t & 127;
    float v[NN_];
    #pragma unroll
    for (int i = 0; i < NN_; ++i) v[i] = H[((size_t)b * NN_ + i) * HID_ + f];
    float bb = bias[f];
    #pragma unroll
    for (int j = 0; j < NN_; ++j) {
        float s = bb;
        #pragma unroll
        for (int i = 0; i < NN_; ++i) s = fmaf(sA[j * NN_ + i], v[i], s);
        G[((size_t)b * NN_ + j) * HID_ + f] = f2bf(s > 0.f ? s : 0.f);
    }
}

// pool = relu(mean_j(Adj @ h2 + bias))
__global__ __launch_bounds__(256) void kern_agg2_pool(const float* __restrict__ H,
    const float* __restrict__ Adj, const float* __restrict__ bias, float* __restrict__ P)
{
    __shared__ float sA[NN_ * NN_];
    if (threadIdx.x < NN_ * NN_) sA[threadIdx.x] = Adj[threadIdx.x];
    __syncthreads();
    int t = blockIdx.x * 256 + threadIdx.x;
    int b = t >> 7, f = t & 127;
    float v[NN_];
    #pragma unroll
    for (int i = 0; i < NN_; ++i) v[i] = H[((size_t)b * NN_ + i) * HID_ + f];
    float acc = 0.f;
    #pragma unroll
    for (int j = 0; j < NN_; ++j) {
        float s = 0.f;
        #pragma unroll
        for (int i = 0; i < NN_; ++i) s = fmaf(sA[j * NN_ + i], v[i], s);
        acc += s;
    }
    acc = acc / (float)NN_ + bias[f];
    P[(size_t)b * HID_ + f] = acc > 0.f ? acc : 0.f;
}

__global__ void kern_lin(const float* __restrict__ pool, const float* __restrict__ W,
                         const float* __restrict__ bias, float* __restrict__ out)
{
    int t = blockIdx.x * 256 + threadIdx.x;
    if (t >= B_ * CC_) return;
    int b = t / CC_, c = t % CC_;
    float s = bias[c];
    const float* pr = pool + (size_t)b * HID_;
    for (int f = 0; f < HID_; ++f) s = fmaf(pr[f], W[f * CC_ + c], s);
    out[t] = s;
}

extern "C" void kernel_launch(void* const* d_in, const int* in_sizes, int n_in,
                              void* d_out, int out_size, void* d_ws, size_t ws_size,
                              hipStream_t stream)
{
    const float* img  = (const float*)d_in[0];
    const float* word = (const float*)d_in[1];
    const int*   ei   = (const int*)d_in[2];
    const float* Wi   = (const float*)d_in[3];
    const float* bi   = (const float*)d_in[4];
    const float* Wo   = (const float*)d_in[5];
    const float* bo   = (const float*)d_in[6];
    const float* g1   = (const float*)d_in[7];
    const float* bt1  = (const float*)d_in[8];
    const float* g2   = (const float*)d_in[9];
    const float* bt2  = (const float*)d_in[10];
    const float* W1   = (const float*)d_in[11];
    const float* bf1  = (const float*)d_in[12];
    const float* W2   = (const float*)d_in[13];
    const float* bf2  = (const float*)d_in[14];
    const float* Wg1  = (const float*)d_in[15];
    const float* bg1  = (const float*)d_in[16];
    const float* Wg2  = (const float*)d_in[17];
    const float* bg2  = (const float*)d_in[18];
    const float* Wl   = (const float*)d_in[19];
    const float* bl   = (const float*)d_in[20];
    float* out = (float*)d_out;

    char* ws = (char*)d_ws;
    float* P    = (float*)(ws + OFF_P);
    u16*   Gb   = (u16*)  (ws + OFF_GB);
    u16*   Hb   = (u16*)  (ws + OFF_HB);
    float* H1   = (float*)(ws + OFF_H1);
    u16*   G1b  = (u16*)  (ws + OFF_G1B);
    float* H2   = (float*)(ws + OFF_H2);
    float* Pool = (float*)(ws + OFF_POOL);
    float* X1   = (float*)(ws + OFF_X1);
    u16*   X1b  = (u16*)  (ws + OFF_X1B);
    u16*   X2b  = (u16*)  (ws + OFF_X1B);
    float* Ebuf = (float*)(ws + OFF_EBUF);
    u16*   Wob  = (u16*)  (ws + OFF_WOB);
    u16*   AvoT = (u16*)  (ws + OFF_AVOT);
    u16*   W1T  = (u16*)  (ws + OFF_W1T);
    u16*   W2T  = (u16*)  (ws + OFF_W2T);
    u16*   Aqb  = (u16*)  (ws + OFF_AQB);
    u16*   Akb  = (u16*)  (ws + OFF_AKB);
    u16*   Avb  = (u16*)  (ws + OFF_AVB);
    u16*   imgb = (u16*)  (ws + OFF_IMGB);
    u16*   Wib  = (u16*)  (ws + OFF_WIB);
    float* Tbuf = (float*)(ws + OFF_TBUF);
    u16*   Tqb  = (u16*)  (ws + OFF_TQB);
    float* wbuf = (float*)(ws + OFF_WBUF);
    float* co   = (float*)(ws + OFF_CO);
    float* Zb   = (float*)(ws + OFF_Z);
    float* Adj  = (float*)(ws + OFF_ADJ);
    u16*   Wg1T = (u16*)  (ws + OFF_WG1T);
    u16*   Wg2T = (u16*)  (ws + OFF_WG2T);

    const float scl = 1.0f / sqrtf((float)DD_);

    // --- small precompute + casts ---
    kern_T<<<(NN_ * D3_ + 255) / 256, 256, 0, stream>>>(word, Wi, bi, Tbuf);
    kern_adj<<<1, 64, 0, stream>>>(ei, Adj);
    kern_cast<<<(B_ * IMG_ + 255) / 256, 256, 0, stream>>>(img, IMG_, imgb, IMG_, B_, IMG_);
    kern_cast<<<(D3_ * IMG_ + 255) / 256, 256, 0, stream>>>(Wi, DD_, Wib, IMG_, D3_, IMG_);
    kern_cast<<<(NN_ * DD_ + 255) / 256, 256, 0, stream>>>(Tbuf, D3_, Tqb, KP_, NN_, DD_);
    kern_cast<<<(DD_ * DD_ + 255) / 256, 256, 0, stream>>>(Wo, DD_, Wob, KP_, DD_, DD_);

    // --- A-proj: [Aq|Ak|Av] = img @ Wi[:, :512]^T  (split-3 bf16 epilogue) ---
    bgemm<4><<<dim3(20, 8), 256, 0, stream>>>(imgb, IMG_, Wib, IMG_,
        B_, D3_, IMG_, 1.f, nullptr, 0, Aqb, 0, nullptr);

    // --- S0 = scale*Aq@Ak^T ; w = scale*Tq@Ak^T ; exp both ---
    bgemm<0><<<dim3(8, 8), 256, 0, stream>>>(Aqb, KP_, Akb, KP_,
        B_, B_, DD_, scl, Ebuf, 1024, nullptr, 0, nullptr);
    bgemm<0><<<dim3(8, 1), 256, 0, stream>>>(Tqb, KP_, Akb, KP_,
        NN_, B_, DD_, scl, wbuf, 1024, nullptr, 0, nullptr);
    kern_exp_rows<<<1024, 256, 0, stream>>>(Ebuf);
    kern_exp_rows<<<NN_, 256, 0, stream>>>(wbuf);   // wbuf becomes ew

    // --- AvoT[d,m] = (Av @ Wo^T)^T  (out-proj folded into values) ---
    bgemm<3><<<dim3(8, 7), 256, 0, stream>>>(Wob, KP_, Avb, KP_,
        DD_, B_, DD_, 1.f, nullptr, 0, AvoT, 1024, nullptr);
    kern_co<<<(NN_ * DD_ + 255) / 256, 256, 0, stream>>>(Tbuf, Wo, bo, co);

    // --- G = E*ew (bf16) + row sums Z; P = G @ Avo ---
    kern_G<<<BNR_, 256, 0, stream>>>(Ebuf, wbuf, Gb, Zb);
    bgemm<0><<<dim3(7, 112), 256, 0, stream>>>(Gb, 1024, AvoT, 1024,
        BNR_, DD_, 1024, 1.f, P, DD_, nullptr, 0, nullptr);

    // --- LN1 ---
    kern_ln1<<<BNR_, 256, 0, stream>>>(img, word, P, Zb, co, g1, bt1, X1, X1b);

    // --- FFN (bf16 MFMA), LN2 ---
    kern_castT<<<(DD_ * FF_ + 255) / 256, 256, 0, stream>>>(W1, FF_, W1T, KP_, DD_, FF_);
    kern_castT<<<(FF_ * DD_ + 255) / 256, 256, 0, stream>>>(W2, DD_, W2T, FF_, FF_, DD_);
    bgemm<1><<<dim3(16, 112), 256, 0, stream>>>(X1b, KP_, W1T, KP_,
        BNR_, FF_, DD_, 1.f, nullptr, 0, Hb, FF_, bf1);
    bgemm<2><<<dim3(7, 112), 256, 0, stream>>>(Hb, FF_, W2T, FF_,
        BNR_, DD_, FF_, 1.f, X1, DD_, nullptr, 0, bf2);
    kern_ln2<<<BNR_, 256, 0, stream>>>(X1, g2, bt2, X2b);

    // --- GCN ---
    kern_castT<<<(DD_ * HID_ + 255) / 256, 256, 0, stream>>>(Wg1, HID_, Wg1T, KP_, DD_, HID_);
    kern_castT<<<(HID_ * HID_ + 255) / 256, 256, 0, stream>>>(Wg2, HID_, Wg2T, HID_, HID_, HID_);
    bgemm<0><<<dim3(1, 112), 256, 0, stream>>>(X2b, KP_, Wg1T, KP_,
        BNR_, HID_, DD_, 1.f, H1, HID_, nullptr, 0, nullptr);
    kern_agg1<<<(B_ * HID_) / 256, 256, 0, stream>>>(H1, Adj, bg1, G1b);
    bgemm<0><<<dim3(1, 112), 256, 0, stream>>>(G1b, HID_, Wg2T, HID_,
        BNR_, HID_, HID_, 1.f, H2, HID_, nullptr, 0, nullptr);
    kern_agg2_pool<<<(B_ * HID_) / 256, 256, 0, stream>>>(H2, Adj, bg2, Pool);
    kern_lin<<<(B_ * CC_) / 256, 256, 0, stream>>>(Pool, Wl, bl, out);
}

// Round 4
// 769.992 us; speedup vs baseline: 3.1701x; 1.2408x over previous
//
#include <hip/hip_runtime.h>
#include <math.h>

// Problem constants
#define B_    1024
#define IMG_  512
#define TXT_  300
#define NN_   14
#define FF_   2048
#define HID_  128
#define CC_   14
#define EE_   182
#define DD_   812
#define D3_   2436
#define BNR_  14336          // B_*NN_
#define KP_   832            // 812 padded to /32 (16B-aligned rows)

typedef __bf16 bf16x8 __attribute__((ext_vector_type(8)));
typedef float  f32x4  __attribute__((ext_vector_type(4)));
typedef unsigned short u16;

__device__ __forceinline__ u16 f2bf(float f) {
    union { float f; unsigned u; } v; v.f = f;
    unsigned r = v.u + 0x7FFFu + ((v.u >> 16) & 1u);   // RNE
    return (u16)(r >> 16);
}

// async global->LDS, 16B per lane. LDS dst = wave-uniform base + lane*16.
__device__ __forceinline__ void gload_lds16(const u16* g, u16* l) {
    __builtin_amdgcn_global_load_lds(
        (const __attribute__((address_space(1))) void*)g,
        (__attribute__((address_space(3))) void*)l, 16, 0, 0);
}

// ---------------------------------------------------------------------------
// Workspace layout (bytes), time-multiplexed overlays.
// NOTE: any K-pad column read by a GEMM MUST be explicitly zeroed on BOTH
// operands — recycled workspace bytes can encode bf16 NaN, and 0*NaN=NaN
// (round-3 bug: W1T pads = old Ebuf bytes -> NaN -> relu clamped to 0).
// ---------------------------------------------------------------------------
#define OFF_P     0ULL
#define OFF_GB    46563328ULL
#define OFF_HB    0ULL
#define OFF_H1    0ULL
#define OFF_G1B   7340032ULL
#define OFF_H2    11010048ULL
#define OFF_POOL  18350080ULL
#define OFF_X1    75923456ULL
#define OFF_X1B   122486784ULL
#define OFF_SCR   146341888ULL
#define OFF_EBUF  (OFF_SCR)
#define OFF_WOB   (OFF_SCR + 4194304ULL)
#define OFF_AVOT  (OFF_SCR + 5685248ULL)
#define OFF_W1T   (OFF_SCR)
#define OFF_W2T   (OFF_SCR + 3407872ULL)
#define OFF_PERS  (OFF_SCR + 7520256ULL)   // 153862144
#define OFF_AQB   (OFF_PERS)
#define OFF_AKB   (OFF_PERS + 1703936ULL)
#define OFF_AVB   (OFF_PERS + 3407872ULL)
#define OFF_IMGB  (OFF_PERS + 5111808ULL)
#define OFF_WIB   (OFF_PERS + 6160384ULL)
#define OFF_TBUF  (OFF_PERS + 8781824ULL)
#define OFF_TQB   (OFF_PERS + 8918272ULL)
#define OFF_WBUF  (OFF_PERS + 9131264ULL)
#define OFF_CO    (OFF_PERS + 9188608ULL)
#define OFF_Z     (OFF_PERS + 9234176ULL)
#define OFF_ADJ   (OFF_PERS + 9291520ULL)
#define OFF_WG1T  (OFF_PERS + 9292544ULL)
#define OFF_WG2T  (OFF_PERS + 9505536ULL)

// ---------------------------------------------------------------------------
// bf16 MFMA GEMM, m97 structure: C[M,N] = scale * A[M,K] @ B^T (B stored [N][K]).
// 128x128 tile, BK=32, 4 waves (2x2 of 64x64), 16x16x32 MFMA.
// global_load_lds width-16 staging, NO bounds checks in the K-loop:
//   - K must be %32 with K-pad zero-filled on BOTH operands (NaN hazard);
//   - A must have >= row0+128 rows allocated, B >= col0+128 rows (pad rows
//     may hold garbage; epilogue masks rm<M, cn<N).
// 1D grid; swiz=1 maps id%8 -> row-tile (needs nyt%8==0) for XCD L2 reuse.
// EPI 0: Cf=v. 1: Cb=bf16(relu(v+bias)). 2: Cf+=v+bias. 3: Cb=bf16(v).
// EPI 4: split-3 store into [Aq|Ak|Av], each [1024][KP_], contiguous.
// ---------------------------------------------------------------------------
template<int EPI>
__global__ __launch_bounds__(256)
void bgemm(const u16* __restrict__ A, int lda,
           const u16* __restrict__ Bm, int ldb,
           int M, int N, int K, float scale,
           float* __restrict__ Cf, int ldc,
           u16* __restrict__ Cb, int ldcb,
           const float* __restrict__ bias,
           int nxt, int swiz)
{
    __shared__ __align__(16) u16 As[128 * 32];
    __shared__ __align__(16) u16 Bs[128 * 32];
    const int tid = threadIdx.x;
    int bx, by;
    {
        int id = blockIdx.x;
        if (swiz) { int r8 = id & 7; int q = id >> 3; bx = q % nxt; by = (q / nxt) * 8 + r8; }
        else      { bx = id % nxt; by = id / nxt; }
    }
    const int row0 = by * 128, col0 = bx * 128;
    const int lane = tid & 63, wv = tid >> 6;
    const int wm = (wv >> 1) * 64, wn = (wv & 1) * 64;
    const int fr = lane & 15, qd = lane >> 4;

    f32x4 acc[4][4] = {};

    for (int k0 = 0; k0 < K; k0 += 32) {
        #pragma unroll
        for (int q = 0; q < 2; ++q) {
            const int chunk = q * 256 + wv * 64 + lane;   // 0..511
            const int r  = chunk >> 2;                    // tile row 0..127
            const int ko = (chunk & 3) * 8;               // k-offset in u16
            const int base = (q * 256 + wv * 64) * 8;     // wave-uniform LDS u16 idx
            gload_lds16(A  + (size_t)(row0 + r) * lda + k0 + ko, &As[base]);
            gload_lds16(Bm + (size_t)(col0 + r) * ldb + k0 + ko, &Bs[base]);
        }
        __syncthreads();

        bf16x8 af[4], bg[4];
        #pragma unroll
        for (int i = 0; i < 4; ++i) {
            af[i] = *(const bf16x8*)&As[(wm + i * 16 + fr) * 32 + qd * 8];
            bg[i] = *(const bf16x8*)&Bs[(wn + i * 16 + fr) * 32 + qd * 8];
        }
        #pragma unroll
        for (int mi = 0; mi < 4; ++mi)
            #pragma unroll
            for (int ni = 0; ni < 4; ++ni)
                acc[mi][ni] = __builtin_amdgcn_mfma_f32_16x16x32_bf16(
                    af[mi], bg[ni], acc[mi][ni], 0, 0, 0);
        __syncthreads();
    }

    #pragma unroll
    for (int mi = 0; mi < 4; ++mi) {
        #pragma unroll
        for (int i = 0; i < 4; ++i) {
            int rm = row0 + wm + mi * 16 + qd * 4 + i;
            if (rm >= M) continue;
            #pragma unroll
            for (int ni = 0; ni < 4; ++ni) {
                int cn = col0 + wn + ni * 16 + fr;
                if (cn >= N) continue;
                float v = acc[mi][ni][i] * scale;
                if (EPI == 0) Cf[(size_t)rm * ldc + cn] = v;
                if (EPI == 1) { v += bias[cn]; v = v > 0.f ? v : 0.f;
                                Cb[(size_t)rm * ldcb + cn] = f2bf(v); }
                if (EPI == 2) { size_t ix = (size_t)rm * ldc + cn;
                                Cf[ix] = v + bias[cn] + Cf[ix]; }
                if (EPI == 3) Cb[(size_t)rm * ldcb + cn] = f2bf(v);
                if (EPI == 4) { int bs = cn / DD_, cc = cn - bs * DD_;
                                Cb[(size_t)bs * (1024 * KP_) + (size_t)rm * KP_ + cc] = f2bf(v); }
            }
        }
    }
}

// fp32->bf16 cast: dst[r*drs+c] = (c<scols) ? src[r*srs+c] : 0, c < dcols
__global__ void kern_cast(const float* __restrict__ src, int srs,
                          u16* __restrict__ dst, int drs, int rows, int dcols, int scols)
{
    int idx = blockIdx.x * 256 + threadIdx.x;
    if (idx >= rows * dcols) return;
    int r = idx / dcols, c = idx - r * dcols;
    dst[(size_t)r * drs + c] = (c < scols) ? f2bf(src[(size_t)r * srs + c]) : (u16)0;
}

// fp32->bf16 cast-transpose: dst[c*drs+r] = src[r*srs+c]
__global__ void kern_castT(const float* __restrict__ src, int srs,
                           u16* __restrict__ dst, int drs, int rows, int cols)
{
    int idx = blockIdx.x * 256 + threadIdx.x;
    if (idx >= rows * cols) return;
    int c = idx / rows, r = idx - c * rows;
    dst[(size_t)c * drs + r] = f2bf(src[(size_t)r * srs + c]);
}

// cast-transpose with zero K-pad: dst[c*drs+r] = r<rows ? src[r*srs+c] : 0,
// for r < padr. (Fixes the round-3 NaN bug: pads MUST be real zeros.)
__global__ void kern_castTp(const float* __restrict__ src, int srs,
                            u16* __restrict__ dst, int drs, int rows, int cols, int padr)
{
    int idx = blockIdx.x * 256 + threadIdx.x;
    if (idx >= cols * padr) return;
    int c = idx / padr, r = idx - c * padr;
    dst[(size_t)c * drs + r] = (r < rows) ? f2bf(src[(size_t)r * srs + c]) : (u16)0;
}

// zero K-pad cols [812,832) of Aq/Ak/Av (contiguous [3][1024][KP_])
__global__ void kern_zeropad(u16* __restrict__ Aq)
{
    int idx = blockIdx.x * 256 + threadIdx.x;
    if (idx >= 3 * 1024 * 20) return;
    int w = idx / (1024 * 20), rem = idx - w * (1024 * 20);
    int r = rem / 20, c = rem - r * 20;
    Aq[(size_t)w * (1024 * KP_) + (size_t)r * KP_ + DD_ + c] = 0;
}

// T[n,r] = in_proj_b[r] + word[n,:] . in_proj_w[r, 512:812]
__global__ void kern_T(const float* __restrict__ word, const float* __restrict__ W,
                       const float* __restrict__ bias, float* __restrict__ T)
{
    int idx = blockIdx.x * 256 + threadIdx.x;
    if (idx >= NN_ * D3_) return;
    int n = idx / D3_, r = idx % D3_;
    const float* wr = word + n * TXT_;
    const float* Wr = W + (size_t)r * DD_ + IMG_;
    float s = bias[r];
    for (int c = 0; c < TXT_; ++c) s = fmaf(wr[c], Wr[c], s);
    T[idx] = s;
}

// Dense 14x14 GCN adjacency (self-loops + symmetric norm)
__global__ void kern_adj(const int* __restrict__ ei, float* __restrict__ Adj)
{
    if (threadIdx.x != 0 || blockIdx.x != 0) return;
    float deg[NN_];
    for (int i = 0; i < NN_; ++i) deg[i] = 1.f;
    for (int e = 0; e < EE_; ++e) deg[ei[EE_ + e]] += 1.f;
    float dinv[NN_];
    for (int i = 0; i < NN_; ++i) dinv[i] = rsqrtf(deg[i]);
    float adj[NN_ * NN_];
    for (int t = 0; t < NN_ * NN_; ++t) adj[t] = 0.f;
    for (int e = 0; e < EE_; ++e) {
        int s = ei[e], d = ei[EE_ + e];
        adj[d * NN_ + s] += dinv[s] * dinv[d];
    }
    for (int i = 0; i < NN_; ++i) adj[i * NN_ + i] += dinv[i] * dinv[i];
    for (int t = 0; t < NN_ * NN_; ++t) Adj[t] = adj[t];
}

// row -> exp(row - rowmax), rows of length 1024, in place
__global__ __launch_bounds__(256) void kern_exp_rows(float* __restrict__ S)
{
    __shared__ float red[256];
    float* row = S + (size_t)blockIdx.x * 1024;
    float m = -1e30f;
    for (int i = threadIdx.x; i < 1024; i += 256) m = fmaxf(m, row[i]);
    red[threadIdx.x] = m; __syncthreads();
    for (int s = 128; s > 0; s >>= 1) {
        if (threadIdx.x < s) red[threadIdx.x] = fmaxf(red[threadIdx.x], red[threadIdx.x + s]);
        __syncthreads();
    }
    m = red[0];
    for (int i = threadIdx.x; i < 1024; i += 256) row[i] = expf(row[i] - m);
}

// co[n,d] = out_proj_b[d] + Tv[n,:] . Wo[d,:]
__global__ void kern_co(const float* __restrict__ T, const float* __restrict__ Wo,
                        const float* __restrict__ bo, float* __restrict__ co)
{
    int idx = blockIdx.x * 256 + threadIdx.x;
    if (idx >= NN_ * DD_) return;
    int n = idx / DD_, d = idx % DD_;
    const float* Tv = T + n * D3_ + 2 * DD_;
    const float* wr = Wo + (size_t)d * DD_;
    float s = bo[d];
    for (int c = 0; c < DD_; ++c) s = fmaf(Tv[c], wr[c], s);
    co[idx] = s;
}

// G[row=l*14+z, m] = E[l,m]*ew[z,m] -> bf16; Z[row] = sum_m (fp32)
__global__ __launch_bounds__(256) void kern_G(const float* __restrict__ E,
    const float* __restrict__ EW, u16* __restrict__ Gb, float* __restrict__ Z)
{
    __shared__ float red[256];
    int row = blockIdx.x;
    int l = row / NN_, z = row - l * NN_;
    const float* er = E + (size_t)l * 1024;
    const float* wr = EW + (size_t)z * 1024;
    float s = 0.f;
    for (int m = threadIdx.x; m < 1024; m += 256) {
        float g = er[m] * wr[m];
        Gb[(size_t)row * 1024 + m] = f2bf(g);
        s += g;
    }
    red[threadIdx.x] = s; __syncthreads();
    for (int t = 128; t > 0; t >>= 1) {
        if (threadIdx.x < t) red[threadIdx.x] += red[threadIdx.x + t];
        __syncthreads();
    }
    if (threadIdx.x == 0) Z[row] = red[0];
}

// x1 = LN1(node + P/Z + co); writes fp32 X1 and bf16 X1b (pad cols zeroed)
__global__ __launch_bounds__(256) void kern_ln1(
    const float* __restrict__ img, const float* __restrict__ word,
    const float* __restrict__ P, const float* __restrict__ Z,
    const float* __restrict__ co, const float* __restrict__ g,
    const float* __restrict__ bta, float* __restrict__ X, u16* __restrict__ Xb)
{
    __shared__ float buf[DD_];
    __shared__ float red[256];
    __shared__ float stats[2];
    int row = blockIdx.x;
    int b = row / NN_, n = row - b * NN_;
    float invZ = 1.f / Z[row];
    const float* pr = P + (size_t)row * DD_;
    const float* cr = co + n * DD_;
    float s = 0.f;
    for (int d = threadIdx.x; d < DD_; d += 256) {
        float v = (d < IMG_) ? img[(size_t)b * IMG_ + d] : word[n * TXT_ + d - IMG_];
        v += pr[d] * invZ + cr[d];
        buf[d] = v; s += v;
    }
    red[threadIdx.x] = s; __syncthreads();
    for (int t = 128; t > 0; t >>= 1) {
        if (threadIdx.x < t) red[threadIdx.x] += red[threadIdx.x + t];
        __syncthreads();
    }
    if (threadIdx.x == 0) stats[0] = red[0] / DD_;
    __syncthreads();
    float mu = stats[0], s2 = 0.f;
    for (int d = threadIdx.x; d < DD_; d += 256) { float t = buf[d] - mu; s2 += t * t; }
    red[threadIdx.x] = s2; __syncthreads();
    for (int t = 128; t > 0; t >>= 1) {
        if (threadIdx.x < t) red[threadIdx.x] += red[threadIdx.x + t];
        __syncthreads();
    }
    if (threadIdx.x == 0) stats[1] = rsqrtf(red[0] / DD_ + 1e-5f);
    __syncthreads();
    float rstd = stats[1];
    float* xr = X + (size_t)row * DD_;
    u16* xb = Xb + (size_t)row * KP_;
    for (int d = threadIdx.x; d < DD_; d += 256) {
        float v = (buf[d] - mu) * rstd * g[d] + bta[d];
        xr[d] = v; xb[d] = f2bf(v);
    }
    for (int d = DD_ + threadIdx.x; d < KP_; d += 256) xb[d] = 0;
}

// in-place LN2 on fp32 X; writes bf16 X2b (pad cols zeroed)
__global__ __launch_bounds__(256) void kern_ln2(float* __restrict__ X,
    const float* __restrict__ g, const float* __restrict__ bta, u16* __restrict__ Xb)
{
    __shared__ float buf[DD_];
    __shared__ float red[256];
    __shared__ float stats[2];
    float* xr = X + (size_t)blockIdx.x * DD_;
    float s = 0.f;
    for (int d = threadIdx.x; d < DD_; d += 256) { float v = xr[d]; buf[d] = v; s += v; }
    red[threadIdx.x] = s; __syncthreads();
    for (int t = 128; t > 0; t >>= 1) {
        if (threadIdx.x < t) red[threadIdx.x] += red[threadIdx.x + t];
        __syncthreads();
    }
    if (threadIdx.x == 0) stats[0] = red[0] / DD_;
    __syncthreads();
    float mu = stats[0], s2 = 0.f;
    for (int d = threadIdx.x; d < DD_; d += 256) { float t = buf[d] - mu; s2 += t * t; }
    red[threadIdx.x] = s2; __syncthreads();
    for (int t = 128; t > 0; t >>= 1) {
        if (threadIdx.x < t) red[threadIdx.x] += red[threadIdx.x + t];
        __syncthreads();
    }
    if (threadIdx.x == 0) stats[1] = rsqrtf(red[0] / DD_ + 1e-5f);
    __syncthreads();
    float rstd = stats[1];
    u16* xb = Xb + (size_t)blockIdx.x * KP_;
    for (int d = threadIdx.x; d < DD_; d += 256) {
        float v = (buf[d] - mu) * rstd * g[d] + bta[d];
        xr[d] = v; xb[d] = f2bf(v);
    }
    for (int d = DD_ + threadIdx.x; d < KP_; d += 256) xb[d] = 0;
}

// g1 = relu(Adj @ h1 + bias) -> bf16
__global__ __launch_bounds__(256) void kern_agg1(const float* __restrict__ H,
    const float* __restrict__ Adj, const float* __restrict__ bias, u16* __restrict__ G)
{
    __shared__ float sA[NN_ * NN_];
    if (threadIdx.x < NN_ * NN_) sA[threadIdx.x] = Adj[threadIdx.x];
    __syncthreads();
    int t = blockIdx.x * 256 + threadIdx.x;
    int b = t >> 7, f = t & 127;
    float v[NN_];
    #pragma unroll
    for (int i = 0; i < NN_; ++i) v[i] = H[((size_t)b * NN_ + i) * HID_ + f];
    float bb = bias[f];
    #pragma unroll
    for (int j = 0; j < NN_; ++j) {
        float s = bb;
        #pragma unroll
        for (int i = 0; i < NN_; ++i) s = fmaf(sA[j * NN_ + i], v[i], s);
        G[((size_t)b * NN_ + j) * HID_ + f] = f2bf(s > 0.f ? s : 0.f);
    }
}

// pool = relu(mean_j(Adj @ h2 + bias))
__global__ __launch_bounds__(256) void kern_agg2_pool(const float* __restrict__ H,
    const float* __restrict__ Adj, const float* __restrict__ bias, float* __restrict__ P)
{
    __shared__ float sA[NN_ * NN_];
    if (threadIdx.x < NN_ * NN_) sA[threadIdx.x] = Adj[threadIdx.x];
    __syncthreads();
    int t = blockIdx.x * 256 + threadIdx.x;
    int b = t >> 7, f = t & 127;
    float v[NN_];
    #pragma unroll
    for (int i = 0; i < NN_; ++i) v[i] = H[((size_t)b * NN_ + i) * HID_ + f];
    float acc = 0.f;
    #pragma unroll
    for (int j = 0; j < NN_; ++j) {
        float s = 0.f;
        #pragma unroll
        for (int i = 0; i < NN_; ++i) s = fmaf(sA[j * NN_ + i], v[i], s);
        acc += s;
    }
    acc = acc / (float)NN_ + bias[f];
    P[(size_t)b * HID_ + f] = acc > 0.f ? acc : 0.f;
}

__global__ void kern_lin(const float* __restrict__ pool, const float* __restrict__ W,
                         const float* __restrict__ bias, float* __restrict__ out)
{
    int t = blockIdx.x * 256 + threadIdx.x;
    if (t >= B_ * CC_) return;
    int b = t / CC_, c = t % CC_;
    float s = bias[c];
    const float* pr = pool + (size_t)b * HID_;
    for (int f = 0; f < HID_; ++f) s = fmaf(pr[f], W[f * CC_ + c], s);
    out[t] = s;
}

extern "C" void kernel_launch(void* const* d_in, const int* in_sizes, int n_in,
                              void* d_out, int out_size, void* d_ws, size_t ws_size,
                              hipStream_t stream)
{
    const float* img  = (const float*)d_in[0];
    const float* word = (const float*)d_in[1];
    const int*   ei   = (const int*)d_in[2];
    const float* Wi   = (const float*)d_in[3];
    const float* bi   = (const float*)d_in[4];
    const float* Wo   = (const float*)d_in[5];
    const float* bo   = (const float*)d_in[6];
    const float* g1   = (const float*)d_in[7];
    const float* bt1  = (const float*)d_in[8];
    const float* g2   = (const float*)d_in[9];
    const float* bt2  = (const float*)d_in[10];
    const float* W1   = (const float*)d_in[11];
    const float* bf1  = (const float*)d_in[12];
    const float* W2   = (const float*)d_in[13];
    const float* bf2  = (const float*)d_in[14];
    const float* Wg1  = (const float*)d_in[15];
    const float* bg1  = (const float*)d_in[16];
    const float* Wg2  = (const float*)d_in[17];
    const float* bg2  = (const float*)d_in[18];
    const float* Wl   = (const float*)d_in[19];
    const float* bl   = (const float*)d_in[20];
    float* out = (float*)d_out;

    char* ws = (char*)d_ws;
    float* P    = (float*)(ws + OFF_P);
    u16*   Gb   = (u16*)  (ws + OFF_GB);
    u16*   Hb   = (u16*)  (ws + OFF_HB);
    float* H1   = (float*)(ws + OFF_H1);
    u16*   G1b  = (u16*)  (ws + OFF_G1B);
    float* H2   = (float*)(ws + OFF_H2);
    float* Pool = (float*)(ws + OFF_POOL);
    float* X1   = (float*)(ws + OFF_X1);
    u16*   X1b  = (u16*)  (ws + OFF_X1B);
    u16*   X2b  = (u16*)  (ws + OFF_X1B);
    float* Ebuf = (float*)(ws + OFF_EBUF);
    u16*   Wob  = (u16*)  (ws + OFF_WOB);
    u16*   AvoT = (u16*)  (ws + OFF_AVOT);
    u16*   W1T  = (u16*)  (ws + OFF_W1T);
    u16*   W2T  = (u16*)  (ws + OFF_W2T);
    u16*   Aqb  = (u16*)  (ws + OFF_AQB);
    u16*   Akb  = (u16*)  (ws + OFF_AKB);
    u16*   Avb  = (u16*)  (ws + OFF_AVB);
    u16*   imgb = (u16*)  (ws + OFF_IMGB);
    u16*   Wib  = (u16*)  (ws + OFF_WIB);
    float* Tbuf = (float*)(ws + OFF_TBUF);
    u16*   Tqb  = (u16*)  (ws + OFF_TQB);
    float* wbuf = (float*)(ws + OFF_WBUF);
    float* co   = (float*)(ws + OFF_CO);
    float* Zb   = (float*)(ws + OFF_Z);
    float* Adj  = (float*)(ws + OFF_ADJ);
    u16*   Wg1T = (u16*)  (ws + OFF_WG1T);
    u16*   Wg2T = (u16*)  (ws + OFF_WG2T);

    const float scl = 1.0f / sqrtf((float)DD_);

    // --- small precompute + casts ---
    kern_T<<<(NN_ * D3_ + 255) / 256, 256, 0, stream>>>(word, Wi, bi, Tbuf);
    kern_adj<<<1, 64, 0, stream>>>(ei, Adj);
    kern_cast<<<(B_ * IMG_ + 255) / 256, 256, 0, stream>>>(img, IMG_, imgb, IMG_, B_, IMG_, IMG_);
    kern_cast<<<(D3_ * IMG_ + 255) / 256, 256, 0, stream>>>(Wi, DD_, Wib, IMG_, D3_, IMG_, IMG_);
    kern_cast<<<(NN_ * KP_ + 255) / 256, 256, 0, stream>>>(Tbuf, D3_, Tqb, KP_, NN_, KP_, DD_);
    kern_cast<<<(DD_ * KP_ + 255) / 256, 256, 0, stream>>>(Wo, DD_, Wob, KP_, DD_, KP_, DD_);

    // --- A-proj: [Aq|Ak|Av] = img @ Wi[:, :512]^T (split-3 bf16), then zero K-pads
    bgemm<4><<<20 * 8, 256, 0, stream>>>(imgb, IMG_, Wib, IMG_,
        B_, D3_, IMG_, 1.f, nullptr, 0, Aqb, 0, nullptr, 20, 1);
    kern_zeropad<<<240, 256, 0, stream>>>(Aqb);

    // --- S0 = scl*Aq@Ak^T ; w = scl*Tq@Ak^T ; exp both ---
    bgemm<0><<<8 * 8, 256, 0, stream>>>(Aqb, KP_, Akb, KP_,
        B_, B_, KP_, scl, Ebuf, 1024, nullptr, 0, nullptr, 8, 1);
    bgemm<0><<<8 * 1, 256, 0, stream>>>(Tqb, KP_, Akb, KP_,
        NN_, B_, KP_, scl, wbuf, 1024, nullptr, 0, nullptr, 8, 0);
    kern_exp_rows<<<1024, 256, 0, stream>>>(Ebuf);
    kern_exp_rows<<<NN_, 256, 0, stream>>>(wbuf);   // wbuf -> ew

    // --- AvoT[d,m] = (Av @ Wo^T)^T ; co = n-only part ---
    bgemm<3><<<8 * 7, 256, 0, stream>>>(Wob, KP_, Avb, KP_,
        DD_, B_, KP_, 1.f, nullptr, 0, AvoT, 1024, nullptr, 8, 0);
    kern_co<<<(NN_ * DD_ + 255) / 256, 256, 0, stream>>>(Tbuf, Wo, bo, co);

    // --- G = E*ew (bf16) + row sums Z; P = G @ Avo ---
    kern_G<<<BNR_, 256, 0, stream>>>(Ebuf, wbuf, Gb, Zb);
    bgemm<0><<<7 * 112, 256, 0, stream>>>(Gb, 1024, AvoT, 1024,
        BNR_, DD_, 1024, 1.f, P, DD_, nullptr, 0, nullptr, 7, 1);

    // --- LN1 ---
    kern_ln1<<<BNR_, 256, 0, stream>>>(img, word, P, Zb, co, g1, bt1, X1, X1b);

    // --- FFN (bf16 MFMA), LN2 ---
    // castTp: K-pad rows [812,832) of W1T/Wg1T are ZEROED (recycled ws bytes
    // can be bf16-NaN; 0*NaN=NaN poisoned round 3's FFN via the relu clamp).
    kern_castTp<<<(FF_ * KP_ + 255) / 256, 256, 0, stream>>>(W1, FF_, W1T, KP_, DD_, FF_, KP_);
    kern_castT<<<(FF_ * DD_ + 255) / 256, 256, 0, stream>>>(W2, DD_, W2T, FF_, FF_, DD_);
    bgemm<1><<<16 * 112, 256, 0, stream>>>(X1b, KP_, W1T, KP_,
        BNR_, FF_, KP_, 1.f, nullptr, 0, Hb, FF_, bf1, 16, 1);
    bgemm<2><<<7 * 112, 256, 0, stream>>>(Hb, FF_, W2T, FF_,
        BNR_, DD_, FF_, 1.f, X1, DD_, nullptr, 0, bf2, 7, 1);
    kern_ln2<<<BNR_, 256, 0, stream>>>(X1, g2, bt2, X2b);

    // --- GCN ---
    kern_castTp<<<(HID_ * KP_ + 255) / 256, 256, 0, stream>>>(Wg1, HID_, Wg1T, KP_, DD_, HID_, KP_);
    kern_castT<<<(HID_ * HID_ + 255) / 256, 256, 0, stream>>>(Wg2, HID_, Wg2T, HID_, HID_, HID_);
    bgemm<0><<<1 * 112, 256, 0, stream>>>(X2b, KP_, Wg1T, KP_,
        BNR_, HID_, KP_, 1.f, H1, HID_, nullptr, 0, nullptr, 1, 0);
    kern_agg1<<<(B_ * HID_) / 256, 256, 0, stream>>>(H1, Adj, bg1, G1b);
    bgemm<0><<<1 * 112, 256, 0, stream>>>(G1b, HID_, Wg2T, HID_,
        BNR_, HID_, HID_, 1.f, H2, HID_, nullptr, 0, nullptr, 1, 0);
    kern_agg2_pool<<<(B_ * HID_) / 256, 256, 0, stream>>>(H2, Adj, bg2, Pool);
    kern_lin<<<(B_ * CC_) / 256, 256, 0, stream>>>(Pool, Wl, bl, out);
}

// Round 5
// 746.018 us; speedup vs baseline: 3.2720x; 1.0321x over previous
//
#include <hip/hip_runtime.h>
#include <math.h>

// Problem constants
#define B_    1024
#define IMG_  512
#define TXT_  300
#define NN_   14
#define FF_   2048
#define HID_  128
#define CC_   14
#define EE_   182
#define DD_   812
#define D3_   2436
#define BNR_  14336          // B_*NN_
#define KP_   832            // 812 padded to /32 (16B-aligned rows)

typedef __bf16 bf16x8 __attribute__((ext_vector_type(8)));
typedef float  f32x4  __attribute__((ext_vector_type(4)));
typedef unsigned short u16;

__device__ __forceinline__ u16 f2bf(float f) {
    union { float f; unsigned u; } v; v.f = f;
    unsigned r = v.u + 0x7FFFu + ((v.u >> 16) & 1u);   // RNE
    return (u16)(r >> 16);
}

// async global->LDS, 16B per lane. LDS dst = wave-uniform base + lane*16.
__device__ __forceinline__ void gload_lds16(const u16* g, u16* l) {
    __builtin_amdgcn_global_load_lds(
        (const __attribute__((address_space(1))) void*)g,
        (__attribute__((address_space(3))) void*)l, 16, 0, 0);
}

// ---------------------------------------------------------------------------
// Workspace layout (bytes), time-multiplexed overlays.
// NOTE: any K-pad column read by a GEMM MUST be explicitly zeroed on BOTH
// operands — recycled workspace bytes can encode bf16 NaN, and 0*NaN=NaN.
// ---------------------------------------------------------------------------
#define OFF_P     0ULL
#define OFF_GB    46563328ULL
#define OFF_HB    0ULL
#define OFF_H1    0ULL
#define OFF_G1B   7340032ULL
#define OFF_H2    11010048ULL
#define OFF_POOL  18350080ULL
#define OFF_X1    75923456ULL
#define OFF_X1B   122486784ULL
#define OFF_SCR   146341888ULL
#define OFF_EBUF  (OFF_SCR)
#define OFF_WOB   (OFF_SCR + 4194304ULL)
#define OFF_AVOT  (OFF_SCR + 5685248ULL)
#define OFF_W1T   (OFF_SCR)
#define OFF_W2T   (OFF_SCR + 3407872ULL)
#define OFF_PERS  (OFF_SCR + 7520256ULL)   // 153862144
#define OFF_AQB   (OFF_PERS)
#define OFF_AKB   (OFF_PERS + 1703936ULL)
#define OFF_AVB   (OFF_PERS + 3407872ULL)
#define OFF_IMGB  (OFF_PERS + 5111808ULL)
#define OFF_WIB   (OFF_PERS + 6160384ULL)
#define OFF_TBUF  (OFF_PERS + 8781824ULL)
#define OFF_TQB   (OFF_PERS + 8918272ULL)
#define OFF_WBUF  (OFF_PERS + 9131264ULL)
#define OFF_CO    (OFF_PERS + 9188608ULL)
#define OFF_Z     (OFF_PERS + 9234176ULL)
#define OFF_ADJ   (OFF_PERS + 9291520ULL)
#define OFF_WG1T  (OFF_PERS + 9292544ULL)
#define OFF_WG2T  (OFF_PERS + 9505536ULL)

// ---------------------------------------------------------------------------
// bf16 MFMA GEMM: C[M,N] = scale * A[M,K] @ B^T (B stored [N][K]).
// 128x128 tile, BK=32, 4 waves (2x2 of 64x64), 16x16x32 MFMA.
// DOUBLE-BUFFERED global_load_lds staging (round-5 change): prefetch tile
// i+1 is issued BEFORE compute(i); the next iteration's __syncthreads()
// (implicit vmcnt(0)) drains it one full compute-phase later, so load
// latency overlaps MFMA+ds_read instead of serializing behind the barrier
// (round-4 shape exposed full latency every iter -> MfmaUtil 15%).
// Requirements unchanged: K%32==0, K-pads zeroed on BOTH operands, operand
// buffers allocated to 128-row multiples; M/N edges masked in epilogue.
// 1D grid; swiz=1 maps id%8 -> row-tile (XCD L2 reuse of A row-tiles).
// EPI 0: Cf=v. 1: Cb=bf16(relu(v+bias)). 2: Cf+=v+bias. 3: Cb=bf16(v).
// EPI 4: split-3 store into [Aq|Ak|Av], each [1024][KP_], contiguous.
// ---------------------------------------------------------------------------
template<int EPI>
__global__ __launch_bounds__(256)
void bgemm(const u16* __restrict__ A, int lda,
           const u16* __restrict__ Bm, int ldb,
           int M, int N, int K, float scale,
           float* __restrict__ Cf, int ldc,
           u16* __restrict__ Cb, int ldcb,
           const float* __restrict__ bias,
           int nxt, int swiz)
{
    __shared__ __align__(16) u16 As[2][128 * 32];
    __shared__ __align__(16) u16 Bs[2][128 * 32];
    const int tid = threadIdx.x;
    int bx, by;
    {
        int id = blockIdx.x;
        if (swiz) { int r8 = id & 7; int q = id >> 3; bx = q % nxt; by = (q / nxt) * 8 + r8; }
        else      { bx = id % nxt; by = id / nxt; }
    }
    const int row0 = by * 128, col0 = bx * 128;
    const int lane = tid & 63, wv = tid >> 6;
    const int wm = (wv >> 1) * 64, wn = (wv & 1) * 64;
    const int fr = lane & 15, qd = lane >> 4;

    // staging geometry (wave-uniform LDS base + lane*16, per global_load_lds)
    const int s_r0  = (wv * 64 + lane) >> 2;          // q=0 row
    const int s_ko  = (lane & 3) * 8;                 // k-offset (u16)
    const int s_b0  = (wv * 64) * 8;                  // q=0 LDS base (u16 idx)
    const u16* Arow0 = A  + (size_t)(row0 + s_r0) * lda + s_ko;
    const u16* Arow1 = A  + (size_t)(row0 + s_r0 + 64) * lda + s_ko;
    const u16* Brow0 = Bm + (size_t)(col0 + s_r0) * ldb + s_ko;
    const u16* Brow1 = Bm + (size_t)(col0 + s_r0 + 64) * ldb + s_ko;

    f32x4 acc[4][4] = {};

    const int T = K >> 5;
    // prologue: stage tile 0 into buffer 0
    gload_lds16(Arow0, &As[0][s_b0]);
    gload_lds16(Arow1, &As[0][s_b0 + 2048]);
    gload_lds16(Brow0, &Bs[0][s_b0]);
    gload_lds16(Brow1, &Bs[0][s_b0 + 2048]);

    for (int i = 0; i < T; ++i) {
        __syncthreads();   // drains tile-i loads (issued one compute-phase ago)
        const int cur = i & 1;
        if (i + 1 < T) {
            const int nxtb = cur ^ 1;
            const int ko = (i + 1) << 5;
            gload_lds16(Arow0 + ko, &As[nxtb][s_b0]);
            gload_lds16(Arow1 + ko, &As[nxtb][s_b0 + 2048]);
            gload_lds16(Brow0 + ko, &Bs[nxtb][s_b0]);
            gload_lds16(Brow1 + ko, &Bs[nxtb][s_b0 + 2048]);
        }
        bf16x8 af[4], bg[4];
        #pragma unroll
        for (int j = 0; j < 4; ++j) {
            af[j] = *(const bf16x8*)&As[cur][(wm + j * 16 + fr) * 32 + qd * 8];
            bg[j] = *(const bf16x8*)&Bs[cur][(wn + j * 16 + fr) * 32 + qd * 8];
        }
        #pragma unroll
        for (int mi = 0; mi < 4; ++mi)
            #pragma unroll
            for (int ni = 0; ni < 4; ++ni)
                acc[mi][ni] = __builtin_amdgcn_mfma_f32_16x16x32_bf16(
                    af[mi], bg[ni], acc[mi][ni], 0, 0, 0);
    }

    #pragma unroll
    for (int mi = 0; mi < 4; ++mi) {
        #pragma unroll
        for (int i = 0; i < 4; ++i) {
            int rm = row0 + wm + mi * 16 + qd * 4 + i;
            if (rm >= M) continue;
            #pragma unroll
            for (int ni = 0; ni < 4; ++ni) {
                int cn = col0 + wn + ni * 16 + fr;
                if (cn >= N) continue;
                float v = acc[mi][ni][i] * scale;
                if (EPI == 0) Cf[(size_t)rm * ldc + cn] = v;
                if (EPI == 1) { v += bias[cn]; v = v > 0.f ? v : 0.f;
                                Cb[(size_t)rm * ldcb + cn] = f2bf(v); }
                if (EPI == 2) { size_t ix = (size_t)rm * ldc + cn;
                                Cf[ix] = v + bias[cn] + Cf[ix]; }
                if (EPI == 3) Cb[(size_t)rm * ldcb + cn] = f2bf(v);
                if (EPI == 4) { int bs = cn / DD_, cc = cn - bs * DD_;
                                Cb[(size_t)bs * (1024 * KP_) + (size_t)rm * KP_ + cc] = f2bf(v); }
            }
        }
    }
}

// fp32->bf16 cast: dst[r*drs+c] = (c<scols) ? src[r*srs+c] : 0, c < dcols
__global__ void kern_cast(const float* __restrict__ src, int srs,
                          u16* __restrict__ dst, int drs, int rows, int dcols, int scols)
{
    int idx = blockIdx.x * 256 + threadIdx.x;
    if (idx >= rows * dcols) return;
    int r = idx / dcols, c = idx - r * dcols;
    dst[(size_t)r * drs + c] = (c < scols) ? f2bf(src[(size_t)r * srs + c]) : (u16)0;
}

// fp32->bf16 cast-transpose: dst[c*drs+r] = src[r*srs+c]
__global__ void kern_castT(const float* __restrict__ src, int srs,
                           u16* __restrict__ dst, int drs, int rows, int cols)
{
    int idx = blockIdx.x * 256 + threadIdx.x;
    if (idx >= rows * cols) return;
    int c = idx / rows, r = idx - c * rows;
    dst[(size_t)c * drs + r] = f2bf(src[(size_t)r * srs + c]);
}

// cast-transpose with zero K-pad rows [rows, padr)
__global__ void kern_castTp(const float* __restrict__ src, int srs,
                            u16* __restrict__ dst, int drs, int rows, int cols, int padr)
{
    int idx = blockIdx.x * 256 + threadIdx.x;
    if (idx >= cols * padr) return;
    int c = idx / padr, r = idx - c * padr;
    dst[(size_t)c * drs + r] = (r < rows) ? f2bf(src[(size_t)r * srs + c]) : (u16)0;
}

// zero K-pad cols [812,832) of Aq/Ak/Av (contiguous [3][1024][KP_])
__global__ void kern_zeropad(u16* __restrict__ Aq)
{
    int idx = blockIdx.x * 256 + threadIdx.x;
    if (idx >= 3 * 1024 * 20) return;
    int w = idx / (1024 * 20), rem = idx - w * (1024 * 20);
    int r = rem / 20, c = rem - r * 20;
    Aq[(size_t)w * (1024 * KP_) + (size_t)r * KP_ + DD_ + c] = 0;
}

// T[n,r] = in_proj_b[r] + word[n,:] . in_proj_w[r, 512:812]
__global__ void kern_T(const float* __restrict__ word, const float* __restrict__ W,
                       const float* __restrict__ bias, float* __restrict__ T)
{
    int idx = blockIdx.x * 256 + threadIdx.x;
    if (idx >= NN_ * D3_) return;
    int n = idx / D3_, r = idx % D3_;
    const float* wr = word + n * TXT_;
    const float* Wr = W + (size_t)r * DD_ + IMG_;
    float s = bias[r];
    for (int c = 0; c < TXT_; ++c) s = fmaf(wr[c], Wr[c], s);
    T[idx] = s;
}

// Dense 14x14 GCN adjacency (self-loops + symmetric norm)
__global__ void kern_adj(const int* __restrict__ ei, float* __restrict__ Adj)
{
    if (threadIdx.x != 0 || blockIdx.x != 0) return;
    float deg[NN_];
    for (int i = 0; i < NN_; ++i) deg[i] = 1.f;
    for (int e = 0; e < EE_; ++e) deg[ei[EE_ + e]] += 1.f;
    float dinv[NN_];
    for (int i = 0; i < NN_; ++i) dinv[i] = rsqrtf(deg[i]);
    float adj[NN_ * NN_];
    for (int t = 0; t < NN_ * NN_; ++t) adj[t] = 0.f;
    for (int e = 0; e < EE_; ++e) {
        int s = ei[e], d = ei[EE_ + e];
        adj[d * NN_ + s] += dinv[s] * dinv[d];
    }
    for (int i = 0; i < NN_; ++i) adj[i * NN_ + i] += dinv[i] * dinv[i];
    for (int t = 0; t < NN_ * NN_; ++t) Adj[t] = adj[t];
}

// row -> exp(row - rowmax), rows of length 1024, in place
__global__ __launch_bounds__(256) void kern_exp_rows(float* __restrict__ S)
{
    __shared__ float red[256];
    float* row = S + (size_t)blockIdx.x * 1024;
    float m = -1e30f;
    for (int i = threadIdx.x; i < 1024; i += 256) m = fmaxf(m, row[i]);
    red[threadIdx.x] = m; __syncthreads();
    for (int s = 128; s > 0; s >>= 1) {
        if (threadIdx.x < s) red[threadIdx.x] = fmaxf(red[threadIdx.x], red[threadIdx.x + s]);
        __syncthreads();
    }
    m = red[0];
    for (int i = threadIdx.x; i < 1024; i += 256) row[i] = expf(row[i] - m);
}

// co[n,d] = out_proj_b[d] + Tv[n,:] . Wo[d,:]
__global__ void kern_co(const float* __restrict__ T, const float* __restrict__ Wo,
                        const float* __restrict__ bo, float* __restrict__ co)
{
    int idx = blockIdx.x * 256 + threadIdx.x;
    if (idx >= NN_ * DD_) return;
    int n = idx / DD_, d = idx % DD_;
    const float* Tv = T + n * D3_ + 2 * DD_;
    const float* wr = Wo + (size_t)d * DD_;
    float s = bo[d];
    for (int c = 0; c < DD_; ++c) s = fmaf(Tv[c], wr[c], s);
    co[idx] = s;
}

// G[row=l*14+z, m] = E[l,m]*ew[z,m] -> bf16; Z[row] = sum_m (fp32)
__global__ __launch_bounds__(256) void kern_G(const float* __restrict__ E,
    const float* __restrict__ EW, u16* __restrict__ Gb, float* __restrict__ Z)
{
    __shared__ float red[256];
    int row = blockIdx.x;
    int l = row / NN_, z = row - l * NN_;
    const float* er = E + (size_t)l * 1024;
    const float* wr = EW + (size_t)z * 1024;
    float s = 0.f;
    for (int m = threadIdx.x; m < 1024; m += 256) {
        float g = er[m] * wr[m];
        Gb[(size_t)row * 1024 + m] = f2bf(g);
        s += g;
    }
    red[threadIdx.x] = s; __syncthreads();
    for (int t = 128; t > 0; t >>= 1) {
        if (threadIdx.x < t) red[threadIdx.x] += red[threadIdx.x + t];
        __syncthreads();
    }
    if (threadIdx.x == 0) Z[row] = red[0];
}

// x1 = LN1(node + P/Z + co); writes fp32 X1 and bf16 X1b (pad cols zeroed)
__global__ __launch_bounds__(256) void kern_ln1(
    const float* __restrict__ img, const float* __restrict__ word,
    const float* __restrict__ P, const float* __restrict__ Z,
    const float* __restrict__ co, const float* __restrict__ g,
    const float* __restrict__ bta, float* __restrict__ X, u16* __restrict__ Xb)
{
    __shared__ float buf[DD_];
    __shared__ float red[256];
    __shared__ float stats[2];
    int row = blockIdx.x;
    int b = row / NN_, n = row - b * NN_;
    float invZ = 1.f / Z[row];
    const float* pr = P + (size_t)row * DD_;
    const float* cr = co + n * DD_;
    float s = 0.f;
    for (int d = threadIdx.x; d < DD_; d += 256) {
        float v = (d < IMG_) ? img[(size_t)b * IMG_ + d] : word[n * TXT_ + d - IMG_];
        v += pr[d] * invZ + cr[d];
        buf[d] = v; s += v;
    }
    red[threadIdx.x] = s; __syncthreads();
    for (int t = 128; t > 0; t >>= 1) {
        if (threadIdx.x < t) red[threadIdx.x] += red[threadIdx.x + t];
        __syncthreads();
    }
    if (threadIdx.x == 0) stats[0] = red[0] / DD_;
    __syncthreads();
    float mu = stats[0], s2 = 0.f;
    for (int d = threadIdx.x; d < DD_; d += 256) { float t = buf[d] - mu; s2 += t * t; }
    red[threadIdx.x] = s2; __syncthreads();
    for (int t = 128; t > 0; t >>= 1) {
        if (threadIdx.x < t) red[threadIdx.x] += red[threadIdx.x + t];
        __syncthreads();
    }
    if (threadIdx.x == 0) stats[1] = rsqrtf(red[0] / DD_ + 1e-5f);
    __syncthreads();
    float rstd = stats[1];
    float* xr = X + (size_t)row * DD_;
    u16* xb = Xb + (size_t)row * KP_;
    for (int d = threadIdx.x; d < DD_; d += 256) {
        float v = (buf[d] - mu) * rstd * g[d] + bta[d];
        xr[d] = v; xb[d] = f2bf(v);
    }
    for (int d = DD_ + threadIdx.x; d < KP_; d += 256) xb[d] = 0;
}

// in-place LN2 on fp32 X; writes bf16 X2b (pad cols zeroed)
__global__ __launch_bounds__(256) void kern_ln2(float* __restrict__ X,
    const float* __restrict__ g, const float* __restrict__ bta, u16* __restrict__ Xb)
{
    __shared__ float buf[DD_];
    __shared__ float red[256];
    __shared__ float stats[2];
    float* xr = X + (size_t)blockIdx.x * DD_;
    float s = 0.f;
    for (int d = threadIdx.x; d < DD_; d += 256) { float v = xr[d]; buf[d] = v; s += v; }
    red[threadIdx.x] = s; __syncthreads();
    for (int t = 128; t > 0; t >>= 1) {
        if (threadIdx.x < t) red[threadIdx.x] += red[threadIdx.x + t];
        __syncthreads();
    }
    if (threadIdx.x == 0) stats[0] = red[0] / DD_;
    __syncthreads();
    float mu = stats[0], s2 = 0.f;
    for (int d = threadIdx.x; d < DD_; d += 256) { float t = buf[d] - mu; s2 += t * t; }
    red[threadIdx.x] = s2; __syncthreads();
    for (int t = 128; t > 0; t >>= 1) {
        if (threadIdx.x < t) red[threadIdx.x] += red[threadIdx.x + t];
        __syncthreads();
    }
    if (threadIdx.x == 0) stats[1] = rsqrtf(red[0] / DD_ + 1e-5f);
    __syncthreads();
    float rstd = stats[1];
    u16* xb = Xb + (size_t)blockIdx.x * KP_;
    for (int d = threadIdx.x; d < DD_; d += 256) {
        float v = (buf[d] - mu) * rstd * g[d] + bta[d];
        xr[d] = v; xb[d] = f2bf(v);
    }
    for (int d = DD_ + threadIdx.x; d < KP_; d += 256) xb[d] = 0;
}

// g1 = relu(Adj @ h1 + bias) -> bf16
__global__ __launch_bounds__(256) void kern_agg1(const float* __restrict__ H,
    const float* __restrict__ Adj, const float* __restrict__ bias, u16* __restrict__ G)
{
    __shared__ float sA[NN_ * NN_];
    if (threadIdx.x < NN_ * NN_) sA[threadIdx.x] = Adj[threadIdx.x];
    __syncthreads();
    int t = blockIdx.x * 256 + threadIdx.x;
    int b = t >> 7, f = t & 127;
    float v[NN_];
    #pragma unroll
    for (int i = 0; i < NN_; ++i) v[i] = H[((size_t)b * NN_ + i) * HID_ + f];
    float bb = bias[f];
    #pragma unroll
    for (int j = 0; j < NN_; ++j) {
        float s = bb;
        #pragma unroll
        for (int i = 0; i < NN_; ++i) s = fmaf(sA[j * NN_ + i], v[i], s);
        G[((size_t)b * NN_ + j) * HID_ + f] = f2bf(s > 0.f ? s : 0.f);
    }
}

// pool = relu(mean_j(Adj @ h2 + bias))
__global__ __launch_bounds__(256) void kern_agg2_pool(const float* __restrict__ H,
    const float* __restrict__ Adj, const float* __restrict__ bias, float* __restrict__ P)
{
    __shared__ float sA[NN_ * NN_];
    if (threadIdx.x < NN_ * NN_) sA[threadIdx.x] = Adj[threadIdx.x];
    __syncthreads();
    int t = blockIdx.x * 256 + threadIdx.x;
    int b = t >> 7, f = t & 127;
    float v[NN_];
    #pragma unroll
    for (int i = 0; i < NN_; ++i) v[i] = H[((size_t)b * NN_ + i) * HID_ + f];
    float acc = 0.f;
    #pragma unroll
    for (int j = 0; j < NN_; ++j) {
        float s = 0.f;
        #pragma unroll
        for (int i = 0; i < NN_; ++i) s = fmaf(sA[j * NN_ + i], v[i], s);
        acc += s;
    }
    acc = acc / (float)NN_ + bias[f];
    P[(size_t)b * HID_ + f] = acc > 0.f ? acc : 0.f;
}

__global__ void kern_lin(const float* __restrict__ pool, const float* __restrict__ W,
                         const float* __restrict__ bias, float* __restrict__ out)
{
    int t = blockIdx.x * 256 + threadIdx.x;
    if (t >= B_ * CC_) return;
    int b = t / CC_, c = t % CC_;
    float s = bias[c];
    const float* pr = pool + (size_t)b * HID_;
    for (int f = 0; f < HID_; ++f) s = fmaf(pr[f], W[f * CC_ + c], s);
    out[t] = s;
}

extern "C" void kernel_launch(void* const* d_in, const int* in_sizes, int n_in,
                              void* d_out, int out_size, void* d_ws, size_t ws_size,
                              hipStream_t stream)
{
    const float* img  = (const float*)d_in[0];
    const float* word = (const float*)d_in[1];
    const int*   ei   = (const int*)d_in[2];
    const float* Wi   = (const float*)d_in[3];
    const float* bi   = (const float*)d_in[4];
    const float* Wo   = (const float*)d_in[5];
    const float* bo   = (const float*)d_in[6];
    const float* g1   = (const float*)d_in[7];
    const float* bt1  = (const float*)d_in[8];
    const float* g2   = (const float*)d_in[9];
    const float* bt2  = (const float*)d_in[10];
    const float* W1   = (const float*)d_in[11];
    const float* bf1  = (const float*)d_in[12];
    const float* W2   = (const float*)d_in[13];
    const float* bf2  = (const float*)d_in[14];
    const float* Wg1  = (const float*)d_in[15];
    const float* bg1  = (const float*)d_in[16];
    const float* Wg2  = (const float*)d_in[17];
    const float* bg2  = (const float*)d_in[18];
    const float* Wl   = (const float*)d_in[19];
    const float* bl   = (const float*)d_in[20];
    float* out = (float*)d_out;

    char* ws = (char*)d_ws;
    float* P    = (float*)(ws + OFF_P);
    u16*   Gb   = (u16*)  (ws + OFF_GB);
    u16*   Hb   = (u16*)  (ws + OFF_HB);
    float* H1   = (float*)(ws + OFF_H1);
    u16*   G1b  = (u16*)  (ws + OFF_G1B);
    float* H2   = (float*)(ws + OFF_H2);
    float* Pool = (float*)(ws + OFF_POOL);
    float* X1   = (float*)(ws + OFF_X1);
    u16*   X1b  = (u16*)  (ws + OFF_X1B);
    u16*   X2b  = (u16*)  (ws + OFF_X1B);
    float* Ebuf = (float*)(ws + OFF_EBUF);
    u16*   Wob  = (u16*)  (ws + OFF_WOB);
    u16*   AvoT = (u16*)  (ws + OFF_AVOT);
    u16*   W1T  = (u16*)  (ws + OFF_W1T);
    u16*   W2T  = (u16*)  (ws + OFF_W2T);
    u16*   Aqb  = (u16*)  (ws + OFF_AQB);
    u16*   Akb  = (u16*)  (ws + OFF_AKB);
    u16*   Avb  = (u16*)  (ws + OFF_AVB);
    u16*   imgb = (u16*)  (ws + OFF_IMGB);
    u16*   Wib  = (u16*)  (ws + OFF_WIB);
    float* Tbuf = (float*)(ws + OFF_TBUF);
    u16*   Tqb  = (u16*)  (ws + OFF_TQB);
    float* wbuf = (float*)(ws + OFF_WBUF);
    float* co   = (float*)(ws + OFF_CO);
    float* Zb   = (float*)(ws + OFF_Z);
    float* Adj  = (float*)(ws + OFF_ADJ);
    u16*   Wg1T = (u16*)  (ws + OFF_WG1T);
    u16*   Wg2T = (u16*)  (ws + OFF_WG2T);

    const float scl = 1.0f / sqrtf((float)DD_);

    // --- small precompute + casts ---
    kern_T<<<(NN_ * D3_ + 255) / 256, 256, 0, stream>>>(word, Wi, bi, Tbuf);
    kern_adj<<<1, 64, 0, stream>>>(ei, Adj);
    kern_cast<<<(B_ * IMG_ + 255) / 256, 256, 0, stream>>>(img, IMG_, imgb, IMG_, B_, IMG_, IMG_);
    kern_cast<<<(D3_ * IMG_ + 255) / 256, 256, 0, stream>>>(Wi, DD_, Wib, IMG_, D3_, IMG_, IMG_);
    kern_cast<<<(NN_ * KP_ + 255) / 256, 256, 0, stream>>>(Tbuf, D3_, Tqb, KP_, NN_, KP_, DD_);
    kern_cast<<<(DD_ * KP_ + 255) / 256, 256, 0, stream>>>(Wo, DD_, Wob, KP_, DD_, KP_, DD_);

    // --- A-proj: [Aq|Ak|Av] = img @ Wi[:, :512]^T (split-3 bf16), then zero K-pads
    bgemm<4><<<20 * 8, 256, 0, stream>>>(imgb, IMG_, Wib, IMG_,
        B_, D3_, IMG_, 1.f, nullptr, 0, Aqb, 0, nullptr, 20, 1);
    kern_zeropad<<<240, 256, 0, stream>>>(Aqb);

    // --- S0 = scl*Aq@Ak^T ; w = scl*Tq@Ak^T ; exp both ---
    bgemm<0><<<8 * 8, 256, 0, stream>>>(Aqb, KP_, Akb, KP_,
        B_, B_, KP_, scl, Ebuf, 1024, nullptr, 0, nullptr, 8, 1);
    bgemm<0><<<8 * 1, 256, 0, stream>>>(Tqb, KP_, Akb, KP_,
        NN_, B_, KP_, scl, wbuf, 1024, nullptr, 0, nullptr, 8, 0);
    kern_exp_rows<<<1024, 256, 0, stream>>>(Ebuf);
    kern_exp_rows<<<NN_, 256, 0, stream>>>(wbuf);   // wbuf -> ew

    // --- AvoT[d,m] = (Av @ Wo^T)^T ; co = n-only part ---
    bgemm<3><<<8 * 7, 256, 0, stream>>>(Wob, KP_, Avb, KP_,
        DD_, B_, KP_, 1.f, nullptr, 0, AvoT, 1024, nullptr, 8, 0);
    kern_co<<<(NN_ * DD_ + 255) / 256, 256, 0, stream>>>(Tbuf, Wo, bo, co);

    // --- G = E*ew (bf16) + row sums Z; P = G @ Avo ---
    kern_G<<<BNR_, 256, 0, stream>>>(Ebuf, wbuf, Gb, Zb);
    bgemm<0><<<7 * 112, 256, 0, stream>>>(Gb, 1024, AvoT, 1024,
        BNR_, DD_, 1024, 1.f, P, DD_, nullptr, 0, nullptr, 7, 1);

    // --- LN1 ---
    kern_ln1<<<BNR_, 256, 0, stream>>>(img, word, P, Zb, co, g1, bt1, X1, X1b);

    // --- FFN (bf16 MFMA), LN2 ---
    kern_castTp<<<(FF_ * KP_ + 255) / 256, 256, 0, stream>>>(W1, FF_, W1T, KP_, DD_, FF_, KP_);
    kern_castT<<<(FF_ * DD_ + 255) / 256, 256, 0, stream>>>(W2, DD_, W2T, FF_, FF_, DD_);
    bgemm<1><<<16 * 112, 256, 0, stream>>>(X1b, KP_, W1T, KP_,
        BNR_, FF_, KP_, 1.f, nullptr, 0, Hb, FF_, bf1, 16, 1);
    bgemm<2><<<7 * 112, 256, 0, stream>>>(Hb, FF_, W2T, FF_,
        BNR_, DD_, FF_, 1.f, X1, DD_, nullptr, 0, bf2, 7, 1);
    kern_ln2<<<BNR_, 256, 0, stream>>>(X1, g2, bt2, X2b);

    // --- GCN ---
    kern_castTp<<<(HID_ * KP_ + 255) / 256, 256, 0, stream>>>(Wg1, HID_, Wg1T, KP_, DD_, HID_, KP_);
    kern_castT<<<(HID_ * HID_ + 255) / 256, 256, 0, stream>>>(Wg2, HID_, Wg2T, HID_, HID_, HID_);
    bgemm<0><<<1 * 112, 256, 0, stream>>>(X2b, KP_, Wg1T, KP_,
        BNR_, HID_, KP_, 1.f, H1, HID_, nullptr, 0, nullptr, 1, 0);
    kern_agg1<<<(B_ * HID_) / 256, 256, 0, stream>>>(H1, Adj, bg1, G1b);
    bgemm<0><<<1 * 112, 256, 0, stream>>>(G1b, HID_, Wg2T, HID_,
        BNR_, HID_, HID_, 1.f, H2, HID_, nullptr, 0, nullptr, 1, 0);
    kern_agg2_pool<<<(B_ * HID_) / 256, 256, 0, stream>>>(H2, Adj, bg2, Pool);
    kern_lin<<<(B_ * CC_) / 256, 256, 0, stream>>>(Pool, Wl, bl, out);
}

// Round 6
// 669.224 us; speedup vs baseline: 3.6474x; 1.1147x over previous
//
#include <hip/hip_runtime.h>
#include <math.h>

// Problem constants
#define B_    1024
#define IMG_  512
#define TXT_  300
#define NN_   14
#define FF_   2048
#define HID_  128
#define CC_   14
#define EE_   182
#define DD_   812
#define D3_   2436
#define BNR_  14336          // B_*NN_
#define KP_   832            // 812 padded to /32 (16B-aligned rows)

typedef __bf16 bf16x8 __attribute__((ext_vector_type(8)));
typedef float  f32x4  __attribute__((ext_vector_type(4)));
typedef unsigned short u16;

__device__ __forceinline__ u16 f2bf(float f) {
    union { float f; unsigned u; } v; v.f = f;
    unsigned r = v.u + 0x7FFFu + ((v.u >> 16) & 1u);   // RNE
    return (u16)(r >> 16);
}
__device__ __forceinline__ float bf2f(u16 h) {
    union { unsigned u; float f; } v; v.u = ((unsigned)h) << 16; return v.f;
}

// async global->LDS, 16B per lane. LDS dst = wave-uniform base + lane*16.
__device__ __forceinline__ void gload_lds16(const u16* g, u16* l) {
    __builtin_amdgcn_global_load_lds(
        (const __attribute__((address_space(1))) void*)g,
        (__attribute__((address_space(3))) void*)l, 16, 0, 0);
}

// ---------------------------------------------------------------------------
// Workspace layout (bytes), time-multiplexed overlays.
// NOTE: any K-pad column read by a GEMM MUST be explicitly zeroed on BOTH
// operands — recycled workspace bytes can encode bf16 NaN, and 0*NaN=NaN.
// ---------------------------------------------------------------------------
#define OFF_P     0ULL                 // Pb bf16 [BNR_][DD_] = 23.3MB (phase1)
#define OFF_GB    46563328ULL
#define OFF_HB    0ULL
#define OFF_H1    0ULL
#define OFF_G1B   7340032ULL
#define OFF_H2    11010048ULL
#define OFF_POOL  18350080ULL
#define OFF_X1    75923456ULL          // Yf fp32 [BNR_][DD_] (FFN2 out)
#define OFF_X1B   122486784ULL         // X1b / X2b bf16 [BNR_][KP_]
#define OFF_SCR   146341888ULL
#define OFF_EBUF  (OFF_SCR)
#define OFF_WOB   (OFF_SCR + 4194304ULL)
#define OFF_AVOT  (OFF_SCR + 5685248ULL)
#define OFF_W1T   (OFF_SCR)
#define OFF_W2T   (OFF_SCR + 3407872ULL)
#define OFF_PERS  (OFF_SCR + 7520256ULL)   // 153862144
#define OFF_AQB   (OFF_PERS)
#define OFF_AKB   (OFF_PERS + 1703936ULL)
#define OFF_AVB   (OFF_PERS + 3407872ULL)
#define OFF_IMGB  (OFF_PERS + 5111808ULL)
#define OFF_WIB   (OFF_PERS + 6160384ULL)
#define OFF_TBUF  (OFF_PERS + 8781824ULL)
#define OFF_TQB   (OFF_PERS + 8918272ULL)
#define OFF_WBUF  (OFF_PERS + 9131264ULL)
#define OFF_CO    (OFF_PERS + 9188608ULL)
#define OFF_Z     (OFF_PERS + 9234176ULL)
#define OFF_ADJ   (OFF_PERS + 9291520ULL)
#define OFF_WG1T  (OFF_PERS + 9292544ULL)
#define OFF_WG2T  (OFF_PERS + 9505536ULL)

// ---------------------------------------------------------------------------
// bf16 MFMA GEMM: C[M,N] = scale * A[M,K] @ B^T (B stored [N][K]).
// 128x128 tile, BK=32, 4 waves (2x2 of 64x64), 16x16x32 MFMA, double-buffered
// global_load_lds staging. __launch_bounds__(256,4) caps regs at 128/wave so
// 4 blocks/CU are resident (round-5: 72 VGPR + 64 AGPR = 136 -> only 3).
// Requirements: K%32==0, K-pads zeroed on BOTH operands, operand buffers
// allocated to 128-row multiples; M/N edges masked in epilogue.
// 1D grid; swiz=1 maps id%8 -> row-tile (XCD L2 reuse of A row-tiles).
// EPI 0: Cf=v. 1: Cb=bf16(relu(v+bias[cn])). 2: Cf=v+bias[cn]+bf2f(Cb) (Cb=resid IN).
// EPI 3: Cb=bf16(v). 4: split-3 store into [Aq|Ak|Av]. 5: Cb=bf16(v/bias[rm]).
// ---------------------------------------------------------------------------
template<int EPI>
__global__ __launch_bounds__(256, 4)
void bgemm(const u16* __restrict__ A, int lda,
           const u16* __restrict__ Bm, int ldb,
           int M, int N, int K, float scale,
           float* __restrict__ Cf, int ldc,
           u16* __restrict__ Cb, int ldcb,
           const float* __restrict__ bias,
           int nxt, int swiz)
{
    __shared__ __align__(16) u16 As[2][128 * 32];
    __shared__ __align__(16) u16 Bs[2][128 * 32];
    const int tid = threadIdx.x;
    int bx, by;
    {
        int id = blockIdx.x;
        if (swiz) { int r8 = id & 7; int q = id >> 3; bx = q % nxt; by = (q / nxt) * 8 + r8; }
        else      { bx = id % nxt; by = id / nxt; }
    }
    const int row0 = by * 128, col0 = bx * 128;
    const int lane = tid & 63, wv = tid >> 6;
    const int wm = (wv >> 1) * 64, wn = (wv & 1) * 64;
    const int fr = lane & 15, qd = lane >> 4;

    // staging geometry (wave-uniform LDS base + lane*16, per global_load_lds)
    const int s_r0  = (wv * 64 + lane) >> 2;          // q=0 row
    const int s_ko  = (lane & 3) * 8;                 // k-offset (u16)
    const int s_b0  = (wv * 64) * 8;                  // q=0 LDS base (u16 idx)
    const u16* Arow0 = A  + (size_t)(row0 + s_r0) * lda + s_ko;
    const u16* Arow1 = A  + (size_t)(row0 + s_r0 + 64) * lda + s_ko;
    const u16* Brow0 = Bm + (size_t)(col0 + s_r0) * ldb + s_ko;
    const u16* Brow1 = Bm + (size_t)(col0 + s_r0 + 64) * ldb + s_ko;

    f32x4 acc[4][4] = {};

    const int T = K >> 5;
    gload_lds16(Arow0, &As[0][s_b0]);
    gload_lds16(Arow1, &As[0][s_b0 + 2048]);
    gload_lds16(Brow0, &Bs[0][s_b0]);
    gload_lds16(Brow1, &Bs[0][s_b0 + 2048]);

    for (int i = 0; i < T; ++i) {
        __syncthreads();   // drains tile-i loads (issued one compute-phase ago)
        const int cur = i & 1;
        if (i + 1 < T) {
            const int nxtb = cur ^ 1;
            const int ko = (i + 1) << 5;
            gload_lds16(Arow0 + ko, &As[nxtb][s_b0]);
            gload_lds16(Arow1 + ko, &As[nxtb][s_b0 + 2048]);
            gload_lds16(Brow0 + ko, &Bs[nxtb][s_b0]);
            gload_lds16(Brow1 + ko, &Bs[nxtb][s_b0 + 2048]);
        }
        bf16x8 af[4], bg[4];
        #pragma unroll
        for (int j = 0; j < 4; ++j) {
            af[j] = *(const bf16x8*)&As[cur][(wm + j * 16 + fr) * 32 + qd * 8];
            bg[j] = *(const bf16x8*)&Bs[cur][(wn + j * 16 + fr) * 32 + qd * 8];
        }
        #pragma unroll
        for (int mi = 0; mi < 4; ++mi)
            #pragma unroll
            for (int ni = 0; ni < 4; ++ni)
                acc[mi][ni] = __builtin_amdgcn_mfma_f32_16x16x32_bf16(
                    af[mi], bg[ni], acc[mi][ni], 0, 0, 0);
    }

    #pragma unroll
    for (int mi = 0; mi < 4; ++mi) {
        #pragma unroll
        for (int i = 0; i < 4; ++i) {
            int rm = row0 + wm + mi * 16 + qd * 4 + i;
            if (rm >= M) continue;
            #pragma unroll
            for (int ni = 0; ni < 4; ++ni) {
                int cn = col0 + wn + ni * 16 + fr;
                if (cn >= N) continue;
                float v = acc[mi][ni][i] * scale;
                if (EPI == 0) Cf[(size_t)rm * ldc + cn] = v;
                if (EPI == 1) { v += bias[cn]; v = v > 0.f ? v : 0.f;
                                Cb[(size_t)rm * ldcb + cn] = f2bf(v); }
                if (EPI == 2) Cf[(size_t)rm * ldc + cn] =
                                v + bias[cn] + bf2f(Cb[(size_t)rm * ldcb + cn]);
                if (EPI == 3) Cb[(size_t)rm * ldcb + cn] = f2bf(v);
                if (EPI == 4) { int bs = cn / DD_, cc = cn - bs * DD_;
                                Cb[(size_t)bs * (1024 * KP_) + (size_t)rm * KP_ + cc] = f2bf(v); }
                if (EPI == 5) { float invz = 1.0f / bias[rm];
                                Cb[(size_t)rm * ldcb + cn] = f2bf(v * invz); }
            }
        }
    }
}

// fp32->bf16 cast: dst[r*drs+c] = (c<scols) ? src[r*srs+c] : 0, c < dcols
__global__ void kern_cast(const float* __restrict__ src, int srs,
                          u16* __restrict__ dst, int drs, int rows, int dcols, int scols)
{
    int idx = blockIdx.x * 256 + threadIdx.x;
    if (idx >= rows * dcols) return;
    int r = idx / dcols, c = idx - r * dcols;
    dst[(size_t)r * drs + c] = (c < scols) ? f2bf(src[(size_t)r * srs + c]) : (u16)0;
}

// fp32->bf16 cast-transpose: dst[c*drs+r] = src[r*srs+c]
__global__ void kern_castT(const float* __restrict__ src, int srs,
                           u16* __restrict__ dst, int drs, int rows, int cols)
{
    int idx = blockIdx.x * 256 + threadIdx.x;
    if (idx >= rows * cols) return;
    int c = idx / rows, r = idx - c * rows;
    dst[(size_t)c * drs + r] = f2bf(src[(size_t)r * srs + c]);
}

// cast-transpose with zero K-pad rows [rows, padr)
__global__ void kern_castTp(const float* __restrict__ src, int srs,
                            u16* __restrict__ dst, int drs, int rows, int cols, int padr)
{
    int idx = blockIdx.x * 256 + threadIdx.x;
    if (idx >= cols * padr) return;
    int c = idx / padr, r = idx - c * padr;
    dst[(size_t)c * drs + r] = (r < rows) ? f2bf(src[(size_t)r * srs + c]) : (u16)0;
}

// zero K-pad cols [812,832) of Aq/Ak/Av (contiguous [3][1024][KP_])
__global__ void kern_zeropad(u16* __restrict__ Aq)
{
    int idx = blockIdx.x * 256 + threadIdx.x;
    if (idx >= 3 * 1024 * 20) return;
    int w = idx / (1024 * 20), rem = idx - w * (1024 * 20);
    int r = rem / 20, c = rem - r * 20;
    Aq[(size_t)w * (1024 * KP_) + (size_t)r * KP_ + DD_ + c] = 0;
}

// T[n,r] = in_proj_b[r] + word[n,:] . in_proj_w[r, 512:812]
__global__ void kern_T(const float* __restrict__ word, const float* __restrict__ W,
                       const float* __restrict__ bias, float* __restrict__ T)
{
    int idx = blockIdx.x * 256 + threadIdx.x;
    if (idx >= NN_ * D3_) return;
    int n = idx / D3_, r = idx % D3_;
    const float* wr = word + n * TXT_;
    const float* Wr = W + (size_t)r * DD_ + IMG_;
    float s = bias[r];
    for (int c = 0; c < TXT_; ++c) s = fmaf(wr[c], Wr[c], s);
    T[idx] = s;
}

// Dense 14x14 GCN adjacency (self-loops + symmetric norm)
__global__ void kern_adj(const int* __restrict__ ei, float* __restrict__ Adj)
{
    if (threadIdx.x != 0 || blockIdx.x != 0) return;
    float deg[NN_];
    for (int i = 0; i < NN_; ++i) deg[i] = 1.f;
    for (int e = 0; e < EE_; ++e) deg[ei[EE_ + e]] += 1.f;
    float dinv[NN_];
    for (int i = 0; i < NN_; ++i) dinv[i] = rsqrtf(deg[i]);
    float adj[NN_ * NN_];
    for (int t = 0; t < NN_ * NN_; ++t) adj[t] = 0.f;
    for (int e = 0; e < EE_; ++e) {
        int s = ei[e], d = ei[EE_ + e];
        adj[d * NN_ + s] += dinv[s] * dinv[d];
    }
    for (int i = 0; i < NN_; ++i) adj[i * NN_ + i] += dinv[i] * dinv[i];
    for (int t = 0; t < NN_ * NN_; ++t) Adj[t] = adj[t];
}

// row -> exp(row - rowmax), rows of length 1024, in place
__global__ __launch_bounds__(256) void kern_exp_rows(float* __restrict__ S)
{
    __shared__ float red[256];
    float* row = S + (size_t)blockIdx.x * 1024;
    float m = -1e30f;
    for (int i = threadIdx.x; i < 1024; i += 256) m = fmaxf(m, row[i]);
    red[threadIdx.x] = m; __syncthreads();
    for (int s = 128; s > 0; s >>= 1) {
        if (threadIdx.x < s) red[threadIdx.x] = fmaxf(red[threadIdx.x], red[threadIdx.x + s]);
        __syncthreads();
    }
    m = red[0];
    for (int i = threadIdx.x; i < 1024; i += 256) row[i] = expf(row[i] - m);
}

// co[n,d] = out_proj_b[d] + Tv[n,:] . Wo[d,:]
__global__ void kern_co(const float* __restrict__ T, const float* __restrict__ Wo,
                        const float* __restrict__ bo, float* __restrict__ co)
{
    int idx = blockIdx.x * 256 + threadIdx.x;
    if (idx >= NN_ * DD_) return;
    int n = idx / DD_, d = idx % DD_;
    const float* Tv = T + n * D3_ + 2 * DD_;
    const float* wr = Wo + (size_t)d * DD_;
    float s = bo[d];
    for (int c = 0; c < DD_; ++c) s = fmaf(Tv[c], wr[c], s);
    co[idx] = s;
}

// G[row=l*14+z, m] = E[l,m]*ew[z,m] -> bf16; Z[row] = sum_m (fp32)
__global__ __launch_bounds__(256) void kern_G(const float* __restrict__ E,
    const float* __restrict__ EW, u16* __restrict__ Gb, float* __restrict__ Z)
{
    __shared__ float red[256];
    int row = blockIdx.x;
    int l = row / NN_, z = row - l * NN_;
    const float* er = E + (size_t)l * 1024;
    const float* wr = EW + (size_t)z * 1024;
    float s = 0.f;
    for (int m = threadIdx.x; m < 1024; m += 256) {
        float g = er[m] * wr[m];
        Gb[(size_t)row * 1024 + m] = f2bf(g);
        s += g;
    }
    red[threadIdx.x] = s; __syncthreads();
    for (int t = 128; t > 0; t >>= 1) {
        if (threadIdx.x < t) red[threadIdx.x] += red[threadIdx.x + t];
        __syncthreads();
    }
    if (threadIdx.x == 0) Z[row] = red[0];
}

// x1 = LN1(node + Pb + co); Pb is bf16 attn-out already scaled by 1/Z.
// Writes bf16 X1b only (pad cols zeroed).
__global__ __launch_bounds__(256) void kern_ln1(
    const float* __restrict__ img, const float* __restrict__ word,
    const u16* __restrict__ Pb,
    const float* __restrict__ co, const float* __restrict__ g,
    const float* __restrict__ bta, u16* __restrict__ Xb)
{
    __shared__ float buf[DD_];
    __shared__ float red[256];
    __shared__ float stats[2];
    int row = blockIdx.x;
    int b = row / NN_, n = row - b * NN_;
    const u16* pr = Pb + (size_t)row * DD_;
    const float* cr = co + n * DD_;
    float s = 0.f;
    for (int d = threadIdx.x; d < DD_; d += 256) {
        float v = (d < IMG_) ? img[(size_t)b * IMG_ + d] : word[n * TXT_ + d - IMG_];
        v += bf2f(pr[d]) + cr[d];
        buf[d] = v; s += v;
    }
    red[threadIdx.x] = s; __syncthreads();
    for (int t = 128; t > 0; t >>= 1) {
        if (threadIdx.x < t) red[threadIdx.x] += red[threadIdx.x + t];
        __syncthreads();
    }
    if (threadIdx.x == 0) stats[0] = red[0] / DD_;
    __syncthreads();
    float mu = stats[0], s2 = 0.f;
    for (int d = threadIdx.x; d < DD_; d += 256) { float t = buf[d] - mu; s2 += t * t; }
    red[threadIdx.x] = s2; __syncthreads();
    for (int t = 128; t > 0; t >>= 1) {
        if (threadIdx.x < t) red[threadIdx.x] += red[threadIdx.x + t];
        __syncthreads();
    }
    if (threadIdx.x == 0) stats[1] = rsqrtf(red[0] / DD_ + 1e-5f);
    __syncthreads();
    float rstd = stats[1];
    u16* xb = Xb + (size_t)row * KP_;
    for (int d = threadIdx.x; d < DD_; d += 256)
        xb[d] = f2bf((buf[d] - mu) * rstd * g[d] + bta[d]);
    for (int d = DD_ + threadIdx.x; d < KP_; d += 256) xb[d] = 0;
}

// LN2: reads fp32 Y (FFN2 output, stride DD_), writes bf16 X2b (pads zeroed).
__global__ __launch_bounds__(256) void kern_ln2(const float* __restrict__ X,
    const float* __restrict__ g, const float* __restrict__ bta, u16* __restrict__ Xb)
{
    __shared__ float buf[DD_];
    __shared__ float red[256];
    __shared__ float stats[2];
    const float* xr = X + (size_t)blockIdx.x * DD_;
    float s = 0.f;
    for (int d = threadIdx.x; d < DD_; d += 256) { float v = xr[d]; buf[d] = v; s += v; }
    red[threadIdx.x] = s; __syncthreads();
    for (int t = 128; t > 0; t >>= 1) {
        if (threadIdx.x < t) red[threadIdx.x] += red[threadIdx.x + t];
        __syncthreads();
    }
    if (threadIdx.x == 0) stats[0] = red[0] / DD_;
    __syncthreads();
    float mu = stats[0], s2 = 0.f;
    for (int d = threadIdx.x; d < DD_; d += 256) { float t = buf[d] - mu; s2 += t * t; }
    red[threadIdx.x] = s2; __syncthreads();
    for (int t = 128; t > 0; t >>= 1) {
        if (threadIdx.x < t) red[threadIdx.x] += red[threadIdx.x + t];
        __syncthreads();
    }
    if (threadIdx.x == 0) stats[1] = rsqrtf(red[0] / DD_ + 1e-5f);
    __syncthreads();
    float rstd = stats[1];
    u16* xb = Xb + (size_t)blockIdx.x * KP_;
    for (int d = threadIdx.x; d < DD_; d += 256)
        xb[d] = f2bf((buf[d] - mu) * rstd * g[d] + bta[d]);
    for (int d = DD_ + threadIdx.x; d < KP_; d += 256) xb[d] = 0;
}

// g1 = relu(Adj @ h1 + bias) -> bf16
__global__ __launch_bounds__(256) void kern_agg1(const float* __restrict__ H,
    const float* __restrict__ Adj, const float* __restrict__ bias, u16* __restrict__ G)
{
    __shared__ float sA[NN_ * NN_];
    if (threadIdx.x < NN_ * NN_) sA[threadIdx.x] = Adj[threadIdx.x];
    __syncthreads();
    int t = blockIdx.x * 256 + threadIdx.x;
    int b = t >> 7, f = t & 127;
    float v[NN_];
    #pragma unroll
    for (int i = 0; i < NN_; ++i) v[i] = H[((size_t)b * NN_ + i) * HID_ + f];
    float bb = bias[f];
    #pragma unroll
    for (int j = 0; j < NN_; ++j) {
        float s = bb;
        #pragma unroll
        for (int i = 0; i < NN_; ++i) s = fmaf(sA[j * NN_ + i], v[i], s);
        G[((size_t)b * NN_ + j) * HID_ + f] = f2bf(s > 0.f ? s : 0.f);
    }
}

// pool = relu(mean_j(Adj @ h2 + bias))
__global__ __launch_bounds__(256) void kern_agg2_pool(const float* __restrict__ H,
    const float* __restrict__ Adj, const float* __restrict__ bias, float* __restrict__ P)
{
    __shared__ float sA[NN_ * NN_];
    if (threadIdx.x < NN_ * NN_) sA[threadIdx.x] = Adj[threadIdx.x];
    __syncthreads();
    int t = blockIdx.x * 256 + threadIdx.x;
    int b = t >> 7, f = t & 127;
    float v[NN_];
    #pragma unroll
    for (int i = 0; i < NN_; ++i) v[i] = H[((size_t)b * NN_ + i) * HID_ + f];
    float acc = 0.f;
    #pragma unroll
    for (int j = 0; j < NN_; ++j) {
        float s = 0.f;
        #pragma unroll
        for (int i = 0; i < NN_; ++i) s = fmaf(sA[j * NN_ + i], v[i], s);
        acc += s;
    }
    acc = acc / (float)NN_ + bias[f];
    P[(size_t)b * HID_ + f] = acc > 0.f ? acc : 0.f;
}

__global__ void kern_lin(const float* __restrict__ pool, const float* __restrict__ W,
                         const float* __restrict__ bias, float* __restrict__ out)
{
    int t = blockIdx.x * 256 + threadIdx.x;
    if (t >= B_ * CC_) return;
    int b = t / CC_, c = t % CC_;
    float s = bias[c];
    const float* pr = pool + (size_t)b * HID_;
    for (int f = 0; f < HID_; ++f) s = fmaf(pr[f], W[f * CC_ + c], s);
    out[t] = s;
}

extern "C" void kernel_launch(void* const* d_in, const int* in_sizes, int n_in,
                              void* d_out, int out_size, void* d_ws, size_t ws_size,
                              hipStream_t stream)
{
    const float* img  = (const float*)d_in[0];
    const float* word = (const float*)d_in[1];
    const int*   ei   = (const int*)d_in[2];
    const float* Wi   = (const float*)d_in[3];
    const float* bi   = (const float*)d_in[4];
    const float* Wo   = (const float*)d_in[5];
    const float* bo   = (const float*)d_in[6];
    const float* g1   = (const float*)d_in[7];
    const float* bt1  = (const float*)d_in[8];
    const float* g2   = (const float*)d_in[9];
    const float* bt2  = (const float*)d_in[10];
    const float* W1   = (const float*)d_in[11];
    const float* bf1  = (const float*)d_in[12];
    const float* W2   = (const float*)d_in[13];
    const float* bf2  = (const float*)d_in[14];
    const float* Wg1  = (const float*)d_in[15];
    const float* bg1  = (const float*)d_in[16];
    const float* Wg2  = (const float*)d_in[17];
    const float* bg2  = (const float*)d_in[18];
    const float* Wl   = (const float*)d_in[19];
    const float* bl   = (const float*)d_in[20];
    float* out = (float*)d_out;

    char* ws = (char*)d_ws;
    u16*   Pb   = (u16*)  (ws + OFF_P);
    u16*   Gb   = (u16*)  (ws + OFF_GB);
    u16*   Hb   = (u16*)  (ws + OFF_HB);
    float* H1   = (float*)(ws + OFF_H1);
    u16*   G1b  = (u16*)  (ws + OFF_G1B);
    float* H2   = (float*)(ws + OFF_H2);
    float* Pool = (float*)(ws + OFF_POOL);
    float* Yf   = (float*)(ws + OFF_X1);
    u16*   X1b  = (u16*)  (ws + OFF_X1B);
    u16*   X2b  = (u16*)  (ws + OFF_X1B);
    float* Ebuf = (float*)(ws + OFF_EBUF);
    u16*   Wob  = (u16*)  (ws + OFF_WOB);
    u16*   AvoT = (u16*)  (ws + OFF_AVOT);
    u16*   W1T  = (u16*)  (ws + OFF_W1T);
    u16*   W2T  = (u16*)  (ws + OFF_W2T);
    u16*   Aqb  = (u16*)  (ws + OFF_AQB);
    u16*   Akb  = (u16*)  (ws + OFF_AKB);
    u16*   Avb  = (u16*)  (ws + OFF_AVB);
    u16*   imgb = (u16*)  (ws + OFF_IMGB);
    u16*   Wib  = (u16*)  (ws + OFF_WIB);
    float* Tbuf = (float*)(ws + OFF_TBUF);
    u16*   Tqb  = (u16*)  (ws + OFF_TQB);
    float* wbuf = (float*)(ws + OFF_WBUF);
    float* co   = (float*)(ws + OFF_CO);
    float* Zb   = (float*)(ws + OFF_Z);
    float* Adj  = (float*)(ws + OFF_ADJ);
    u16*   Wg1T = (u16*)  (ws + OFF_WG1T);
    u16*   Wg2T = (u16*)  (ws + OFF_WG2T);

    const float scl = 1.0f / sqrtf((float)DD_);

    // --- small precompute + casts ---
    kern_T<<<(NN_ * D3_ + 255) / 256, 256, 0, stream>>>(word, Wi, bi, Tbuf);
    kern_adj<<<1, 64, 0, stream>>>(ei, Adj);
    kern_cast<<<(B_ * IMG_ + 255) / 256, 256, 0, stream>>>(img, IMG_, imgb, IMG_, B_, IMG_, IMG_);
    kern_cast<<<(D3_ * IMG_ + 255) / 256, 256, 0, stream>>>(Wi, DD_, Wib, IMG_, D3_, IMG_, IMG_);
    kern_cast<<<(NN_ * KP_ + 255) / 256, 256, 0, stream>>>(Tbuf, D3_, Tqb, KP_, NN_, KP_, DD_);
    kern_cast<<<(DD_ * KP_ + 255) / 256, 256, 0, stream>>>(Wo, DD_, Wob, KP_, DD_, KP_, DD_);

    // --- A-proj: [Aq|Ak|Av] = img @ Wi[:, :512]^T (split-3 bf16), then zero K-pads
    bgemm<4><<<20 * 8, 256, 0, stream>>>(imgb, IMG_, Wib, IMG_,
        B_, D3_, IMG_, 1.f, nullptr, 0, Aqb, 0, nullptr, 20, 1);
    kern_zeropad<<<240, 256, 0, stream>>>(Aqb);

    // --- S0 = scl*Aq@Ak^T ; w = scl*Tq@Ak^T ; exp both ---
    bgemm<0><<<8 * 8, 256, 0, stream>>>(Aqb, KP_, Akb, KP_,
        B_, B_, KP_, scl, Ebuf, 1024, nullptr, 0, nullptr, 8, 1);
    bgemm<0><<<8 * 1, 256, 0, stream>>>(Tqb, KP_, Akb, KP_,
        NN_, B_, KP_, scl, wbuf, 1024, nullptr, 0, nullptr, 8, 0);
    kern_exp_rows<<<1024, 256, 0, stream>>>(Ebuf);
    kern_exp_rows<<<NN_, 256, 0, stream>>>(wbuf);   // wbuf -> ew

    // --- AvoT[d,m] = (Av @ Wo^T)^T ; co = n-only part ---
    bgemm<3><<<8 * 7, 256, 0, stream>>>(Wob, KP_, Avb, KP_,
        DD_, B_, KP_, 1.f, nullptr, 0, AvoT, 1024, nullptr, 8, 0);
    kern_co<<<(NN_ * DD_ + 255) / 256, 256, 0, stream>>>(Tbuf, Wo, bo, co);

    // --- G = E*ew (bf16) + row sums Z; Pb = (G @ Avo)/Z as bf16 (EPI5) ---
    kern_G<<<BNR_, 256, 0, stream>>>(Ebuf, wbuf, Gb, Zb);
    bgemm<5><<<7 * 112, 256, 0, stream>>>(Gb, 1024, AvoT, 1024,
        BNR_, DD_, 1024, 1.f, nullptr, 0, Pb, DD_, Zb, 7, 1);

    // --- LN1 (bf16 in, bf16 out) ---
    kern_ln1<<<BNR_, 256, 0, stream>>>(img, word, Pb, co, g1, bt1, X1b);

    // --- FFN (bf16 MFMA), LN2 ---
    kern_castTp<<<(FF_ * KP_ + 255) / 256, 256, 0, stream>>>(W1, FF_, W1T, KP_, DD_, FF_, KP_);
    kern_castT<<<(FF_ * DD_ + 255) / 256, 256, 0, stream>>>(W2, DD_, W2T, FF_, FF_, DD_);
    bgemm<1><<<16 * 112, 256, 0, stream>>>(X1b, KP_, W1T, KP_,
        BNR_, FF_, KP_, 1.f, nullptr, 0, Hb, FF_, bf1, 16, 1);
    bgemm<2><<<7 * 112, 256, 0, stream>>>(Hb, FF_, W2T, FF_,
        BNR_, DD_, FF_, 1.f, Yf, DD_, X1b, KP_, bf2, 7, 1);   // resid from X1b
    kern_ln2<<<BNR_, 256, 0, stream>>>(Yf, g2, bt2, X2b);

    // --- GCN ---
    kern_castTp<<<(HID_ * KP_ + 255) / 256, 256, 0, stream>>>(Wg1, HID_, Wg1T, KP_, DD_, HID_, KP_);
    kern_castT<<<(HID_ * HID_ + 255) / 256, 256, 0, stream>>>(Wg2, HID_, Wg2T, HID_, HID_, HID_);
    bgemm<0><<<1 * 112, 256, 0, stream>>>(X2b, KP_, Wg1T, KP_,
        BNR_, HID_, KP_, 1.f, H1, HID_, nullptr, 0, nullptr, 1, 0);
    kern_agg1<<<(B_ * HID_) / 256, 256, 0, stream>>>(H1, Adj, bg1, G1b);
    bgemm<0><<<1 * 112, 256, 0, stream>>>(G1b, HID_, Wg2T, HID_,
        BNR_, HID_, HID_, 1.f, H2, HID_, nullptr, 0, nullptr, 1, 0);
    kern_agg2_pool<<<(B_ * HID_) / 256, 256, 0, stream>>>(H2, Adj, bg2, Pool);
    kern_lin<<<(B_ * CC_) / 256, 256, 0, stream>>>(Pool, Wl, bl, out);
}

// Round 7
// 631.751 us; speedup vs baseline: 3.8638x; 1.0593x over previous
//
#include <hip/hip_runtime.h>
#include <math.h>

// Problem constants
#define B_    1024
#define IMG_  512
#define TXT_  300
#define NN_   14
#define FF_   2048
#define HID_  128
#define CC_   14
#define EE_   182
#define DD_   812
#define D3_   2436
#define BNR_  14336          // B_*NN_
#define KP_   832            // 812 padded to /32 (16B-aligned rows)
#define TXP_  320            // 300 padded to /32
#define AROWS_ 1152          // Aq/Ak/Av rows: 1024 data + 14 Tq + pad to tile mult

typedef __bf16 bf16x8 __attribute__((ext_vector_type(8)));
typedef float  f32x4  __attribute__((ext_vector_type(4)));
typedef unsigned short u16;

__device__ __forceinline__ u16 f2bf(float f) {
    union { float f; unsigned u; } v; v.f = f;
    unsigned r = v.u + 0x7FFFu + ((v.u >> 16) & 1u);   // RNE
    return (u16)(r >> 16);
}
__device__ __forceinline__ float bf2f(u16 h) {
    union { unsigned u; float f; } v; v.u = ((unsigned)h) << 16; return v.f;
}

// async global->LDS, 16B per lane. LDS dst = wave-uniform base + lane*16.
__device__ __forceinline__ void gload_lds16(const u16* g, u16* l) {
    __builtin_amdgcn_global_load_lds(
        (const __attribute__((address_space(1))) void*)g,
        (__attribute__((address_space(3))) void*)l, 16, 0, 0);
}

// ---------------------------------------------------------------------------
// Workspace layout (bytes), time-multiplexed overlays (all conflicts audited
// against the launch timeline; garbage/NaN only reaches epilogue-masked
// rows/cols; K-pad columns of REAL rows are always explicitly zeroed).
// ---------------------------------------------------------------------------
#define OFF_IMGB  0ULL              // bf16 [1024][512]   (dead after A-proj)
#define OFF_WIB   1048576ULL        // bf16 [2436][512]   (dead after A-proj)
#define OFF_WORDB 3543040ULL        // bf16 [128][320]    (dead after T-GEMM)
#define OFF_WITX  3624960ULL        // bf16 [2560][320]   (dead after T-GEMM)
#define OFF_GB    0ULL              // bf16 [14336][1024] (eG..P)
#define OFF_EBUF  29360128ULL       // f32  [1038][1024]  (S0..eG)
#define OFF_AVOT  33611776ULL       // bf16 [896][1024]   (Avo..P)
#define OFF_WOB   35446784ULL       // bf16 [896][832]    (cast..co)
#define OFF_HB    0ULL              // bf16 [14336][2048] (FFN1..FFN2)
#define OFF_H1    0ULL              // GCN phase
#define OFF_G1B   7340032ULL
#define OFF_H2    11010048ULL
#define OFF_POOL  18350080ULL
#define OFF_PB    58720256ULL       // bf16 [14336][812]  (P..ln1)
#define OFF_W1T   58720256ULL       // bf16 [2048][832]   (cast after ln1!)
#define OFF_W2T   62128128ULL       // bf16 [896][2048]
#define OFF_X1B   82001920ULL       // bf16 [14336][832]  (ln1..FFN2; X2b reuse)
#define OFF_YF    105857024ULL      // f32  [14336][812]  (FFN2..ln2)
#define OFF_AQB   152420352ULL      // bf16 3x[1152][832] (Aq|Ak|Av)
#define OFF_TBUF  158171136ULL      // f32  [14][2436]
#define OFF_TVB   158307552ULL      // bf16 [128][832]
#define OFF_CO    158520544ULL      // f32  [14][812]
#define OFF_Z     158566016ULL      // f32  [14336]
#define OFF_ADJ   158623360ULL      // f32  [196]
#define OFF_WG1T  158624144ULL      // bf16 [128][832]
#define OFF_WG2T  158837136ULL      // bf16 [128][128]

// ---------------------------------------------------------------------------
// bf16 MFMA GEMM: C[M,N] = scale * A[M,K] @ B^T (B stored [N][K]).
// 128x128 tile, BK=32, 4 waves (2x2 of 64x64), 16x16x32 MFMA, double-buffered
// global_load_lds staging, __launch_bounds__(256,4) -> 4 blocks/CU.
// Requirements: K%32==0, K-pads zeroed on BOTH operands (NaN hazard), operand
// buffers allocated/readable to 128-row tile multiples; M/N edges masked in
// the epilogue (garbage pad rows only pollute masked outputs).
// EPI 0: Cf=v. 1: Cb=bf16(relu(v+bias[cn])). 2: Cf=v+bias[cn]+bf2f(Cb) (resid IN).
// EPI 3: Cb=bf16(v). 4: split-3 into [Aq|Ak|Av] (stride AROWS_*KP_).
// EPI 5: Cb=bf16(v/bias[rm]). 6: Cf=v+bias[cn].
// ---------------------------------------------------------------------------
template<int EPI>
__global__ __launch_bounds__(256, 4)
void bgemm(const u16* __restrict__ A, int lda,
           const u16* __restrict__ Bm, int ldb,
           int M, int N, int K, float scale,
           float* __restrict__ Cf, int ldc,
           u16* __restrict__ Cb, int ldcb,
           const float* __restrict__ bias,
           int nxt, int swiz)
{
    __shared__ __align__(16) u16 As[2][128 * 32];
    __shared__ __align__(16) u16 Bs[2][128 * 32];
    const int tid = threadIdx.x;
    int bx, by;
    {
        int id = blockIdx.x;
        if (swiz) { int r8 = id & 7; int q = id >> 3; bx = q % nxt; by = (q / nxt) * 8 + r8; }
        else      { bx = id % nxt; by = id / nxt; }
    }
    const int row0 = by * 128, col0 = bx * 128;
    const int lane = tid & 63, wv = tid >> 6;
    const int wm = (wv >> 1) * 64, wn = (wv & 1) * 64;
    const int fr = lane & 15, qd = lane >> 4;

    const int s_r0  = (wv * 64 + lane) >> 2;
    const int s_ko  = (lane & 3) * 8;
    const int s_b0  = (wv * 64) * 8;
    const u16* Arow0 = A  + (size_t)(row0 + s_r0) * lda + s_ko;
    const u16* Arow1 = A  + (size_t)(row0 + s_r0 + 64) * lda + s_ko;
    const u16* Brow0 = Bm + (size_t)(col0 + s_r0) * ldb + s_ko;
    const u16* Brow1 = Bm + (size_t)(col0 + s_r0 + 64) * ldb + s_ko;

    f32x4 acc[4][4] = {};

    const int T = K >> 5;
    gload_lds16(Arow0, &As[0][s_b0]);
    gload_lds16(Arow1, &As[0][s_b0 + 2048]);
    gload_lds16(Brow0, &Bs[0][s_b0]);
    gload_lds16(Brow1, &Bs[0][s_b0 + 2048]);

    for (int i = 0; i < T; ++i) {
        __syncthreads();
        const int cur = i & 1;
        if (i + 1 < T) {
            const int nxtb = cur ^ 1;
            const int ko = (i + 1) << 5;
            gload_lds16(Arow0 + ko, &As[nxtb][s_b0]);
            gload_lds16(Arow1 + ko, &As[nxtb][s_b0 + 2048]);
            gload_lds16(Brow0 + ko, &Bs[nxtb][s_b0]);
            gload_lds16(Brow1 + ko, &Bs[nxtb][s_b0 + 2048]);
        }
        bf16x8 af[4], bg[4];
        #pragma unroll
        for (int j = 0; j < 4; ++j) {
            af[j] = *(const bf16x8*)&As[cur][(wm + j * 16 + fr) * 32 + qd * 8];
            bg[j] = *(const bf16x8*)&Bs[cur][(wn + j * 16 + fr) * 32 + qd * 8];
        }
        #pragma unroll
        for (int mi = 0; mi < 4; ++mi)
            #pragma unroll
            for (int ni = 0; ni < 4; ++ni)
                acc[mi][ni] = __builtin_amdgcn_mfma_f32_16x16x32_bf16(
                    af[mi], bg[ni], acc[mi][ni], 0, 0, 0);
    }

    #pragma unroll
    for (int mi = 0; mi < 4; ++mi) {
        #pragma unroll
        for (int i = 0; i < 4; ++i) {
            int rm = row0 + wm + mi * 16 + qd * 4 + i;
            if (rm >= M) continue;
            #pragma unroll
            for (int ni = 0; ni < 4; ++ni) {
                int cn = col0 + wn + ni * 16 + fr;
                if (cn >= N) continue;
                float v = acc[mi][ni][i] * scale;
                if (EPI == 0) Cf[(size_t)rm * ldc + cn] = v;
                if (EPI == 1) { v += bias[cn]; v = v > 0.f ? v : 0.f;
                                Cb[(size_t)rm * ldcb + cn] = f2bf(v); }
                if (EPI == 2) Cf[(size_t)rm * ldc + cn] =
                                v + bias[cn] + bf2f(Cb[(size_t)rm * ldcb + cn]);
                if (EPI == 3) Cb[(size_t)rm * ldcb + cn] = f2bf(v);
                if (EPI == 4) { int bs = cn / DD_, cc = cn - bs * DD_;
                                Cb[(size_t)bs * (AROWS_ * KP_) + (size_t)rm * KP_ + cc] = f2bf(v); }
                if (EPI == 5) { float invz = 1.0f / bias[rm];
                                Cb[(size_t)rm * ldcb + cn] = f2bf(v * invz); }
                if (EPI == 6) Cf[(size_t)rm * ldc + cn] = v + bias[cn];
            }
        }
    }
}

// fp32->bf16 cast: dst[r*drs+c] = (c<scols) ? src[r*srs+c] : 0, c < dcols
__global__ void kern_cast(const float* __restrict__ src, int srs,
                          u16* __restrict__ dst, int drs, int rows, int dcols, int scols)
{
    int idx = blockIdx.x * 256 + threadIdx.x;
    if (idx >= rows * dcols) return;
    int r = idx / dcols, c = idx - r * dcols;
    dst[(size_t)r * drs + c] = (c < scols) ? f2bf(src[(size_t)r * srs + c]) : (u16)0;
}

// Coalesced LDS-tiled cast-transpose: dst[c][r] = (r<rows ? src[r][c] : 0),
// r < padrows, c < cols. 32x32 tiles, 256 threads (32x8), both sides coalesced.
__global__ __launch_bounds__(256) void kern_castT32(
    const float* __restrict__ src, int srs, u16* __restrict__ dst, int drs,
    int rows, int cols, int padrows)
{
    __shared__ float t[32][33];
    int r0 = blockIdx.x * 32, c0 = blockIdx.y * 32;
    int tx = threadIdx.x & 31, ty = threadIdx.x >> 5;   // 32 x 8
    #pragma unroll
    for (int k = 0; k < 4; ++k) {
        int r = r0 + ty + k * 8, c = c0 + tx;
        t[ty + k * 8][tx] = (r < rows && c < cols) ? src[(size_t)r * srs + c] : 0.f;
    }
    __syncthreads();
    #pragma unroll
    for (int k = 0; k < 4; ++k) {
        int c = c0 + ty + k * 8, r = r0 + tx;
        if (c < cols && r < padrows)
            dst[(size_t)c * drs + r] = f2bf(t[tx][ty + k * 8]);
    }
}

// zero K-pad cols [812,832) of Aq/Ak/Av data rows (each [AROWS_][KP_])
__global__ void kern_zeropad(u16* __restrict__ Aq)
{
    int idx = blockIdx.x * 256 + threadIdx.x;
    if (idx >= 3 * 1024 * 20) return;
    int w = idx / (1024 * 20), rem = idx - w * (1024 * 20);
    int r = rem / 20, c = rem - r * 20;
    Aq[(size_t)w * (AROWS_ * KP_) + (size_t)r * KP_ + DD_ + c] = 0;
}

// Dense 14x14 GCN adjacency (self-loops + symmetric norm)
__global__ void kern_adj(const int* __restrict__ ei, float* __restrict__ Adj)
{
    if (threadIdx.x != 0 || blockIdx.x != 0) return;
    float deg[NN_];
    for (int i = 0; i < NN_; ++i) deg[i] = 1.f;
    for (int e = 0; e < EE_; ++e) deg[ei[EE_ + e]] += 1.f;
    float dinv[NN_];
    for (int i = 0; i < NN_; ++i) dinv[i] = rsqrtf(deg[i]);
    float adj[NN_ * NN_];
    for (int t = 0; t < NN_ * NN_; ++t) adj[t] = 0.f;
    for (int e = 0; e < EE_; ++e) {
        int s = ei[e], d = ei[EE_ + e];
        adj[d * NN_ + s] += dinv[s] * dinv[d];
    }
    for (int i = 0; i < NN_; ++i) adj[i * NN_ + i] += dinv[i] * dinv[i];
    for (int t = 0; t < NN_ * NN_; ++t) Adj[t] = adj[t];
}

// row -> exp(row - rowmax), rows of length 1024, in place (used for ew rows)
__global__ __launch_bounds__(256) void kern_exp_rows(float* __restrict__ S)
{
    __shared__ float red[256];
    float* row = S + (size_t)blockIdx.x * 1024;
    float m = -1e30f;
    for (int i = threadIdx.x; i < 1024; i += 256) m = fmaxf(m, row[i]);
    red[threadIdx.x] = m; __syncthreads();
    for (int s = 128; s > 0; s >>= 1) {
        if (threadIdx.x < s) red[threadIdx.x] = fmaxf(red[threadIdx.x], red[threadIdx.x + s]);
        __syncthreads();
    }
    m = red[0];
    for (int i = threadIdx.x; i < 1024; i += 256) row[i] = expf(row[i] - m);
}

// Fused exp + G + Z: block l: e = exp(S0[l,:]-max) kept in registers;
// Gb[(l*14+z), m] = e[m]*ew[z,m] (bf16), Z[l*14+z] = sum_m.
// S = Ebuf: rows 0..1023 raw S0 scores; rows 1024..1037 ew (already exp'd).
__global__ __launch_bounds__(256) void kern_eG(const float* __restrict__ S,
    u16* __restrict__ Gb, float* __restrict__ Z)
{
    __shared__ float red[256];
    int l = blockIdx.x;
    const float* row = S + (size_t)l * 1024;
    float v0[4]; float m = -1e30f;
    #pragma unroll
    for (int k = 0; k < 4; ++k) { v0[k] = row[threadIdx.x + 256 * k]; m = fmaxf(m, v0[k]); }
    red[threadIdx.x] = m; __syncthreads();
    for (int s = 128; s > 0; s >>= 1) {
        if (threadIdx.x < s) red[threadIdx.x] = fmaxf(red[threadIdx.x], red[threadIdx.x + s]);
        __syncthreads();
    }
    m = red[0];
    float ev[4];
    #pragma unroll
    for (int k = 0; k < 4; ++k) ev[k] = expf(v0[k] - m);
    const float* ew = S + 1024 * 1024;
    u16* gr = Gb + (size_t)l * NN_ * 1024;
    for (int z = 0; z < NN_; ++z) {
        float part = 0.f;
        #pragma unroll
        for (int k = 0; k < 4; ++k) {
            float p = ev[k] * ew[z * 1024 + threadIdx.x + 256 * k];
            gr[(size_t)z * 1024 + threadIdx.x + 256 * k] = f2bf(p);
            part += p;
        }
        __syncthreads();
        red[threadIdx.x] = part; __syncthreads();
        for (int s = 128; s > 0; s >>= 1) {
            if (threadIdx.x < s) red[threadIdx.x] += red[threadIdx.x + s];
            __syncthreads();
        }
        if (threadIdx.x == 0) Z[l * NN_ + z] = red[0];
    }
}

// x1 = LN1(node + Pb + co); Pb is bf16 attn-out already scaled by 1/Z.
__global__ __launch_bounds__(256) void kern_ln1(
    const float* __restrict__ img, const float* __restrict__ word,
    const u16* __restrict__ Pb,
    const float* __restrict__ co, const float* __restrict__ g,
    const float* __restrict__ bta, u16* __restrict__ Xb)
{
    __shared__ float buf[DD_];
    __shared__ float red[256];
    __shared__ float stats[2];
    int row = blockIdx.x;
    int b = row / NN_, n = row - b * NN_;
    const u16* pr = Pb + (size_t)row * DD_;
    const float* cr = co + n * DD_;
    float s = 0.f;
    for (int d = threadIdx.x; d < DD_; d += 256) {
        float v = (d < IMG_) ? img[(size_t)b * IMG_ + d] : word[n * TXT_ + d - IMG_];
        v += bf2f(pr[d]) + cr[d];
        buf[d] = v; s += v;
    }
    red[threadIdx.x] = s; __syncthreads();
    for (int t = 128; t > 0; t >>= 1) {
        if (threadIdx.x < t) red[threadIdx.x] += red[threadIdx.x + t];
        __syncthreads();
    }
    if (threadIdx.x == 0) stats[0] = red[0] / DD_;
    __syncthreads();
    float mu = stats[0], s2 = 0.f;
    for (int d = threadIdx.x; d < DD_; d += 256) { float t = buf[d] - mu; s2 += t * t; }
    red[threadIdx.x] = s2; __syncthreads();
    for (int t = 128; t > 0; t >>= 1) {
        if (threadIdx.x < t) red[threadIdx.x] += red[threadIdx.x + t];
        __syncthreads();
    }
    if (threadIdx.x == 0) stats[1] = rsqrtf(red[0] / DD_ + 1e-5f);
    __syncthreads();
    float rstd = stats[1];
    u16* xb = Xb + (size_t)row * KP_;
    for (int d = threadIdx.x; d < DD_; d += 256)
        xb[d] = f2bf((buf[d] - mu) * rstd * g[d] + bta[d]);
    for (int d = DD_ + threadIdx.x; d < KP_; d += 256) xb[d] = 0;
}

// LN2: reads fp32 Y (FFN2 output), writes bf16 X2b (pads zeroed).
__global__ __launch_bounds__(256) void kern_ln2(const float* __restrict__ X,
    const float* __restrict__ g, const float* __restrict__ bta, u16* __restrict__ Xb)
{
    __shared__ float buf[DD_];
    __shared__ float red[256];
    __shared__ float stats[2];
    const float* xr = X + (size_t)blockIdx.x * DD_;
    float s = 0.f;
    for (int d = threadIdx.x; d < DD_; d += 256) { float v = xr[d]; buf[d] = v; s += v; }
    red[threadIdx.x] = s; __syncthreads();
    for (int t = 128; t > 0; t >>= 1) {
        if (threadIdx.x < t) red[threadIdx.x] += red[threadIdx.x + t];
        __syncthreads();
    }
    if (threadIdx.x == 0) stats[0] = red[0] / DD_;
    __syncthreads();
    float mu = stats[0], s2 = 0.f;
    for (int d = threadIdx.x; d < DD_; d += 256) { float t = buf[d] - mu; s2 += t * t; }
    red[threadIdx.x] = s2; __syncthreads();
    for (int t = 128; t > 0; t >>= 1) {
        if (threadIdx.x < t) red[threadIdx.x] += red[threadIdx.x + t];
        __syncthreads();
    }
    if (threadIdx.x == 0) stats[1] = rsqrtf(red[0] / DD_ + 1e-5f);
    __syncthreads();
    float rstd = stats[1];
    u16* xb = Xb + (size_t)blockIdx.x * KP_;
    for (int d = threadIdx.x; d < DD_; d += 256)
        xb[d] = f2bf((buf[d] - mu) * rstd * g[d] + bta[d]);
    for (int d = DD_ + threadIdx.x; d < KP_; d += 256) xb[d] = 0;
}

// g1 = relu(Adj @ h1 + bias) -> bf16
__global__ __launch_bounds__(256) void kern_agg1(const float* __restrict__ H,
    const float* __restrict__ Adj, const float* __restrict__ bias, u16* __restrict__ G)
{
    __shared__ float sA[NN_ * NN_];
    if (threadIdx.x < NN_ * NN_) sA[threadIdx.x] = Adj[threadIdx.x];
    __syncthreads();
    int t = blockIdx.x * 256 + threadIdx.x;
    int b = t >> 7, f = t & 127;
    float v[NN_];
    #pragma unroll
    for (int i = 0; i < NN_; ++i) v[i] = H[((size_t)b * NN_ + i) * HID_ + f];
    float bb = bias[f];
    #pragma unroll
    for (int j = 0; j < NN_; ++j) {
        float s = bb;
        #pragma unroll
        for (int i = 0; i < NN_; ++i) s = fmaf(sA[j * NN_ + i], v[i], s);
        G[((size_t)b * NN_ + j) * HID_ + f] = f2bf(s > 0.f ? s : 0.f);
    }
}

// pool = relu(mean_j(Adj @ h2 + bias))
__global__ __launch_bounds__(256) void kern_agg2_pool(const float* __restrict__ H,
    const float* __restrict__ Adj, const float* __restrict__ bias, float* __restrict__ P)
{
    __shared__ float sA[NN_ * NN_];
    if (threadIdx.x < NN_ * NN_) sA[threadIdx.x] = Adj[threadIdx.x];
    __syncthreads();
    int t = blockIdx.x * 256 + threadIdx.x;
    int b = t >> 7, f = t & 127;
    float v[NN_];
    #pragma unroll
    for (int i = 0; i < NN_; ++i) v[i] = H[((size_t)b * NN_ + i) * HID_ + f];
    float acc = 0.f;
    #pragma unroll
    for (int j = 0; j < NN_; ++j) {
        float s = 0.f;
        #pragma unroll
        for (int i = 0; i < NN_; ++i) s = fmaf(sA[j * NN_ + i], v[i], s);
        acc += s;
    }
    acc = acc / (float)NN_ + bias[f];
    P[(size_t)b * HID_ + f] = acc > 0.f ? acc : 0.f;
}

__global__ void kern_lin(const float* __restrict__ pool, const float* __restrict__ W,
                         const float* __restrict__ bias, float* __restrict__ out)
{
    int t = blockIdx.x * 256 + threadIdx.x;
    if (t >= B_ * CC_) return;
    int b = t / CC_, c = t % CC_;
    float s = bias[c];
    const float* pr = pool + (size_t)b * HID_;
    for (int f = 0; f < HID_; ++f) s = fmaf(pr[f], W[f * CC_ + c], s);
    out[t] = s;
}

extern "C" void kernel_launch(void* const* d_in, const int* in_sizes, int n_in,
                              void* d_out, int out_size, void* d_ws, size_t ws_size,
                              hipStream_t stream)
{
    const float* img  = (const float*)d_in[0];
    const float* word = (const float*)d_in[1];
    const int*   ei   = (const int*)d_in[2];
    const float* Wi   = (const float*)d_in[3];
    const float* bi   = (const float*)d_in[4];
    const float* Wo   = (const float*)d_in[5];
    const float* bo   = (const float*)d_in[6];
    const float* g1   = (const float*)d_in[7];
    const float* bt1  = (const float*)d_in[8];
    const float* g2   = (const float*)d_in[9];
    const float* bt2  = (const float*)d_in[10];
    const float* W1   = (const float*)d_in[11];
    const float* bf1  = (const float*)d_in[12];
    const float* W2   = (const float*)d_in[13];
    const float* bf2  = (const float*)d_in[14];
    const float* Wg1  = (const float*)d_in[15];
    const float* bg1  = (const float*)d_in[16];
    const float* Wg2  = (const float*)d_in[17];
    const float* bg2  = (const float*)d_in[18];
    const float* Wl   = (const float*)d_in[19];
    const float* bl   = (const float*)d_in[20];
    float* out = (float*)d_out;

    char* ws = (char*)d_ws;
    u16*   imgb = (u16*)  (ws + OFF_IMGB);
    u16*   Wib  = (u16*)  (ws + OFF_WIB);
    u16*   wordb= (u16*)  (ws + OFF_WORDB);
    u16*   WiTX = (u16*)  (ws + OFF_WITX);
    u16*   Gb   = (u16*)  (ws + OFF_GB);
    float* Ebuf = (float*)(ws + OFF_EBUF);
    u16*   AvoT = (u16*)  (ws + OFF_AVOT);
    u16*   Wob  = (u16*)  (ws + OFF_WOB);
    u16*   Hb   = (u16*)  (ws + OFF_HB);
    float* H1   = (float*)(ws + OFF_H1);
    u16*   G1b  = (u16*)  (ws + OFF_G1B);
    float* H2   = (float*)(ws + OFF_H2);
    float* Pool = (float*)(ws + OFF_POOL);
    u16*   Pb   = (u16*)  (ws + OFF_PB);
    u16*   W1T  = (u16*)  (ws + OFF_W1T);
    u16*   W2T  = (u16*)  (ws + OFF_W2T);
    u16*   X1b  = (u16*)  (ws + OFF_X1B);
    u16*   X2b  = (u16*)  (ws + OFF_X1B);
    float* Yf   = (float*)(ws + OFF_YF);
    u16*   Aqb  = (u16*)  (ws + OFF_AQB);
    u16*   Akb  = Aqb + AROWS_ * KP_;
    u16*   Avb  = Aqb + 2 * AROWS_ * KP_;
    float* Tbuf = (float*)(ws + OFF_TBUF);
    u16*   Tvb  = (u16*)  (ws + OFF_TVB);
    float* co   = (float*)(ws + OFF_CO);
    float* Zb   = (float*)(ws + OFF_Z);
    float* Adj  = (float*)(ws + OFF_ADJ);
    u16*   Wg1T = (u16*)  (ws + OFF_WG1T);
    u16*   Wg2T = (u16*)  (ws + OFF_WG2T);

    const float scl = 1.0f / sqrtf((float)DD_);

    // --- input casts (coalesced) + adjacency ---
    kern_cast<<<(B_ * IMG_ + 255) / 256, 256, 0, stream>>>(img, IMG_, imgb, IMG_, B_, IMG_, IMG_);
    kern_cast<<<(D3_ * IMG_ + 255) / 256, 256, 0, stream>>>(Wi, DD_, Wib, IMG_, D3_, IMG_, IMG_);
    kern_cast<<<(NN_ * TXP_ + 255) / 256, 256, 0, stream>>>(word, TXT_, wordb, TXP_, NN_, TXP_, TXT_);
    kern_cast<<<(D3_ * TXP_ + 255) / 256, 256, 0, stream>>>(Wi + IMG_, DD_, WiTX, TXP_, D3_, TXP_, TXT_);
    kern_cast<<<(DD_ * KP_ + 255) / 256, 256, 0, stream>>>(Wo, DD_, Wob, KP_, DD_, KP_, DD_);
    kern_adj<<<1, 64, 0, stream>>>(ei, Adj);

    // --- T = word @ WiTX^T + bi  (tiny MFMA GEMM; was 34K-thread serial kern_T)
    bgemm<6><<<20, 256, 0, stream>>>(wordb, TXP_, WiTX, TXP_,
        NN_, D3_, TXP_, 1.f, Tbuf, D3_, nullptr, 0, bi, 20, 0);
    // Tq -> Aq rows 1024..1037 (K-pads zeroed); Tv -> Tvb
    kern_cast<<<(NN_ * KP_ + 255) / 256, 256, 0, stream>>>(Tbuf, D3_, Aqb + 1024 * KP_, KP_, NN_, KP_, DD_);
    kern_cast<<<(NN_ * KP_ + 255) / 256, 256, 0, stream>>>(Tbuf + 2 * DD_, D3_, Tvb, KP_, NN_, KP_, DD_);

    // --- A-proj: [Aq|Ak|Av] = img @ Wi[:, :512]^T (split-3), zero K-pads ---
    bgemm<4><<<20 * 8, 256, 0, stream>>>(imgb, IMG_, Wib, IMG_,
        B_, D3_, IMG_, 1.f, nullptr, 0, Aqb, 0, nullptr, 20, 1);
    kern_zeropad<<<240, 256, 0, stream>>>(Aqb);

    // --- S0 (rows 0..1023) and w (rows 1024..1037) in ONE GEMM, M=1038 ---
    bgemm<0><<<8 * 9, 256, 0, stream>>>(Aqb, KP_, Akb, KP_,
        1024 + NN_, B_, KP_, scl, Ebuf, 1024, nullptr, 0, nullptr, 8, 0);
    kern_exp_rows<<<NN_, 256, 0, stream>>>(Ebuf + 1024 * 1024);   // ew rows only

    // --- fused exp + G + Z ---
    kern_eG<<<1024, 256, 0, stream>>>(Ebuf, Gb, Zb);

    // --- AvoT = (Wo @ Av^T) ; co = Tv @ Wo^T + bo (tiny GEMM; was kern_co) ---
    bgemm<3><<<8 * 7, 256, 0, stream>>>(Wob, KP_, Avb, KP_,
        DD_, B_, KP_, 1.f, nullptr, 0, AvoT, 1024, nullptr, 8, 0);
    bgemm<6><<<7, 256, 0, stream>>>(Tvb, KP_, Wob, KP_,
        NN_, DD_, KP_, 1.f, co, DD_, nullptr, 0, bo, 7, 0);

    // --- Pb = (G @ Avo)/Z as bf16 ---
    bgemm<5><<<7 * 112, 256, 0, stream>>>(Gb, 1024, AvoT, 1024,
        BNR_, DD_, 1024, 1.f, nullptr, 0, Pb, DD_, Zb, 7, 1);

    // --- LN1 ---
    kern_ln1<<<BNR_, 256, 0, stream>>>(img, word, Pb, co, g1, bt1, X1b);

    // --- weight transposes (coalesced LDS-tiled; AFTER ln1 — W1T overlays Pb)
    kern_castT32<<<dim3(26, 64), 256, 0, stream>>>(W1, FF_, W1T, KP_, DD_, FF_, KP_);
    kern_castT32<<<dim3(64, 26), 256, 0, stream>>>(W2, DD_, W2T, FF_, FF_, DD_, FF_);

    // --- FFN (bf16 MFMA), LN2 ---
    bgemm<1><<<16 * 112, 256, 0, stream>>>(X1b, KP_, W1T, KP_,
        BNR_, FF_, KP_, 1.f, nullptr, 0, Hb, FF_, bf1, 16, 1);
    bgemm<2><<<7 * 112, 256, 0, stream>>>(Hb, FF_, W2T, FF_,
        BNR_, DD_, FF_, 1.f, Yf, DD_, X1b, KP_, bf2, 7, 1);
    kern_ln2<<<BNR_, 256, 0, stream>>>(Yf, g2, bt2, X2b);

    // --- GCN ---
    kern_castT32<<<dim3(26, 4), 256, 0, stream>>>(Wg1, HID_, Wg1T, KP_, DD_, HID_, KP_);
    kern_castT32<<<dim3(4, 4), 256, 0, stream>>>(Wg2, HID_, Wg2T, HID_, HID_, HID_, HID_);
    bgemm<0><<<1 * 112, 256, 0, stream>>>(X2b, KP_, Wg1T, KP_,
        BNR_, HID_, KP_, 1.f, H1, HID_, nullptr, 0, nullptr, 1, 0);
    kern_agg1<<<(B_ * HID_) / 256, 256, 0, stream>>>(H1, Adj, bg1, G1b);
    bgemm<0><<<1 * 112, 256, 0, stream>>>(G1b, HID_, Wg2T, HID_,
        BNR_, HID_, HID_, 1.f, H2, HID_, nullptr, 0, nullptr, 1, 0);
    kern_agg2_pool<<<(B_ * HID_) / 256, 256, 0, stream>>>(H2, Adj, bg2, Pool);
    kern_lin<<<(B_ * CC_) / 256, 256, 0, stream>>>(Pool, Wl, bl, out);
}

// Round 8
// 583.030 us; speedup vs baseline: 4.1867x; 1.0836x over previous
//
#include <hip/hip_runtime.h>
#include <math.h>

// Problem constants
#define B_    1024
#define IMG_  512
#define TXT_  300
#define NN_   14
#define FF_   2048
#define HID_  128
#define CC_   14
#define EE_   182
#define DD_   812
#define D3_   2436
#define BNR_  14336          // B_*NN_
#define KP_   832            // 812 padded to /32 (16B-aligned rows)
#define TXP_  320            // 300 padded to /32
#define AROWS_ 1152          // Aq/Ak/Av rows: 1024 data + 14 Tq + pad to tile mult

typedef __bf16 bf16x8 __attribute__((ext_vector_type(8)));
typedef float  f32x4  __attribute__((ext_vector_type(4)));
typedef unsigned short u16;

__device__ __forceinline__ u16 f2bf(float f) {
    union { float f; unsigned u; } v; v.f = f;
    unsigned r = v.u + 0x7FFFu + ((v.u >> 16) & 1u);   // RNE
    return (u16)(r >> 16);
}
__device__ __forceinline__ float bf2f(u16 h) {
    union { unsigned u; float f; } v; v.u = ((unsigned)h) << 16; return v.f;
}

// async global->LDS, 16B per lane. LDS dst = wave-uniform base + lane*16.
__device__ __forceinline__ void gload_lds16(const u16* g, u16* l) {
    __builtin_amdgcn_global_load_lds(
        (const __attribute__((address_space(1))) void*)g,
        (__attribute__((address_space(3))) void*)l, 16, 0, 0);
}

// ---------------------------------------------------------------------------
// Workspace layout (bytes), time-multiplexed overlays (all conflicts audited
// against the launch timeline; garbage/NaN only reaches epilogue-masked
// rows/cols; K-pad columns of REAL rows are always explicitly zeroed).
// ---------------------------------------------------------------------------
#define OFF_IMGB  0ULL              // bf16 [1024][512]   (dead after G1)
#define OFF_WIB   1048576ULL        // bf16 [2436][512]   (dead after G1)
#define OFF_WORDB 3543040ULL        // bf16 [128][320]    (dead after G1)
#define OFF_WITX  3624960ULL        // bf16 [2560][320]   (dead after G1)
#define OFF_GB    0ULL              // bf16 [14336][1024] (eG..P)
#define OFF_EBUF  29360128ULL       // f32  [1038][1024]  (S0..eG)
#define OFF_AVOT  33611776ULL       // bf16 [896][1024]   (G2..P)
#define OFF_WOB   35446784ULL       // bf16 [896][832]    (mcast..G2)
#define OFF_HB    0ULL              // bf16 [14336][2048] (FFN1..FFN2)
#define OFF_H1    0ULL              // GCN phase
#define OFF_G1B   7340032ULL
#define OFF_H2    11010048ULL
#define OFF_POOL  18350080ULL
#define OFF_PB    58720256ULL       // bf16 [14336][812]  (P..ln1)
#define OFF_W1T   58720256ULL       // bf16 [2048][832]   (cast after ln1!)
#define OFF_W2T   62128128ULL       // bf16 [896][2048]
#define OFF_X1B   82001920ULL       // bf16 [14336][832]  (ln1..FFN2; X2b reuse)
#define OFF_YF    105857024ULL      // f32  [14336][812]  (FFN2..ln2)
#define OFF_AQB   152420352ULL      // bf16 3x[1152][832] (Aq|Ak|Av)
#define OFF_TBUF  158171136ULL      // f32  [14][2436]
#define OFF_TVB   158307552ULL      // bf16 [128][832]
#define OFF_CO    158520544ULL      // f32  [14][812]
#define OFF_Z     158566016ULL      // f32  [14336]
#define OFF_ADJ   158623360ULL      // f32  [196]
#define OFF_WG1T  158624144ULL      // bf16 [128][832]
#define OFF_WG2T  158837136ULL      // bf16 [128][128]

// ---------------------------------------------------------------------------
// Shared GEMM pipeline body: C[M,N] = scale * A[M,K] @ B^T (B stored [N][K]).
// 128x128 tile, BK=32, 4 waves (2x2 of 64x64), 16x16x32 MFMA, double-buffered
// global_load_lds staging. Requirements: K%32==0, K-pads zeroed on BOTH
// operands (NaN hazard), operand buffers readable to 128-row tile multiples;
// M/N edges masked in epilogue. swiz=1: id%8 -> row-tile (XCD L2 reuse).
// epi 0: Cf=v. 1: Cb=bf16(relu(v+bias[cn])). 2: Cf=v+bias[cn]+bf2f(Cb).
// 3: Cb=bf16(v). 4: split-3 into [Aq|Ak|Av]. 5: Cb=bf16(v/bias[rm]).
// 6: Cf=v+bias[cn].
// Template kernels pass compile-time epi (folds); grouped kernel passes runtime.
// ---------------------------------------------------------------------------
__device__ __forceinline__ void gemm_body(
    const u16* __restrict__ A, int lda,
    const u16* __restrict__ Bm, int ldb,
    int M, int N, int K, float scale,
    float* __restrict__ Cf, int ldc,
    u16* __restrict__ Cb, int ldcb,
    const float* __restrict__ bias,
    int nxt, int swiz, int epi, int id)
{
    __shared__ __align__(16) u16 As[2][128 * 32];
    __shared__ __align__(16) u16 Bs[2][128 * 32];
    const int tid = threadIdx.x;
    int bx, by;
    if (swiz) { int r8 = id & 7; int q = id >> 3; bx = q % nxt; by = (q / nxt) * 8 + r8; }
    else      { bx = id % nxt; by = id / nxt; }
    const int row0 = by * 128, col0 = bx * 128;
    const int lane = tid & 63, wv = tid >> 6;
    const int wm = (wv >> 1) * 64, wn = (wv & 1) * 64;
    const int fr = lane & 15, qd = lane >> 4;

    const int s_r0  = (wv * 64 + lane) >> 2;
    const int s_ko  = (lane & 3) * 8;
    const int s_b0  = (wv * 64) * 8;
    const u16* Arow0 = A  + (size_t)(row0 + s_r0) * lda + s_ko;
    const u16* Arow1 = A  + (size_t)(row0 + s_r0 + 64) * lda + s_ko;
    const u16* Brow0 = Bm + (size_t)(col0 + s_r0) * ldb + s_ko;
    const u16* Brow1 = Bm + (size_t)(col0 + s_r0 + 64) * ldb + s_ko;

    f32x4 acc[4][4] = {};

    const int T = K >> 5;
    gload_lds16(Arow0, &As[0][s_b0]);
    gload_lds16(Arow1, &As[0][s_b0 + 2048]);
    gload_lds16(Brow0, &Bs[0][s_b0]);
    gload_lds16(Brow1, &Bs[0][s_b0 + 2048]);

    for (int i = 0; i < T; ++i) {
        __syncthreads();   // drains tile-i loads (issued one compute-phase ago)
        const int cur = i & 1;
        if (i + 1 < T) {
            const int nb = cur ^ 1;
            const int ko = (i + 1) << 5;
            gload_lds16(Arow0 + ko, &As[nb][s_b0]);
            gload_lds16(Arow1 + ko, &As[nb][s_b0 + 2048]);
            gload_lds16(Brow0 + ko, &Bs[nb][s_b0]);
            gload_lds16(Brow1 + ko, &Bs[nb][s_b0 + 2048]);
        }
        bf16x8 af[4], bg[4];
        #pragma unroll
        for (int j = 0; j < 4; ++j) {
            af[j] = *(const bf16x8*)&As[cur][(wm + j * 16 + fr) * 32 + qd * 8];
            bg[j] = *(const bf16x8*)&Bs[cur][(wn + j * 16 + fr) * 32 + qd * 8];
        }
        #pragma unroll
        for (int mi = 0; mi < 4; ++mi)
            #pragma unroll
            for (int ni = 0; ni < 4; ++ni)
                acc[mi][ni] = __builtin_amdgcn_mfma_f32_16x16x32_bf16(
                    af[mi], bg[ni], acc[mi][ni], 0, 0, 0);
    }

    #pragma unroll
    for (int mi = 0; mi < 4; ++mi) {
        #pragma unroll
        for (int i = 0; i < 4; ++i) {
            int rm = row0 + wm + mi * 16 + qd * 4 + i;
            if (rm >= M) continue;
            #pragma unroll
            for (int ni = 0; ni < 4; ++ni) {
                int cn = col0 + wn + ni * 16 + fr;
                if (cn >= N) continue;
                float v = acc[mi][ni][i] * scale;
                if (epi == 0) Cf[(size_t)rm * ldc + cn] = v;
                else if (epi == 1) { v += bias[cn]; v = v > 0.f ? v : 0.f;
                                Cb[(size_t)rm * ldcb + cn] = f2bf(v); }
                else if (epi == 2) Cf[(size_t)rm * ldc + cn] =
                                v + bias[cn] + bf2f(Cb[(size_t)rm * ldcb + cn]);
                else if (epi == 3) Cb[(size_t)rm * ldcb + cn] = f2bf(v);
                else if (epi == 4) { int bs = cn / DD_, cc = cn - bs * DD_;
                                Cb[(size_t)bs * (AROWS_ * KP_) + (size_t)rm * KP_ + cc] = f2bf(v); }
                else if (epi == 5) { float invz = 1.0f / bias[rm];
                                Cb[(size_t)rm * ldcb + cn] = f2bf(v * invz); }
                else if (epi == 6) Cf[(size_t)rm * ldc + cn] = v + bias[cn];
            }
        }
    }
}

template<int EPI>
__global__ __launch_bounds__(256, 4)
void bgemm(const u16* __restrict__ A, int lda,
           const u16* __restrict__ Bm, int ldb,
           int M, int N, int K, float scale,
           float* __restrict__ Cf, int ldc,
           u16* __restrict__ Cb, int ldcb,
           const float* __restrict__ bias,
           int nxt, int swiz)
{
    gemm_body(A, lda, Bm, ldb, M, N, K, scale, Cf, ldc, Cb, ldcb, bias,
              nxt, swiz, EPI, blockIdx.x);
}

// Grouped GEMM: up to 3 independent sub-GEMMs co-scheduled in one launch
// (graph-captured stream is strictly serial; this is the only way to fill
// the machine with several small underfilled GEMMs at once).
struct GDesc {
    const u16* A; const u16* B; float* Cf; u16* Cb; const float* bias;
    int lda, ldb, ldc, ldcb, M, N, K, epi, nxt, swiz, blk0;
    float scale;
};
struct GPack { GDesc d[3]; int n; };

__global__ __launch_bounds__(256, 4)
void gbgemm(GPack p)
{
    int id = blockIdx.x;
    int si = 0;
    for (int s = 1; s < p.n; ++s) if (id >= p.d[s].blk0) si = s;
    GDesc D = p.d[si];
    gemm_body(D.A, D.lda, D.B, D.ldb, D.M, D.N, D.K, D.scale,
              D.Cf, D.ldc, D.Cb, D.ldcb, D.bias, D.nxt, D.swiz, D.epi,
              id - D.blk0);
}

// Multi-segment fp32->bf16 cast (+ zero-fill segments with scols=0):
// dst[r*drs+c] = (c<scols) ? bf16(src[r*srs+c]) : 0, for c < dcols.
struct CDesc { const float* src; u16* dst; int srs, drs, dcols, scols; };
struct CPack { CDesc d[8]; unsigned cum[9]; int n; };

__global__ void kern_mcast(CPack p)
{
    unsigned idx = blockIdx.x * 256 + threadIdx.x;
    int si = -1;
    for (int s = 0; s < p.n; ++s)
        if (idx >= p.cum[s] && idx < p.cum[s + 1]) { si = s; break; }
    if (si < 0) return;
    CDesc D = p.d[si];
    unsigned k = idx - p.cum[si];
    int r = k / D.dcols, c = k - r * D.dcols;
    D.dst[(size_t)r * D.drs + c] =
        (c < D.scols) ? f2bf(D.src[(size_t)r * D.srs + c]) : (u16)0;
}

// Coalesced LDS-tiled cast-transpose: dst[c][r] = (r<rows ? src[r][c] : 0),
// r < padrows, c < cols. 32x32 tiles, 256 threads (32x8).
__global__ __launch_bounds__(256) void kern_castT32(
    const float* __restrict__ src, int srs, u16* __restrict__ dst, int drs,
    int rows, int cols, int padrows)
{
    __shared__ float t[32][33];
    int r0 = blockIdx.x * 32, c0 = blockIdx.y * 32;
    int tx = threadIdx.x & 31, ty = threadIdx.x >> 5;
    #pragma unroll
    for (int k = 0; k < 4; ++k) {
        int r = r0 + ty + k * 8, c = c0 + tx;
        t[ty + k * 8][tx] = (r < rows && c < cols) ? src[(size_t)r * srs + c] : 0.f;
    }
    __syncthreads();
    #pragma unroll
    for (int k = 0; k < 4; ++k) {
        int c = c0 + ty + k * 8, r = r0 + tx;
        if (c < cols && r < padrows)
            dst[(size_t)c * drs + r] = f2bf(t[tx][ty + k * 8]);
    }
}

// Dense 14x14 GCN adjacency (self-loops + symmetric norm)
__global__ void kern_adj(const int* __restrict__ ei, float* __restrict__ Adj)
{
    if (threadIdx.x != 0 || blockIdx.x != 0) return;
    float deg[NN_];
    for (int i = 0; i < NN_; ++i) deg[i] = 1.f;
    for (int e = 0; e < EE_; ++e) deg[ei[EE_ + e]] += 1.f;
    float dinv[NN_];
    for (int i = 0; i < NN_; ++i) dinv[i] = rsqrtf(deg[i]);
    float adj[NN_ * NN_];
    for (int t = 0; t < NN_ * NN_; ++t) adj[t] = 0.f;
    for (int e = 0; e < EE_; ++e) {
        int s = ei[e], d = ei[EE_ + e];
        adj[d * NN_ + s] += dinv[s] * dinv[d];
    }
    for (int i = 0; i < NN_; ++i) adj[i * NN_ + i] += dinv[i] * dinv[i];
    for (int t = 0; t < NN_ * NN_; ++t) Adj[t] = adj[t];
}

// row -> exp(row - rowmax), rows of length 1024, in place (ew rows)
__global__ __launch_bounds__(256) void kern_exp_rows(float* __restrict__ S)
{
    __shared__ float red[256];
    float* row = S + (size_t)blockIdx.x * 1024;
    float m = -1e30f;
    for (int i = threadIdx.x; i < 1024; i += 256) m = fmaxf(m, row[i]);
    red[threadIdx.x] = m; __syncthreads();
    for (int s = 128; s > 0; s >>= 1) {
        if (threadIdx.x < s) red[threadIdx.x] = fmaxf(red[threadIdx.x], red[threadIdx.x + s]);
        __syncthreads();
    }
    m = red[0];
    for (int i = threadIdx.x; i < 1024; i += 256) row[i] = expf(row[i] - m);
}

// Fused exp + G + Z, low-barrier version: block l computes rowmax (2 barriers),
// then each WAVE owns z = wv, wv+4, ... with a private full exp vector
// (ev[16]: m = lane + 64j) and butterfly-reduced Z — no barriers in the z-loop
// (round-7 version had 2 barriers per z = 28/block).
// S rows 0..1023 = raw S0; rows 1024..1037 = ew (already exp'd).
__global__ __launch_bounds__(256) void kern_eG(const float* __restrict__ S,
    u16* __restrict__ Gb, float* __restrict__ Z)
{
    __shared__ float red[256];
    const int l = blockIdx.x, tid = threadIdx.x;
    const int lane = tid & 63, wv = tid >> 6;
    const float* row = S + (size_t)l * 1024;
    float m = -1e30f;
    #pragma unroll
    for (int k = 0; k < 4; ++k) m = fmaxf(m, row[tid + 256 * k]);
    red[tid] = m; __syncthreads();
    for (int s = 128; s > 0; s >>= 1) {
        if (tid < s) red[tid] = fmaxf(red[tid], red[tid + s]);
        __syncthreads();
    }
    m = red[0];
    float ev[16];
    #pragma unroll
    for (int j = 0; j < 16; ++j) ev[j] = expf(row[lane + 64 * j] - m);
    const float* ew = S + 1024 * 1024;
    u16* gr = Gb + (size_t)l * NN_ * 1024;
    for (int z = wv; z < NN_; z += 4) {
        const float* er = ew + z * 1024;
        float s = 0.f;
        #pragma unroll
        for (int j = 0; j < 16; ++j) {
            float pv = ev[j] * er[lane + 64 * j];
            gr[(size_t)z * 1024 + lane + 64 * j] = f2bf(pv);
            s += pv;
        }
        #pragma unroll
        for (int off = 32; off > 0; off >>= 1) s += __shfl_down(s, off);
        if (lane == 0) Z[l * NN_ + z] = s;
    }
}

// x1 = LN1(node + Pb + co); Pb is bf16 attn-out already scaled by 1/Z.
__global__ __launch_bounds__(256) void kern_ln1(
    const float* __restrict__ img, const float* __restrict__ word,
    const u16* __restrict__ Pb,
    const float* __restrict__ co, const float* __restrict__ g,
    const float* __restrict__ bta, u16* __restrict__ Xb)
{
    __shared__ float buf[DD_];
    __shared__ float red[256];
    __shared__ float stats[2];
    int row = blockIdx.x;
    int b = row / NN_, n = row - b * NN_;
    const u16* pr = Pb + (size_t)row * DD_;
    const float* cr = co + n * DD_;
    float s = 0.f;
    for (int d = threadIdx.x; d < DD_; d += 256) {
        float v = (d < IMG_) ? img[(size_t)b * IMG_ + d] : word[n * TXT_ + d - IMG_];
        v += bf2f(pr[d]) + cr[d];
        buf[d] = v; s += v;
    }
    red[threadIdx.x] = s; __syncthreads();
    for (int t = 128; t > 0; t >>= 1) {
        if (threadIdx.x < t) red[threadIdx.x] += red[threadIdx.x + t];
        __syncthreads();
    }
    if (threadIdx.x == 0) stats[0] = red[0] / DD_;
    __syncthreads();
    float mu = stats[0], s2 = 0.f;
    for (int d = threadIdx.x; d < DD_; d += 256) { float t = buf[d] - mu; s2 += t * t; }
    red[threadIdx.x] = s2; __syncthreads();
    for (int t = 128; t > 0; t >>= 1) {
        if (threadIdx.x < t) red[threadIdx.x] += red[threadIdx.x + t];
        __syncthreads();
    }
    if (threadIdx.x == 0) stats[1] = rsqrtf(red[0] / DD_ + 1e-5f);
    __syncthreads();
    float rstd = stats[1];
    u16* xb = Xb + (size_t)row * KP_;
    for (int d = threadIdx.x; d < DD_; d += 256)
        xb[d] = f2bf((buf[d] - mu) * rstd * g[d] + bta[d]);
    for (int d = DD_ + threadIdx.x; d < KP_; d += 256) xb[d] = 0;
}

// LN2: reads fp32 Y (FFN2 output), writes bf16 X2b (pads zeroed).
__global__ __launch_bounds__(256) void kern_ln2(const float* __restrict__ X,
    const float* __restrict__ g, const float* __restrict__ bta, u16* __restrict__ Xb)
{
    __shared__ float buf[DD_];
    __shared__ float red[256];
    __shared__ float stats[2];
    const float* xr = X + (size_t)blockIdx.x * DD_;
    float s = 0.f;
    for (int d = threadIdx.x; d < DD_; d += 256) { float v = xr[d]; buf[d] = v; s += v; }
    red[threadIdx.x] = s; __syncthreads();
    for (int t = 128; t > 0; t >>= 1) {
        if (threadIdx.x < t) red[threadIdx.x] += red[threadIdx.x + t];
        __syncthreads();
    }
    if (threadIdx.x == 0) stats[0] = red[0] / DD_;
    __syncthreads();
    float mu = stats[0], s2 = 0.f;
    for (int d = threadIdx.x; d < DD_; d += 256) { float t = buf[d] - mu; s2 += t * t; }
    red[threadIdx.x] = s2; __syncthreads();
    for (int t = 128; t > 0; t >>= 1) {
        if (threadIdx.x < t) red[threadIdx.x] += red[threadIdx.x + t];
        __syncthreads();
    }
    if (threadIdx.x == 0) stats[1] = rsqrtf(red[0] / DD_ + 1e-5f);
    __syncthreads();
    float rstd = stats[1];
    u16* xb = Xb + (size_t)blockIdx.x * KP_;
    for (int d = threadIdx.x; d < DD_; d += 256)
        xb[d] = f2bf((buf[d] - mu) * rstd * g[d] + bta[d]);
    for (int d = DD_ + threadIdx.x; d < KP_; d += 256) xb[d] = 0;
}

// g1 = relu(Adj @ h1 + bias) -> bf16
__global__ __launch_bounds__(256) void kern_agg1(const float* __restrict__ H,
    const float* __restrict__ Adj, const float* __restrict__ bias, u16* __restrict__ G)
{
    __shared__ float sA[NN_ * NN_];
    if (threadIdx.x < NN_ * NN_) sA[threadIdx.x] = Adj[threadIdx.x];
    __syncthreads();
    int t = blockIdx.x * 256 + threadIdx.x;
    int b = t >> 7, f = t & 127;
    float v[NN_];
    #pragma unroll
    for (int i = 0; i < NN_; ++i) v[i] = H[((size_t)b * NN_ + i) * HID_ + f];
    float bb = bias[f];
    #pragma unroll
    for (int j = 0; j < NN_; ++j) {
        float s = bb;
        #pragma unroll
        for (int i = 0; i < NN_; ++i) s = fmaf(sA[j * NN_ + i], v[i], s);
        G[((size_t)b * NN_ + j) * HID_ + f] = f2bf(s > 0.f ? s : 0.f);
    }
}

// pool = relu(mean_j(Adj @ h2 + bias))
__global__ __launch_bounds__(256) void kern_agg2_pool(const float* __restrict__ H,
    const float* __restrict__ Adj, const float* __restrict__ bias, float* __restrict__ P)
{
    __shared__ float sA[NN_ * NN_];
    if (threadIdx.x < NN_ * NN_) sA[threadIdx.x] = Adj[threadIdx.x];
    __syncthreads();
    int t = blockIdx.x * 256 + threadIdx.x;
    int b = t >> 7, f = t & 127;
    float v[NN_];
    #pragma unroll
    for (int i = 0; i < NN_; ++i) v[i] = H[((size_t)b * NN_ + i) * HID_ + f];
    float acc = 0.f;
    #pragma unroll
    for (int j = 0; j < NN_; ++j) {
        float s = 0.f;
        #pragma unroll
        for (int i = 0; i < NN_; ++i) s = fmaf(sA[j * NN_ + i], v[i], s);
        acc += s;
    }
    acc = acc / (float)NN_ + bias[f];
    P[(size_t)b * HID_ + f] = acc > 0.f ? acc : 0.f;
}

__global__ void kern_lin(const float* __restrict__ pool, const float* __restrict__ W,
                         const float* __restrict__ bias, float* __restrict__ out)
{
    int t = blockIdx.x * 256 + threadIdx.x;
    if (t >= B_ * CC_) return;
    int b = t / CC_, c = t % CC_;
    float s = bias[c];
    const float* pr = pool + (size_t)b * HID_;
    for (int f = 0; f < HID_; ++f) s = fmaf(pr[f], W[f * CC_ + c], s);
    out[t] = s;
}

extern "C" void kernel_launch(void* const* d_in, const int* in_sizes, int n_in,
                              void* d_out, int out_size, void* d_ws, size_t ws_size,
                              hipStream_t stream)
{
    const float* img  = (const float*)d_in[0];
    const float* word = (const float*)d_in[1];
    const int*   ei   = (const int*)d_in[2];
    const float* Wi   = (const float*)d_in[3];
    const float* bi   = (const float*)d_in[4];
    const float* Wo   = (const float*)d_in[5];
    const float* bo   = (const float*)d_in[6];
    const float* g1   = (const float*)d_in[7];
    const float* bt1  = (const float*)d_in[8];
    const float* g2   = (const float*)d_in[9];
    const float* bt2  = (const float*)d_in[10];
    const float* W1   = (const float*)d_in[11];
    const float* bf1  = (const float*)d_in[12];
    const float* W2   = (const float*)d_in[13];
    const float* bf2  = (const float*)d_in[14];
    const float* Wg1  = (const float*)d_in[15];
    const float* bg1  = (const float*)d_in[16];
    const float* Wg2  = (const float*)d_in[17];
    const float* bg2  = (const float*)d_in[18];
    const float* Wl   = (const float*)d_in[19];
    const float* bl   = (const float*)d_in[20];
    float* out = (float*)d_out;

    char* ws = (char*)d_ws;
    u16*   imgb = (u16*)  (ws + OFF_IMGB);
    u16*   Wib  = (u16*)  (ws + OFF_WIB);
    u16*   wordb= (u16*)  (ws + OFF_WORDB);
    u16*   WiTX = (u16*)  (ws + OFF_WITX);
    u16*   Gb   = (u16*)  (ws + OFF_GB);
    float* Ebuf = (float*)(ws + OFF_EBUF);
    u16*   AvoT = (u16*)  (ws + OFF_AVOT);
    u16*   Wob  = (u16*)  (ws + OFF_WOB);
    u16*   Hb   = (u16*)  (ws + OFF_HB);
    float* H1   = (float*)(ws + OFF_H1);
    u16*   G1b  = (u16*)  (ws + OFF_G1B);
    float* H2   = (float*)(ws + OFF_H2);
    float* Pool = (float*)(ws + OFF_POOL);
    u16*   Pb   = (u16*)  (ws + OFF_PB);
    u16*   W1T  = (u16*)  (ws + OFF_W1T);
    u16*   W2T  = (u16*)  (ws + OFF_W2T);
    u16*   X1b  = (u16*)  (ws + OFF_X1B);
    u16*   X2b  = (u16*)  (ws + OFF_X1B);
    float* Yf   = (float*)(ws + OFF_YF);
    u16*   Aqb  = (u16*)  (ws + OFF_AQB);
    u16*   Akb  = Aqb + AROWS_ * KP_;
    u16*   Avb  = Aqb + 2 * AROWS_ * KP_;
    float* Tbuf = (float*)(ws + OFF_TBUF);
    u16*   Tvb  = (u16*)  (ws + OFF_TVB);
    float* co   = (float*)(ws + OFF_CO);
    float* Zb   = (float*)(ws + OFF_Z);
    float* Adj  = (float*)(ws + OFF_ADJ);
    u16*   Wg1T = (u16*)  (ws + OFF_WG1T);
    u16*   Wg2T = (u16*)  (ws + OFF_WG2T);

    const float scl = 1.0f / sqrtf((float)DD_);

    // --- one multi-cast launch: all input casts + Aq/Ak/Av K-pad zeroing ---
    {
        CPack p; p.n = 8;
        unsigned c = 0;
        auto seg = [&](int i, const float* s, int srs, u16* d, int drs,
                       int rows, int dcols, int scols) {
            p.d[i] = { s, d, srs, drs, dcols, scols };
            p.cum[i] = c; c += (unsigned)rows * dcols;
        };
        seg(0, img,        IMG_, imgb,  IMG_, B_,   IMG_, IMG_);
        seg(1, Wi,         DD_,  Wib,   IMG_, D3_,  IMG_, IMG_);
        seg(2, word,       TXT_, wordb, TXP_, NN_,  TXP_, TXT_);
        seg(3, Wi + IMG_,  DD_,  WiTX,  TXP_, D3_,  TXP_, TXT_);
        seg(4, Wo,         DD_,  Wob,   KP_,  DD_,  KP_,  DD_);
        seg(5, nullptr, 0, Aqb + DD_,                    KP_, 1024, 20, 0);
        seg(6, nullptr, 0, Aqb + AROWS_ * KP_ + DD_,     KP_, 1024, 20, 0);
        seg(7, nullptr, 0, Aqb + 2 * AROWS_ * KP_ + DD_, KP_, 1024, 20, 0);
        p.cum[8] = c;
        kern_mcast<<<(c + 255) / 256, 256, 0, stream>>>(p);
    }
    kern_adj<<<1, 64, 0, stream>>>(ei, Adj);
    // GCN weight transposes depend only on inputs -> do them early
    kern_castT32<<<dim3(26, 4), 256, 0, stream>>>(Wg1, HID_, Wg1T, KP_, DD_, HID_, KP_);
    kern_castT32<<<dim3(4, 4), 256, 0, stream>>>(Wg2, HID_, Wg2T, HID_, HID_, HID_, HID_);

    // --- Group1: T = word@WiTX^T + bi  ||  [Aq|Ak|Av] = img@Wi[:,:512]^T ---
    {
        GPack p; p.n = 2;
        p.d[0] = { wordb, WiTX, Tbuf, nullptr, bi,
                   TXP_, TXP_, D3_, 0, NN_, D3_, TXP_, 6, 20, 0, 0, 1.f };
        p.d[1] = { imgb, Wib, nullptr, Aqb, nullptr,
                   IMG_, IMG_, 0, 0, B_, D3_, IMG_, 4, 20, 1, 20, 1.f };
        gbgemm<<<20 + 160, 256, 0, stream>>>(p);
    }
    // Tq -> Aq rows 1024..1037 ; Tv -> Tvb (K-pads zeroed)
    {
        CPack p; p.n = 2;
        p.d[0] = { Tbuf,           Aqb + 1024 * KP_, D3_, KP_, KP_, DD_ };
        p.d[1] = { Tbuf + 2 * DD_, Tvb,              D3_, KP_, KP_, DD_ };
        p.cum[0] = 0; p.cum[1] = NN_ * KP_; p.cum[2] = 2 * NN_ * KP_;
        kern_mcast<<<(2 * NN_ * KP_ + 255) / 256, 256, 0, stream>>>(p);
    }

    // --- Group2: S0+w (M=1038) || AvoT = Wo@Av^T || co = Tv@Wo^T + bo ---
    {
        GPack p; p.n = 3;
        p.d[0] = { Aqb, Akb, Ebuf, nullptr, nullptr,
                   KP_, KP_, 1024, 0, 1024 + NN_, 1024, KP_, 0, 8, 0, 0, scl };
        p.d[1] = { Wob, Avb, nullptr, AvoT, nullptr,
                   KP_, KP_, 0, 1024, DD_, B_, KP_, 3, 8, 0, 72, 1.f };
        p.d[2] = { Tvb, Wob, co, nullptr, bo,
                   KP_, KP_, DD_, 0, NN_, DD_, KP_, 6, 7, 0, 128, 1.f };
        gbgemm<<<72 + 56 + 7, 256, 0, stream>>>(p);
    }
    kern_exp_rows<<<NN_, 256, 0, stream>>>(Ebuf + 1024 * 1024);   // ew rows

    // --- fused exp + G + Z (low-barrier) ---
    kern_eG<<<1024, 256, 0, stream>>>(Ebuf, Gb, Zb);

    // --- Pb = (G @ Avo)/Z as bf16 ---
    bgemm<5><<<7 * 112, 256, 0, stream>>>(Gb, 1024, AvoT, 1024,
        BNR_, DD_, 1024, 1.f, nullptr, 0, Pb, DD_, Zb, 7, 1);

    // --- LN1 ---
    kern_ln1<<<BNR_, 256, 0, stream>>>(img, word, Pb, co, g1, bt1, X1b);

    // --- FFN weight transposes (AFTER ln1 — W1T overlays Pb) ---
    kern_castT32<<<dim3(26, 64), 256, 0, stream>>>(W1, FF_, W1T, KP_, DD_, FF_, KP_);
    kern_castT32<<<dim3(64, 26), 256, 0, stream>>>(W2, DD_, W2T, FF_, FF_, DD_, FF_);

    // --- FFN (bf16 MFMA), LN2 ---
    bgemm<1><<<16 * 112, 256, 0, stream>>>(X1b, KP_, W1T, KP_,
        BNR_, FF_, KP_, 1.f, nullptr, 0, Hb, FF_, bf1, 16, 1);
    bgemm<2><<<7 * 112, 256, 0, stream>>>(Hb, FF_, W2T, FF_,
        BNR_, DD_, FF_, 1.f, Yf, DD_, X1b, KP_, bf2, 7, 1);
    kern_ln2<<<BNR_, 256, 0, stream>>>(Yf, g2, bt2, X2b);

    // --- GCN ---
    bgemm<0><<<1 * 112, 256, 0, stream>>>(X2b, KP_, Wg1T, KP_,
        BNR_, HID_, KP_, 1.f, H1, HID_, nullptr, 0, nullptr, 1, 0);
    kern_agg1<<<(B_ * HID_) / 256, 256, 0, stream>>>(H1, Adj, bg1, G1b);
    bgemm<0><<<1 * 112, 256, 0, stream>>>(G1b, HID_, Wg2T, HID_,
        BNR_, HID_, HID_, 1.f, H2, HID_, nullptr, 0, nullptr, 1, 0);
    kern_agg2_pool<<<(B_ * HID_) / 256, 256, 0, stream>>>(H2, Adj, bg2, Pool);
    kern_lin<<<(B_ * CC_) / 256, 256, 0, stream>>>(Pool, Wl, bl, out);
}

// Round 9
// 576.697 us; speedup vs baseline: 4.2326x; 1.0110x over previous
//
#include <hip/hip_runtime.h>
#include <math.h>

// Problem constants
#define B_    1024
#define IMG_  512
#define TXT_  300
#define NN_   14
#define FF_   2048
#define HID_  128
#define CC_   14
#define EE_   182
#define DD_   812
#define D3_   2436
#define BNR_  14336          // B_*NN_
#define KP_   832            // 812 padded to /32 (16B-aligned rows)
#define TXP_  320            // 300 padded to /32
#define AROWS_ 1152          // Aq/Ak/Av rows: 1024 data + 14 Tq + pad to tile mult

typedef __bf16 bf16x8 __attribute__((ext_vector_type(8)));
typedef float  f32x4  __attribute__((ext_vector_type(4)));
typedef unsigned short u16;

__device__ __forceinline__ u16 f2bf(float f) {
    union { float f; unsigned u; } v; v.f = f;
    unsigned r = v.u + 0x7FFFu + ((v.u >> 16) & 1u);   // RNE
    return (u16)(r >> 16);
}
__device__ __forceinline__ float bf2f(u16 h) {
    union { unsigned u; float f; } v; v.u = ((unsigned)h) << 16; return v.f;
}

// async global->LDS, 16B per lane. LDS dst = wave-uniform base + lane*16.
__device__ __forceinline__ void gload_lds16(const u16* g, u16* l) {
    __builtin_amdgcn_global_load_lds(
        (const __attribute__((address_space(1))) void*)g,
        (__attribute__((address_space(3))) void*)l, 16, 0, 0);
}

// ---------------------------------------------------------------------------
// Workspace layout (bytes), time-multiplexed overlays (audited vs launch
// timeline; garbage/NaN only reaches epilogue-masked rows/cols; K-pads of
// real rows always explicitly zeroed on at least one GEMM operand side,
// with the OTHER side guaranteed non-NaN -> product 0).
// ---------------------------------------------------------------------------
#define OFF_IMGB  0ULL              // bf16 [1024][512]   (dead after G1)
#define OFF_WIB   1048576ULL        // bf16 [2436][512]
#define OFF_WORDB 3543040ULL        // bf16 [128][320]
#define OFF_WITX  3624960ULL        // bf16 [2560][320]
#define OFF_GB    0ULL              // bf16 [14336][1024] (eG..P)
#define OFF_EBUF  29360128ULL       // f32  [1038][1024]  (S0..eG)
#define OFF_AVOT  33611776ULL       // bf16 [896][1024]   (G2..P)
#define OFF_WOB   35446784ULL       // bf16 [896][832]    (mcast..G2)
#define OFF_HB    0ULL              // bf16 [14336][2048] (FFN1..FFN2)
#define OFF_PB    58720256ULL       // bf16 [14336][812]  (P..ln1)
#define OFF_X1B   82001920ULL       // bf16 [14336][832]  (ln1..FFN2)
#define OFF_YB    105857024ULL      // bf16 [14336][832]  (FFN2..gcn)
#define OFF_W1T   129712128ULL      // bf16 [2048][832]
#define OFF_W2T   133120000ULL      // bf16 [896][2048]
#define OFF_AQB   152420352ULL      // bf16 3x[1152][832] (Aq|Ak|Av)
#define OFF_TBUF  158171136ULL      // f32  [14][2436]
#define OFF_TVB   158307552ULL      // bf16 [128][832]
#define OFF_CO    158520544ULL      // f32  [14][812]
#define OFF_Z     158566016ULL      // f32  [14336]
#define OFF_ADJ   158623360ULL      // f32  [196 adj + 16 colw]
#define OFF_WG1T  158624384ULL      // bf16 [128][832]
#define OFF_WG2T  158837376ULL     // bf16 [128][128]

// ---------------------------------------------------------------------------
// Shared GEMM pipeline body: C[M,N] = scale * A[M,K] @ B^T (B stored [N][K]).
// 128x128 tile, BK=32, 4 waves (2x2 of 64x64), 16x16x32 MFMA, double-buffered
// global_load_lds staging. K%32==0; K-pads zeroed; buffers readable to
// 128-row multiples; M/N edges masked in epilogue. swiz=1: id%8 -> row-tile.
// epi 0: Cf=v. 1: Cb=bf16(relu(v+bias[cn])). 2: Cf=v+bias[cn]+bf2f(Cb).
// 3: Cb=bf16(v). 4: split-3 into [Aq|Ak|Av]. 5: Cb=bf16(v/bias[rm]).
// 6: Cf=v+bias[cn]. 7: Cb=bf16(v+bias[cn]+bf2f(((u16*)Cf)[rm*ldc+cn])).
// ---------------------------------------------------------------------------
__device__ __forceinline__ void gemm_body(
    const u16* __restrict__ A, int lda,
    const u16* __restrict__ Bm, int ldb,
    int M, int N, int K, float scale,
    float* __restrict__ Cf, int ldc,
    u16* __restrict__ Cb, int ldcb,
    const float* __restrict__ bias,
    int nxt, int swiz, int epi, int id)
{
    __shared__ __align__(16) u16 As[2][128 * 32];
    __shared__ __align__(16) u16 Bs[2][128 * 32];
    const int tid = threadIdx.x;
    int bx, by;
    if (swiz) { int r8 = id & 7; int q = id >> 3; bx = q % nxt; by = (q / nxt) * 8 + r8; }
    else      { bx = id % nxt; by = id / nxt; }
    const int row0 = by * 128, col0 = bx * 128;
    const int lane = tid & 63, wv = tid >> 6;
    const int wm = (wv >> 1) * 64, wn = (wv & 1) * 64;
    const int fr = lane & 15, qd = lane >> 4;

    const int s_r0  = (wv * 64 + lane) >> 2;
    const int s_ko  = (lane & 3) * 8;
    const int s_b0  = (wv * 64) * 8;
    const u16* Arow0 = A  + (size_t)(row0 + s_r0) * lda + s_ko;
    const u16* Arow1 = A  + (size_t)(row0 + s_r0 + 64) * lda + s_ko;
    const u16* Brow0 = Bm + (size_t)(col0 + s_r0) * ldb + s_ko;
    const u16* Brow1 = Bm + (size_t)(col0 + s_r0 + 64) * ldb + s_ko;

    f32x4 acc[4][4] = {};

    const int T = K >> 5;
    gload_lds16(Arow0, &As[0][s_b0]);
    gload_lds16(Arow1, &As[0][s_b0 + 2048]);
    gload_lds16(Brow0, &Bs[0][s_b0]);
    gload_lds16(Brow1, &Bs[0][s_b0 + 2048]);

    for (int i = 0; i < T; ++i) {
        __syncthreads();
        const int cur = i & 1;
        if (i + 1 < T) {
            const int nb = cur ^ 1;
            const int ko = (i + 1) << 5;
            gload_lds16(Arow0 + ko, &As[nb][s_b0]);
            gload_lds16(Arow1 + ko, &As[nb][s_b0 + 2048]);
            gload_lds16(Brow0 + ko, &Bs[nb][s_b0]);
            gload_lds16(Brow1 + ko, &Bs[nb][s_b0 + 2048]);
        }
        bf16x8 af[4], bg[4];
        #pragma unroll
        for (int j = 0; j < 4; ++j) {
            af[j] = *(const bf16x8*)&As[cur][(wm + j * 16 + fr) * 32 + qd * 8];
            bg[j] = *(const bf16x8*)&Bs[cur][(wn + j * 16 + fr) * 32 + qd * 8];
        }
        #pragma unroll
        for (int mi = 0; mi < 4; ++mi)
            #pragma unroll
            for (int ni = 0; ni < 4; ++ni)
                acc[mi][ni] = __builtin_amdgcn_mfma_f32_16x16x32_bf16(
                    af[mi], bg[ni], acc[mi][ni], 0, 0, 0);
    }

    #pragma unroll
    for (int mi = 0; mi < 4; ++mi) {
        #pragma unroll
        for (int i = 0; i < 4; ++i) {
            int rm = row0 + wm + mi * 16 + qd * 4 + i;
            if (rm >= M) continue;
            #pragma unroll
            for (int ni = 0; ni < 4; ++ni) {
                int cn = col0 + wn + ni * 16 + fr;
                if (cn >= N) continue;
                float v = acc[mi][ni][i] * scale;
                if (epi == 0) Cf[(size_t)rm * ldc + cn] = v;
                else if (epi == 1) { v += bias[cn]; v = v > 0.f ? v : 0.f;
                                Cb[(size_t)rm * ldcb + cn] = f2bf(v); }
                else if (epi == 2) Cf[(size_t)rm * ldc + cn] =
                                v + bias[cn] + bf2f(Cb[(size_t)rm * ldcb + cn]);
                else if (epi == 3) Cb[(size_t)rm * ldcb + cn] = f2bf(v);
                else if (epi == 4) { int bs = cn / DD_, cc = cn - bs * DD_;
                                Cb[(size_t)bs * (AROWS_ * KP_) + (size_t)rm * KP_ + cc] = f2bf(v); }
                else if (epi == 5) { float invz = 1.0f / bias[rm];
                                Cb[(size_t)rm * ldcb + cn] = f2bf(v * invz); }
                else if (epi == 6) Cf[(size_t)rm * ldc + cn] = v + bias[cn];
                else if (epi == 7) { const u16* rx = (const u16*)Cf;
                                Cb[(size_t)rm * ldcb + cn] =
                                    f2bf(v + bias[cn] + bf2f(rx[(size_t)rm * ldc + cn])); }
            }
        }
    }
}

template<int EPI>
__global__ __launch_bounds__(256, 4)
void bgemm(const u16* __restrict__ A, int lda,
           const u16* __restrict__ Bm, int ldb,
           int M, int N, int K, float scale,
           float* __restrict__ Cf, int ldc,
           u16* __restrict__ Cb, int ldcb,
           const float* __restrict__ bias,
           int nxt, int swiz)
{
    gemm_body(A, lda, Bm, ldb, M, N, K, scale, Cf, ldc, Cb, ldcb, bias,
              nxt, swiz, EPI, blockIdx.x);
}

// Grouped GEMM: up to 3 independent sub-GEMMs co-scheduled in one launch.
struct GDesc {
    const u16* A; const u16* B; float* Cf; u16* Cb; const float* bias;
    int lda, ldb, ldc, ldcb, M, N, K, epi, nxt, swiz, blk0;
    float scale;
};
struct GPack { GDesc d[3]; int n; };

__global__ __launch_bounds__(256, 4)
void gbgemm(GPack p)
{
    int id = blockIdx.x;
    int si = 0;
    for (int s = 1; s < p.n; ++s) if (id >= p.d[s].blk0) si = s;
    GDesc D = p.d[si];
    gemm_body(D.A, D.lda, D.B, D.ldb, D.M, D.N, D.K, D.scale,
              D.Cf, D.ldc, D.Cb, D.ldcb, D.bias, D.nxt, D.swiz, D.epi,
              id - D.blk0);
}

// Multi-segment fp32->bf16 cast (+ zero-fill segments with scols=0).
struct CDesc { const float* src; u16* dst; int srs, drs, dcols, scols; };
struct CPack { CDesc d[8]; unsigned cum[9]; int n; };

__global__ void kern_mcast(CPack p)
{
    unsigned idx = blockIdx.x * 256 + threadIdx.x;
    int si = -1;
    for (int s = 0; s < p.n; ++s)
        if (idx >= p.cum[s] && idx < p.cum[s + 1]) { si = s; break; }
    if (si < 0) return;
    CDesc D = p.d[si];
    unsigned k = idx - p.cum[si];
    int r = k / D.dcols, c = k - r * D.dcols;
    D.dst[(size_t)r * D.drs + c] =
        (c < D.scols) ? f2bf(D.src[(size_t)r * D.srs + c]) : (u16)0;
}

// Coalesced LDS-tiled cast-transpose: dst[c][r] = (r<rows ? src[r][c] : 0),
// r < padrows, c < cols. 32x32 tiles, 256 threads (32x8).
__global__ __launch_bounds__(256) void kern_castT32(
    const float* __restrict__ src, int srs, u16* __restrict__ dst, int drs,
    int rows, int cols, int padrows)
{
    __shared__ float t[32][33];
    int r0 = blockIdx.x * 32, c0 = blockIdx.y * 32;
    int tx = threadIdx.x & 31, ty = threadIdx.x >> 5;
    #pragma unroll
    for (int k = 0; k < 4; ++k) {
        int r = r0 + ty + k * 8, c = c0 + tx;
        t[ty + k * 8][tx] = (r < rows && c < cols) ? src[(size_t)r * srs + c] : 0.f;
    }
    __syncthreads();
    #pragma unroll
    for (int k = 0; k < 4; ++k) {
        int c = c0 + ty + k * 8, r = r0 + tx;
        if (c < cols && r < padrows)
            dst[(size_t)c * drs + r] = f2bf(t[tx][ty + k * 8]);
    }
}

// Dense 14x14 GCN adjacency (self-loops + symmetric norm) + column means
// colw[i] = mean_j Adj[j,i] (mean-pool folded; [14..15]=0 for 16-row MFMA).
__global__ void kern_adj(const int* __restrict__ ei, float* __restrict__ Adj)
{
    if (threadIdx.x != 0 || blockIdx.x != 0) return;
    float deg[NN_];
    for (int i = 0; i < NN_; ++i) deg[i] = 1.f;
    for (int e = 0; e < EE_; ++e) deg[ei[EE_ + e]] += 1.f;
    float dinv[NN_];
    for (int i = 0; i < NN_; ++i) dinv[i] = rsqrtf(deg[i]);
    float adj[NN_ * NN_];
    for (int t = 0; t < NN_ * NN_; ++t) adj[t] = 0.f;
    for (int e = 0; e < EE_; ++e) {
        int s = ei[e], d = ei[EE_ + e];
        adj[d * NN_ + s] += dinv[s] * dinv[d];
    }
    for (int i = 0; i < NN_; ++i) adj[i * NN_ + i] += dinv[i] * dinv[i];
    for (int t = 0; t < NN_ * NN_; ++t) Adj[t] = adj[t];
    for (int i = 0; i < 16; ++i) {
        float s = 0.f;
        if (i < NN_) for (int j = 0; j < NN_; ++j) s += adj[j * NN_ + i];
        Adj[NN_ * NN_ + i] = s / (float)NN_;
    }
}

// row -> exp(row - rowmax), rows of length 1024, in place (ew rows)
__global__ __launch_bounds__(256) void kern_exp_rows(float* __restrict__ S)
{
    __shared__ float red[256];
    float* row = S + (size_t)blockIdx.x * 1024;
    float m = -1e30f;
    for (int i = threadIdx.x; i < 1024; i += 256) m = fmaxf(m, row[i]);
    red[threadIdx.x] = m; __syncthreads();
    for (int s = 128; s > 0; s >>= 1) {
        if (threadIdx.x < s) red[threadIdx.x] = fmaxf(red[threadIdx.x], red[threadIdx.x + s]);
        __syncthreads();
    }
    m = red[0];
    for (int i = threadIdx.x; i < 1024; i += 256) row[i] = expf(row[i] - m);
}

// Fused exp + G + Z, low-barrier (see round 8).
__global__ __launch_bounds__(256) void kern_eG(const float* __restrict__ S,
    u16* __restrict__ Gb, float* __restrict__ Z)
{
    __shared__ float red[256];
    const int l = blockIdx.x, tid = threadIdx.x;
    const int lane = tid & 63, wv = tid >> 6;
    const float* row = S + (size_t)l * 1024;
    float m = -1e30f;
    #pragma unroll
    for (int k = 0; k < 4; ++k) m = fmaxf(m, row[tid + 256 * k]);
    red[tid] = m; __syncthreads();
    for (int s = 128; s > 0; s >>= 1) {
        if (tid < s) red[tid] = fmaxf(red[tid], red[tid + s]);
        __syncthreads();
    }
    m = red[0];
    float ev[16];
    #pragma unroll
    for (int j = 0; j < 16; ++j) ev[j] = expf(row[lane + 64 * j] - m);
    const float* ew = S + 1024 * 1024;
    u16* gr = Gb + (size_t)l * NN_ * 1024;
    for (int z = wv; z < NN_; z += 4) {
        const float* er = ew + z * 1024;
        float s = 0.f;
        #pragma unroll
        for (int j = 0; j < 16; ++j) {
            float pv = ev[j] * er[lane + 64 * j];
            gr[(size_t)z * 1024 + lane + 64 * j] = f2bf(pv);
            s += pv;
        }
        #pragma unroll
        for (int off = 32; off > 0; off >>= 1) s += __shfl_down(s, off);
        if (lane == 0) Z[l * NN_ + z] = s;
    }
}

// x1 = LN1(node + Pb + co); Pb is bf16 attn-out already scaled by 1/Z.
__global__ __launch_bounds__(256) void kern_ln1(
    const float* __restrict__ img, const float* __restrict__ word,
    const u16* __restrict__ Pb,
    const float* __restrict__ co, const float* __restrict__ g,
    const float* __restrict__ bta, u16* __restrict__ Xb)
{
    __shared__ float buf[DD_];
    __shared__ float red[256];
    __shared__ float stats[2];
    int row = blockIdx.x;
    int b = row / NN_, n = row - b * NN_;
    const u16* pr = Pb + (size_t)row * DD_;
    const float* cr = co + n * DD_;
    float s = 0.f;
    for (int d = threadIdx.x; d < DD_; d += 256) {
        float v = (d < IMG_) ? img[(size_t)b * IMG_ + d] : word[n * TXT_ + d - IMG_];
        v += bf2f(pr[d]) + cr[d];
        buf[d] = v; s += v;
    }
    red[threadIdx.x] = s; __syncthreads();
    for (int t = 128; t > 0; t >>= 1) {
        if (threadIdx.x < t) red[threadIdx.x] += red[threadIdx.x + t];
        __syncthreads();
    }
    if (threadIdx.x == 0) stats[0] = red[0] / DD_;
    __syncthreads();
    float mu = stats[0], s2 = 0.f;
    for (int d = threadIdx.x; d < DD_; d += 256) { float t = buf[d] - mu; s2 += t * t; }
    red[threadIdx.x] = s2; __syncthreads();
    for (int t = 128; t > 0; t >>= 1) {
        if (threadIdx.x < t) red[threadIdx.x] += red[threadIdx.x + t];
        __syncthreads();
    }
    if (threadIdx.x == 0) stats[1] = rsqrtf(red[0] / DD_ + 1e-5f);
    __syncthreads();
    float rstd = stats[1];
    u16* xb = Xb + (size_t)row * KP_;
    for (int d = threadIdx.x; d < DD_; d += 256)
        xb[d] = f2bf((buf[d] - mu) * rstd * g[d] + bta[d]);
    for (int d = DD_ + threadIdx.x; d < KP_; d += 256) xb[d] = 0;
}

// ---------------------------------------------------------------------------
// Fused LN2 + GCN1 + GCN2 + mean-pool + linear. One block per image b.
// Yb: bf16 [BNR_][KP_] pre-LN2 (x1 + FFN out + bias).
// x2s stride 840 u16 (1680 B: bank step 4 -> ~2-way, free). 16-row M-tile
// (rows 14,15 zero). GCN1/GCN2 via 16x16x32 MFMA, B-operand read from L2.
// ---------------------------------------------------------------------------
#define X2S_ 840
#define G1S_ 136
__global__ __launch_bounds__(256, 3)
void kern_gcn(const u16* __restrict__ Yb,
              const float* __restrict__ g2v, const float* __restrict__ bt2,
              const u16* __restrict__ Wg1T, const float* __restrict__ bg1,
              const u16* __restrict__ Wg2T, const float* __restrict__ bg2,
              const float* __restrict__ Wl,  const float* __restrict__ bl,
              const float* __restrict__ AdjW, float* __restrict__ out)
{
    __shared__ __align__(16) u16 x2s[16 * X2S_];
    __shared__ __align__(16) float h1s[16 * 132];
    __shared__ __align__(16) u16 g1s[16 * G1S_];
    __shared__ float adj_s[NN_ * NN_];
    __shared__ float colw_s[16];
    __shared__ float pool_s[HID_];
    const int b = blockIdx.x, tid = threadIdx.x;
    const int lane = tid & 63, wv = tid >> 6;
    const int fr = lane & 15, qd = lane >> 4;

    if (tid < NN_ * NN_) adj_s[tid] = AdjW[tid];
    if (tid >= NN_ * NN_ && tid < NN_ * NN_ + 16) colw_s[tid - NN_ * NN_] = AdjW[tid];
    // zero x2s pad rows 14,15 and K-pad cols [812,840) of data rows; g1s pads
    for (int k = tid; k < 2 * X2S_; k += 256) x2s[14 * X2S_ + k] = 0;
    for (int k = tid; k < 14 * (X2S_ - DD_); k += 256) {
        int j = k / (X2S_ - DD_), c = k - j * (X2S_ - DD_);
        x2s[j * X2S_ + DD_ + c] = 0;
    }
    for (int k = tid; k < 2 * G1S_; k += 256) g1s[14 * G1S_ + k] = 0;

    // --- LN2 per node row (wave w handles rows w, w+4, ...) ---
    for (int j = wv; j < NN_; j += 4) {
        const u16* yr = Yb + (size_t)(b * NN_ + j) * KP_;
        float vv[13], s = 0.f;
        #pragma unroll
        for (int k = 0; k < 13; ++k) {
            int d = lane + 64 * k;
            float v = (d < DD_) ? bf2f(yr[d]) : 0.f;
            vv[k] = v; s += v;
        }
        #pragma unroll
        for (int off = 32; off > 0; off >>= 1) s += __shfl_down(s, off);
        s = __shfl(s, 0);
        float mu = s / (float)DD_, s2 = 0.f;
        #pragma unroll
        for (int k = 0; k < 13; ++k) {
            int d = lane + 64 * k;
            float t = (d < DD_) ? vv[k] - mu : 0.f;
            s2 += t * t;
        }
        #pragma unroll
        for (int off = 32; off > 0; off >>= 1) s2 += __shfl_down(s2, off);
        s2 = __shfl(s2, 0);
        float rstd = rsqrtf(s2 / (float)DD_ + 1e-5f);
        #pragma unroll
        for (int k = 0; k < 13; ++k) {
            int d = lane + 64 * k;
            if (d < DD_)
                x2s[j * X2S_ + d] = f2bf((vv[k] - mu) * rstd * g2v[d] + bt2[d]);
        }
    }
    __syncthreads();

    // --- GCN1: H1 = X2 @ Wg1 (MFMA, M=16, N=128, K=KP_); wave w: f in [w*32, w*32+32) ---
    {
        f32x4 acc[2] = {{}, {}};
        for (int k0 = 0; k0 < KP_; k0 += 32) {
            bf16x8 af = *(const bf16x8*)&x2s[fr * X2S_ + k0 + qd * 8];
            #pragma unroll
            for (int t = 0; t < 2; ++t) {
                bf16x8 bg = *(const bf16x8*)&Wg1T[(size_t)(wv * 32 + t * 16 + fr) * KP_ + k0 + qd * 8];
                acc[t] = __builtin_amdgcn_mfma_f32_16x16x32_bf16(af, bg, acc[t], 0, 0, 0);
            }
        }
        #pragma unroll
        for (int t = 0; t < 2; ++t)
            #pragma unroll
            for (int i = 0; i < 4; ++i)
                h1s[(qd * 4 + i) * 132 + wv * 32 + t * 16 + fr] = acc[t][i];
    }
    __syncthreads();

    // --- G1 = relu(Adj @ H1 + bg1) -> bf16 (A-operand for GCN2) ---
    {
        const int f = tid & 127, jj = (tid >> 7) * 7;
        #pragma unroll
        for (int j = 0; j < 7; ++j) {
            float s = bg1[f];
            #pragma unroll
            for (int i = 0; i < NN_; ++i)
                s = fmaf(adj_s[(jj + j) * NN_ + i], h1s[i * 132 + f], s);
            g1s[(jj + j) * G1S_ + f] = f2bf(s > 0.f ? s : 0.f);
        }
    }
    __syncthreads();

    // --- GCN2 (MFMA, K=128) + pool = relu(colw·H2 + bg2) ---
    {
        f32x4 acc[2] = {{}, {}};
        for (int k0 = 0; k0 < HID_; k0 += 32) {
            bf16x8 af = *(const bf16x8*)&g1s[fr * G1S_ + k0 + qd * 8];
            #pragma unroll
            for (int t = 0; t < 2; ++t) {
                bf16x8 bg = *(const bf16x8*)&Wg2T[(size_t)(wv * 32 + t * 16 + fr) * HID_ + k0 + qd * 8];
                acc[t] = __builtin_amdgcn_mfma_f32_16x16x32_bf16(af, bg, acc[t], 0, 0, 0);
            }
        }
        #pragma unroll
        for (int t = 0; t < 2; ++t) {
            float s = 0.f;
            #pragma unroll
            for (int i = 0; i < 4; ++i) s += colw_s[qd * 4 + i] * acc[t][i];
            s += __shfl_xor(s, 16);
            s += __shfl_xor(s, 32);
            if (qd == 0) {
                int f = wv * 32 + t * 16 + fr;
                float p = s + bg2[f];
                pool_s[f] = p > 0.f ? p : 0.f;
            }
        }
    }
    __syncthreads();

    // --- out = pool @ Wl + bl ---
    if (tid < CC_) {
        float s = bl[tid];
        #pragma unroll 8
        for (int f = 0; f < HID_; ++f)
            s = fmaf(pool_s[f], Wl[(size_t)f * CC_ + tid], s);
        out[(size_t)b * CC_ + tid] = s;
    }
}

extern "C" void kernel_launch(void* const* d_in, const int* in_sizes, int n_in,
                              void* d_out, int out_size, void* d_ws, size_t ws_size,
                              hipStream_t stream)
{
    const float* img  = (const float*)d_in[0];
    const float* word = (const float*)d_in[1];
    const int*   ei   = (const int*)d_in[2];
    const float* Wi   = (const float*)d_in[3];
    const float* bi   = (const float*)d_in[4];
    const float* Wo   = (const float*)d_in[5];
    const float* bo   = (const float*)d_in[6];
    const float* g1   = (const float*)d_in[7];
    const float* bt1  = (const float*)d_in[8];
    const float* g2   = (const float*)d_in[9];
    const float* bt2  = (const float*)d_in[10];
    const float* W1   = (const float*)d_in[11];
    const float* bf1  = (const float*)d_in[12];
    const float* W2   = (const float*)d_in[13];
    const float* bf2  = (const float*)d_in[14];
    const float* Wg1  = (const float*)d_in[15];
    const float* bg1  = (const float*)d_in[16];
    const float* Wg2  = (const float*)d_in[17];
    const float* bg2  = (const float*)d_in[18];
    const float* Wl   = (const float*)d_in[19];
    const float* bl   = (const float*)d_in[20];
    float* out = (float*)d_out;

    char* ws = (char*)d_ws;
    u16*   imgb = (u16*)  (ws + OFF_IMGB);
    u16*   Wib  = (u16*)  (ws + OFF_WIB);
    u16*   wordb= (u16*)  (ws + OFF_WORDB);
    u16*   WiTX = (u16*)  (ws + OFF_WITX);
    u16*   Gb   = (u16*)  (ws + OFF_GB);
    float* Ebuf = (float*)(ws + OFF_EBUF);
    u16*   AvoT = (u16*)  (ws + OFF_AVOT);
    u16*   Wob  = (u16*)  (ws + OFF_WOB);
    u16*   Hb   = (u16*)  (ws + OFF_HB);
    u16*   Pb   = (u16*)  (ws + OFF_PB);
    u16*   X1b  = (u16*)  (ws + OFF_X1B);
    u16*   Yb   = (u16*)  (ws + OFF_YB);
    u16*   W1T  = (u16*)  (ws + OFF_W1T);
    u16*   W2T  = (u16*)  (ws + OFF_W2T);
    u16*   Aqb  = (u16*)  (ws + OFF_AQB);
    u16*   Akb  = Aqb + AROWS_ * KP_;
    u16*   Avb  = Aqb + 2 * AROWS_ * KP_;
    float* Tbuf = (float*)(ws + OFF_TBUF);
    u16*   Tvb  = (u16*)  (ws + OFF_TVB);
    float* co   = (float*)(ws + OFF_CO);
    float* Zb   = (float*)(ws + OFF_Z);
    float* Adj  = (float*)(ws + OFF_ADJ);
    u16*   Wg1T = (u16*)  (ws + OFF_WG1T);
    u16*   Wg2T = (u16*)  (ws + OFF_WG2T);

    const float scl = 1.0f / sqrtf((float)DD_);

    // --- one multi-cast launch: all input casts + Aq/Ak/Av K-pad zeroing ---
    {
        CPack p; p.n = 8;
        unsigned c = 0;
        auto seg = [&](int i, const float* s, int srs, u16* d, int drs,
                       int rows, int dcols, int scols) {
            p.d[i] = { s, d, srs, drs, dcols, scols };
            p.cum[i] = c; c += (unsigned)rows * dcols;
        };
        seg(0, img,        IMG_, imgb,  IMG_, B_,   IMG_, IMG_);
        seg(1, Wi,         DD_,  Wib,   IMG_, D3_,  IMG_, IMG_);
        seg(2, word,       TXT_, wordb, TXP_, NN_,  TXP_, TXT_);
        seg(3, Wi + IMG_,  DD_,  WiTX,  TXP_, D3_,  TXP_, TXT_);
        seg(4, Wo,         DD_,  Wob,   KP_,  DD_,  KP_,  DD_);
        seg(5, nullptr, 0, Aqb + DD_,                    KP_, 1024, 20, 0);
        seg(6, nullptr, 0, Aqb + AROWS_ * KP_ + DD_,     KP_, 1024, 20, 0);
        seg(7, nullptr, 0, Aqb + 2 * AROWS_ * KP_ + DD_, KP_, 1024, 20, 0);
        p.cum[8] = c;
        kern_mcast<<<(c + 255) / 256, 256, 0, stream>>>(p);
    }
    kern_adj<<<1, 64, 0, stream>>>(ei, Adj);
    // weight transposes (input-only deps; dedicated buffers, any order)
    kern_castT32<<<dim3(26, 64), 256, 0, stream>>>(W1, FF_, W1T, KP_, DD_, FF_, KP_);
    kern_castT32<<<dim3(64, 26), 256, 0, stream>>>(W2, DD_, W2T, FF_, FF_, DD_, FF_);
    kern_castT32<<<dim3(26, 4), 256, 0, stream>>>(Wg1, HID_, Wg1T, KP_, DD_, HID_, KP_);
    kern_castT32<<<dim3(4, 4), 256, 0, stream>>>(Wg2, HID_, Wg2T, HID_, HID_, HID_, HID_);

    // --- Group1: T = word@WiTX^T + bi  ||  [Aq|Ak|Av] = img@Wi[:,:512]^T ---
    {
        GPack p; p.n = 2;
        p.d[0] = { wordb, WiTX, Tbuf, nullptr, bi,
                   TXP_, TXP_, D3_, 0, NN_, D3_, TXP_, 6, 20, 0, 0, 1.f };
        p.d[1] = { imgb, Wib, nullptr, Aqb, nullptr,
                   IMG_, IMG_, 0, 0, B_, D3_, IMG_, 4, 20, 1, 20, 1.f };
        gbgemm<<<20 + 160, 256, 0, stream>>>(p);
    }
    // Tq -> Aq rows 1024..1037 ; Tv -> Tvb (K-pads zeroed)
    {
        CPack p; p.n = 2;
        p.d[0] = { Tbuf,           Aqb + 1024 * KP_, D3_, KP_, KP_, DD_ };
        p.d[1] = { Tbuf + 2 * DD_, Tvb,              D3_, KP_, KP_, DD_ };
        p.cum[0] = 0; p.cum[1] = NN_ * KP_; p.cum[2] = 2 * NN_ * KP_;
        kern_mcast<<<(2 * NN_ * KP_ + 255) / 256, 256, 0, stream>>>(p);
    }

    // --- Group2: S0+w (M=1038) || AvoT = Wo@Av^T || co = Tv@Wo^T + bo ---
    {
        GPack p; p.n = 3;
        p.d[0] = { Aqb, Akb, Ebuf, nullptr, nullptr,
                   KP_, KP_, 1024, 0, 1024 + NN_, 1024, KP_, 0, 8, 0, 0, scl };
        p.d[1] = { Wob, Avb, nullptr, AvoT, nullptr,
                   KP_, KP_, 0, 1024, DD_, B_, KP_, 3, 8, 0, 72, 1.f };
        p.d[2] = { Tvb, Wob, co, nullptr, bo,
                   KP_, KP_, DD_, 0, NN_, DD_, KP_, 6, 7, 0, 128, 1.f };
        gbgemm<<<72 + 56 + 7, 256, 0, stream>>>(p);
    }
    kern_exp_rows<<<NN_, 256, 0, stream>>>(Ebuf + 1024 * 1024);   // ew rows

    // --- fused exp + G + Z ---
    kern_eG<<<1024, 256, 0, stream>>>(Ebuf, Gb, Zb);

    // --- Pb = (G @ Avo)/Z as bf16 ---
    bgemm<5><<<7 * 112, 256, 0, stream>>>(Gb, 1024, AvoT, 1024,
        BNR_, DD_, 1024, 1.f, nullptr, 0, Pb, DD_, Zb, 7, 1);

    // --- LN1 ---
    kern_ln1<<<BNR_, 256, 0, stream>>>(img, word, Pb, co, g1, bt1, X1b);

    // --- FFN: H = relu(X1@W1+b1); Yb = bf16(H@W2 + b2 + X1b) (EPI7) ---
    bgemm<1><<<16 * 112, 256, 0, stream>>>(X1b, KP_, W1T, KP_,
        BNR_, FF_, KP_, 1.f, nullptr, 0, Hb, FF_, bf1, 16, 1);
    bgemm<7><<<7 * 112, 256, 0, stream>>>(Hb, FF_, W2T, FF_,
        BNR_, DD_, FF_, 1.f, (float*)X1b, KP_, Yb, KP_, bf2, 7, 1);

    // --- fused LN2 + GCN1 + GCN2 + pool + linear ---
    kern_gcn<<<B_, 256, 0, stream>>>(Yb, g2, bt2, Wg1T, bg1, Wg2T, bg2,
                                     Wl, bl, Adj, out);
}

// Round 10
// 561.382 us; speedup vs baseline: 4.3481x; 1.0273x over previous
//
#include <hip/hip_runtime.h>
#include <math.h>

// Problem constants
#define B_    1024
#define IMG_  512
#define TXT_  300
#define NN_   14
#define FF_   2048
#define HID_  128
#define CC_   14
#define EE_   182
#define DD_   812
#define D3_   2436
#define BNR_  14336          // B_*NN_
#define KP_   832            // 812 padded to /32 (16B-aligned rows)
#define TXP_  320            // 300 padded to /32
#define AROWS_ 1152          // Aq/Ak/Av rows: 1024 data + 14 Tq + pad to tile mult

typedef __bf16 bf16x8 __attribute__((ext_vector_type(8)));
typedef float  f32x4  __attribute__((ext_vector_type(4)));
typedef unsigned short u16;

__device__ __forceinline__ u16 f2bf(float f) {
    union { float f; unsigned u; } v; v.f = f;
    unsigned r = v.u + 0x7FFFu + ((v.u >> 16) & 1u);   // RNE
    return (u16)(r >> 16);
}
__device__ __forceinline__ float bf2f(u16 h) {
    union { unsigned u; float f; } v; v.u = ((unsigned)h) << 16; return v.f;
}

// async global->LDS, 16B per lane. LDS dst = wave-uniform base + lane*16.
__device__ __forceinline__ void gload_lds16(const u16* g, u16* l) {
    __builtin_amdgcn_global_load_lds(
        (const __attribute__((address_space(1))) void*)g,
        (__attribute__((address_space(3))) void*)l, 16, 0, 0);
}

// ---------------------------------------------------------------------------
// Workspace layout (bytes), time-multiplexed overlays (audited vs launch
// timeline; garbage/NaN only reaches epilogue-masked rows/cols; K-pads of
// real rows always explicitly zeroed).
// ---------------------------------------------------------------------------
#define OFF_IMGB  0ULL              // bf16 [1024][512]
#define OFF_WIB   1048576ULL        // bf16 [2436][512]
#define OFF_WORDB 3543040ULL        // bf16 [128][320]
#define OFF_WITX  3624960ULL        // bf16 [2560][320]
#define OFF_GB    0ULL              // bf16 [14336][1024] (eG..P)
#define OFF_EBUF  29360128ULL       // f32  [1038][1024]  (S0..eG)
#define OFF_AVOT  33611776ULL       // bf16 [896][1024]   (G2..P)
#define OFF_WOB   35446784ULL       // bf16 [896][832]    (mcast..G2)
#define OFF_HB    0ULL              // bf16 [14336][2048] (FFN1..FFN2)
#define OFF_PB    58720256ULL       // bf16 [14336][812]  (P..ln1)
#define OFF_X1B   82001920ULL       // bf16 [14336][832]  (ln1..FFN2)
#define OFF_YB    105857024ULL      // bf16 [14336][832]  (FFN2..gcn)
#define OFF_W1T   129712128ULL      // bf16 [2048][832]
#define OFF_W2T   133120000ULL      // bf16 [896][2048]
#define OFF_AQB   152420352ULL      // bf16 3x[1152][832] (Aq|Ak|Av)
#define OFF_TVB   158307552ULL      // bf16 [128][832]
#define OFF_CO    158520544ULL      // f32  [14][812]
#define OFF_Z     158566016ULL      // f32  [14336]
#define OFF_ADJ   158623360ULL      // f32  [196 adj + 16 colw]
#define OFF_WG1T  158624384ULL      // bf16 [128][832]
#define OFF_WG2T  158837376ULL      // bf16 [128][128]

// ---------------------------------------------------------------------------
// Shared GEMM pipeline body: C[M,N] = scale * A[M,K] @ B^T (B stored [N][K]).
// 128x128 tile, BK=32, 4 waves (2x2 of 64x64), 16x16x32 MFMA, double-buffered
// global_load_lds staging. K%32==0; K-pads zeroed; buffers readable to
// 128-row multiples; M/N edges masked in epilogue. swiz=1: id%8 -> row-tile.
// epi 0: Cf=v. 1: Cb=bf16(relu(v+bias[cn])). 2: Cf=v+bias[cn]+bf2f(Cb).
// 3: Cb=bf16(v). 4: split-3 into [Aq|Ak|Av]. 5: Cb=bf16(v/bias[rm]).
// 6: Cf=v+bias[cn]. 7: Cb=bf16(v+bias[cn]+bf2f(((u16*)Cf)[rm*ldc+cn])).
// 8: T-split: cn<812 -> Cb[(1024+rm)*KP_+cn]=bf16(v+bias) (Tq into Aq rows);
//    cn>=1624 -> ((u16*)Cf)[rm*KP_+cn-1624]=bf16(v+bias) (Tv); middle dropped.
// ---------------------------------------------------------------------------
__device__ __forceinline__ void gemm_body(
    const u16* __restrict__ A, int lda,
    const u16* __restrict__ Bm, int ldb,
    int M, int N, int K, float scale,
    float* __restrict__ Cf, int ldc,
    u16* __restrict__ Cb, int ldcb,
    const float* __restrict__ bias,
    int nxt, int swiz, int epi, int id)
{
    __shared__ __align__(16) u16 As[2][128 * 32];
    __shared__ __align__(16) u16 Bs[2][128 * 32];
    const int tid = threadIdx.x;
    int bx, by;
    if (swiz) { int r8 = id & 7; int q = id >> 3; bx = q % nxt; by = (q / nxt) * 8 + r8; }
    else      { bx = id % nxt; by = id / nxt; }
    const int row0 = by * 128, col0 = bx * 128;
    const int lane = tid & 63, wv = tid >> 6;
    const int wm = (wv >> 1) * 64, wn = (wv & 1) * 64;
    const int fr = lane & 15, qd = lane >> 4;

    const int s_r0  = (wv * 64 + lane) >> 2;
    const int s_ko  = (lane & 3) * 8;
    const int s_b0  = (wv * 64) * 8;
    const u16* Arow0 = A  + (size_t)(row0 + s_r0) * lda + s_ko;
    const u16* Arow1 = A  + (size_t)(row0 + s_r0 + 64) * lda + s_ko;
    const u16* Brow0 = Bm + (size_t)(col0 + s_r0) * ldb + s_ko;
    const u16* Brow1 = Bm + (size_t)(col0 + s_r0 + 64) * ldb + s_ko;

    f32x4 acc[4][4] = {};

    const int T = K >> 5;
    gload_lds16(Arow0, &As[0][s_b0]);
    gload_lds16(Arow1, &As[0][s_b0 + 2048]);
    gload_lds16(Brow0, &Bs[0][s_b0]);
    gload_lds16(Brow1, &Bs[0][s_b0 + 2048]);

    for (int i = 0; i < T; ++i) {
        __syncthreads();
        const int cur = i & 1;
        if (i + 1 < T) {
            const int nb = cur ^ 1;
            const int ko = (i + 1) << 5;
            gload_lds16(Arow0 + ko, &As[nb][s_b0]);
            gload_lds16(Arow1 + ko, &As[nb][s_b0 + 2048]);
            gload_lds16(Brow0 + ko, &Bs[nb][s_b0]);
            gload_lds16(Brow1 + ko, &Bs[nb][s_b0 + 2048]);
        }
        bf16x8 af[4], bg[4];
        #pragma unroll
        for (int j = 0; j < 4; ++j) {
            af[j] = *(const bf16x8*)&As[cur][(wm + j * 16 + fr) * 32 + qd * 8];
            bg[j] = *(const bf16x8*)&Bs[cur][(wn + j * 16 + fr) * 32 + qd * 8];
        }
        #pragma unroll
        for (int mi = 0; mi < 4; ++mi)
            #pragma unroll
            for (int ni = 0; ni < 4; ++ni)
                acc[mi][ni] = __builtin_amdgcn_mfma_f32_16x16x32_bf16(
                    af[mi], bg[ni], acc[mi][ni], 0, 0, 0);
    }

    #pragma unroll
    for (int mi = 0; mi < 4; ++mi) {
        #pragma unroll
        for (int i = 0; i < 4; ++i) {
            int rm = row0 + wm + mi * 16 + qd * 4 + i;
            if (rm >= M) continue;
            #pragma unroll
            for (int ni = 0; ni < 4; ++ni) {
                int cn = col0 + wn + ni * 16 + fr;
                if (cn >= N) continue;
                float v = acc[mi][ni][i] * scale;
                if (epi == 0) Cf[(size_t)rm * ldc + cn] = v;
                else if (epi == 1) { v += bias[cn]; v = v > 0.f ? v : 0.f;
                                Cb[(size_t)rm * ldcb + cn] = f2bf(v); }
                else if (epi == 2) Cf[(size_t)rm * ldc + cn] =
                                v + bias[cn] + bf2f(Cb[(size_t)rm * ldcb + cn]);
                else if (epi == 3) Cb[(size_t)rm * ldcb + cn] = f2bf(v);
                else if (epi == 4) { int bs = cn / DD_, cc = cn - bs * DD_;
                                Cb[(size_t)bs * (AROWS_ * KP_) + (size_t)rm * KP_ + cc] = f2bf(v); }
                else if (epi == 5) { float invz = 1.0f / bias[rm];
                                Cb[(size_t)rm * ldcb + cn] = f2bf(v * invz); }
                else if (epi == 6) Cf[(size_t)rm * ldc + cn] = v + bias[cn];
                else if (epi == 7) { const u16* rx = (const u16*)Cf;
                                Cb[(size_t)rm * ldcb + cn] =
                                    f2bf(v + bias[cn] + bf2f(rx[(size_t)rm * ldc + cn])); }
                else if (epi == 8) {
                    float t = v + bias[cn];
                    if (cn < DD_) Cb[(size_t)(1024 + rm) * KP_ + cn] = f2bf(t);
                    else if (cn >= 2 * DD_)
                        ((u16*)Cf)[(size_t)rm * KP_ + (cn - 2 * DD_)] = f2bf(t);
                }
            }
        }
    }
}

template<int EPI>
__global__ __launch_bounds__(256, 4)
void bgemm(const u16* __restrict__ A, int lda,
           const u16* __restrict__ Bm, int ldb,
           int M, int N, int K, float scale,
           float* __restrict__ Cf, int ldc,
           u16* __restrict__ Cb, int ldcb,
           const float* __restrict__ bias,
           int nxt, int swiz)
{
    gemm_body(A, lda, Bm, ldb, M, N, K, scale, Cf, ldc, Cb, ldcb, bias,
              nxt, swiz, EPI, blockIdx.x);
}

// Grouped GEMM: up to 3 independent sub-GEMMs co-scheduled in one launch.
struct GDesc {
    const u16* A; const u16* B; float* Cf; u16* Cb; const float* bias;
    int lda, ldb, ldc, ldcb, M, N, K, epi, nxt, swiz, blk0;
    float scale;
};
struct GPack { GDesc d[3]; int n; };

__global__ __launch_bounds__(256, 4)
void gbgemm(GPack p)
{
    int id = blockIdx.x;
    int si = 0;
    for (int s = 1; s < p.n; ++s) if (id >= p.d[s].blk0) si = s;
    GDesc D = p.d[si];
    gemm_body(D.A, D.lda, D.B, D.ldb, D.M, D.N, D.K, D.scale,
              D.Cf, D.ldc, D.Cb, D.ldcb, D.bias, D.nxt, D.swiz, D.epi,
              id - D.blk0);
}

// Multi-segment fp32->bf16 cast (+ zero-fill segments with scols=0).
struct CDesc { const float* src; u16* dst; int srs, drs, dcols, scols; };
struct CPack { CDesc d[9]; unsigned cum[10]; int n; };

__global__ void kern_mcast(CPack p)
{
    unsigned idx = blockIdx.x * 256 + threadIdx.x;
    int si = -1;
    for (int s = 0; s < p.n; ++s)
        if (idx >= p.cum[s] && idx < p.cum[s + 1]) { si = s; break; }
    if (si < 0) return;
    CDesc D = p.d[si];
    unsigned k = idx - p.cum[si];
    int r = k / D.dcols, c = k - r * D.dcols;
    D.dst[(size_t)r * D.drs + c] =
        (c < D.scols) ? f2bf(D.src[(size_t)r * D.srs + c]) : (u16)0;
}

// Coalesced LDS-tiled cast-transpose: dst[c][r] = (r<rows ? src[r][c] : 0),
// r < padrows, c < cols. 32x32 tiles, 256 threads (32x8).
__global__ __launch_bounds__(256) void kern_castT32(
    const float* __restrict__ src, int srs, u16* __restrict__ dst, int drs,
    int rows, int cols, int padrows)
{
    __shared__ float t[32][33];
    int r0 = blockIdx.x * 32, c0 = blockIdx.y * 32;
    int tx = threadIdx.x & 31, ty = threadIdx.x >> 5;
    #pragma unroll
    for (int k = 0; k < 4; ++k) {
        int r = r0 + ty + k * 8, c = c0 + tx;
        t[ty + k * 8][tx] = (r < rows && c < cols) ? src[(size_t)r * srs + c] : 0.f;
    }
    __syncthreads();
    #pragma unroll
    for (int k = 0; k < 4; ++k) {
        int c = c0 + ty + k * 8, r = r0 + tx;
        if (c < cols && r < padrows)
            dst[(size_t)c * drs + r] = f2bf(t[tx][ty + k * 8]);
    }
}

// Dense 14x14 GCN adjacency (self-loops + symmetric norm) + column means
// colw[i] = mean_j Adj[j,i] ([14..15]=0 for 16-row MFMA).
__global__ void kern_adj(const int* __restrict__ ei, float* __restrict__ Adj)
{
    if (threadIdx.x != 0 || blockIdx.x != 0) return;
    float deg[NN_];
    for (int i = 0; i < NN_; ++i) deg[i] = 1.f;
    for (int e = 0; e < EE_; ++e) deg[ei[EE_ + e]] += 1.f;
    float dinv[NN_];
    for (int i = 0; i < NN_; ++i) dinv[i] = rsqrtf(deg[i]);
    float adj[NN_ * NN_];
    for (int t = 0; t < NN_ * NN_; ++t) adj[t] = 0.f;
    for (int e = 0; e < EE_; ++e) {
        int s = ei[e], d = ei[EE_ + e];
        adj[d * NN_ + s] += dinv[s] * dinv[d];
    }
    for (int i = 0; i < NN_; ++i) adj[i * NN_ + i] += dinv[i] * dinv[i];
    for (int t = 0; t < NN_ * NN_; ++t) Adj[t] = adj[t];
    for (int i = 0; i < 16; ++i) {
        float s = 0.f;
        if (i < NN_) for (int j = 0; j < NN_; ++j) s += adj[j * NN_ + i];
        Adj[NN_ * NN_ + i] = s / (float)NN_;
    }
}

// Fused [ew rowmax+exp] + exp(S0) + G + Z. Block l: exps the 14 raw w rows
// into bf16 LDS (block-local, redundant, L2-served), then Gb/Z as before.
// S rows 0..1023 raw S0; rows 1024..1037 raw w (NOT pre-exp'd).
__global__ __launch_bounds__(256) void kern_eG(const float* __restrict__ S,
    u16* __restrict__ Gb, float* __restrict__ Z)
{
    __shared__ float red[256];
    __shared__ u16 ews[NN_ * 1024];   // 28.7 KB
    const int l = blockIdx.x, tid = threadIdx.x;
    const int lane = tid & 63, wv = tid >> 6;

    // phase A: exp the raw w rows (wave w owns z = w, w+4, ...)
    const float* wraw = S + 1024 * 1024;
    for (int z = wv; z < NN_; z += 4) {
        const float* r = wraw + z * 1024;
        float vv[16], mx = -1e30f;
        #pragma unroll
        for (int j = 0; j < 16; ++j) { vv[j] = r[lane + 64 * j]; mx = fmaxf(mx, vv[j]); }
        #pragma unroll
        for (int off = 32; off > 0; off >>= 1) mx = fmaxf(mx, __shfl_down(mx, off));
        mx = __shfl(mx, 0);
        #pragma unroll
        for (int j = 0; j < 16; ++j)
            ews[z * 1024 + lane + 64 * j] = f2bf(expf(vv[j] - mx));
    }
    // rowmax of own S0 row
    const float* row = S + (size_t)l * 1024;
    float m = -1e30f;
    #pragma unroll
    for (int k = 0; k < 4; ++k) m = fmaxf(m, row[tid + 256 * k]);
    red[tid] = m; __syncthreads();          // also publishes ews
    for (int s = 128; s > 0; s >>= 1) {
        if (tid < s) red[tid] = fmaxf(red[tid], red[tid + s]);
        __syncthreads();
    }
    m = red[0];
    float ev[16];
    #pragma unroll
    for (int j = 0; j < 16; ++j) ev[j] = expf(row[lane + 64 * j] - m);
    u16* gr = Gb + (size_t)l * NN_ * 1024;
    for (int z = wv; z < NN_; z += 4) {
        const u16* er = &ews[z * 1024];
        float s = 0.f;
        #pragma unroll
        for (int j = 0; j < 16; ++j) {
            float pv = ev[j] * bf2f(er[lane + 64 * j]);
            gr[(size_t)z * 1024 + lane + 64 * j] = f2bf(pv);
            s += pv;
        }
        #pragma unroll
        for (int off = 32; off > 0; off >>= 1) s += __shfl_down(s, off);
        if (lane == 0) Z[l * NN_ + z] = s;
    }
}

// x1 = LN1(node + Pb + co); Pb is bf16 attn-out already scaled by 1/Z.
__global__ __launch_bounds__(256) void kern_ln1(
    const float* __restrict__ img, const float* __restrict__ word,
    const u16* __restrict__ Pb,
    const float* __restrict__ co, const float* __restrict__ g,
    const float* __restrict__ bta, u16* __restrict__ Xb)
{
    __shared__ float buf[DD_];
    __shared__ float red[256];
    __shared__ float stats[2];
    int row = blockIdx.x;
    int b = row / NN_, n = row - b * NN_;
    const u16* pr = Pb + (size_t)row * DD_;
    const float* cr = co + n * DD_;
    float s = 0.f;
    for (int d = threadIdx.x; d < DD_; d += 256) {
        float v = (d < IMG_) ? img[(size_t)b * IMG_ + d] : word[n * TXT_ + d - IMG_];
        v += bf2f(pr[d]) + cr[d];
        buf[d] = v; s += v;
    }
    red[threadIdx.x] = s; __syncthreads();
    for (int t = 128; t > 0; t >>= 1) {
        if (threadIdx.x < t) red[threadIdx.x] += red[threadIdx.x + t];
        __syncthreads();
    }
    if (threadIdx.x == 0) stats[0] = red[0] / DD_;
    __syncthreads();
    float mu = stats[0], s2 = 0.f;
    for (int d = threadIdx.x; d < DD_; d += 256) { float t = buf[d] - mu; s2 += t * t; }
    red[threadIdx.x] = s2; __syncthreads();
    for (int t = 128; t > 0; t >>= 1) {
        if (threadIdx.x < t) red[threadIdx.x] += red[threadIdx.x + t];
        __syncthreads();
    }
    if (threadIdx.x == 0) stats[1] = rsqrtf(red[0] / DD_ + 1e-5f);
    __syncthreads();
    float rstd = stats[1];
    u16* xb = Xb + (size_t)row * KP_;
    for (int d = threadIdx.x; d < DD_; d += 256)
        xb[d] = f2bf((buf[d] - mu) * rstd * g[d] + bta[d]);
    for (int d = DD_ + threadIdx.x; d < KP_; d += 256) xb[d] = 0;
}

// ---------------------------------------------------------------------------
// Fused LN2 + GCN1 + GCN2 + mean-pool + linear. One block per image b.
// g1s OVERLAYS x2s (dead after GCN1 reads) -> 36.7 KB LDS -> 4 blocks/CU.
// B-operand loads rotate-prefetched to break the L2-latency chain.
// ---------------------------------------------------------------------------
#define X2S_ 840
#define G1S_ 136
__global__ __launch_bounds__(256, 4)
void kern_gcn(const u16* __restrict__ Yb,
              const float* __restrict__ g2v, const float* __restrict__ bt2,
              const u16* __restrict__ Wg1T, const float* __restrict__ bg1,
              const u16* __restrict__ Wg2T, const float* __restrict__ bg2,
              const float* __restrict__ Wl,  const float* __restrict__ bl,
              const float* __restrict__ AdjW, float* __restrict__ out)
{
    __shared__ __align__(16) u16 x2s[16 * X2S_];      // 26.9 KB; g1s overlays
    __shared__ __align__(16) float h1s[16 * 132];     // 8.4 KB
    __shared__ float adj_s[NN_ * NN_];
    __shared__ float colw_s[16];
    __shared__ float pool_s[HID_];
    u16* g1s = x2s;                                   // overlay (16*G1S_ u16)
    const int b = blockIdx.x, tid = threadIdx.x;
    const int lane = tid & 63, wv = tid >> 6;
    const int fr = lane & 15, qd = lane >> 4;

    if (tid < NN_ * NN_) adj_s[tid] = AdjW[tid];
    if (tid >= NN_ * NN_ && tid < NN_ * NN_ + 16) colw_s[tid - NN_ * NN_] = AdjW[tid];
    // zero x2s pad rows 14,15 and K-pad cols [812,840) of data rows
    for (int k = tid; k < 2 * X2S_; k += 256) x2s[14 * X2S_ + k] = 0;
    for (int k = tid; k < 14 * (X2S_ - DD_); k += 256) {
        int j = k / (X2S_ - DD_), c = k - j * (X2S_ - DD_);
        x2s[j * X2S_ + DD_ + c] = 0;
    }

    // --- LN2 per node row (wave w handles rows w, w+4, ...) ---
    for (int j = wv; j < NN_; j += 4) {
        const u16* yr = Yb + (size_t)(b * NN_ + j) * KP_;
        float vv[13], s = 0.f;
        #pragma unroll
        for (int k = 0; k < 13; ++k) {
            int d = lane + 64 * k;
            float v = (d < DD_) ? bf2f(yr[d]) : 0.f;
            vv[k] = v; s += v;
        }
        #pragma unroll
        for (int off = 32; off > 0; off >>= 1) s += __shfl_down(s, off);
        s = __shfl(s, 0);
        float mu = s / (float)DD_, s2 = 0.f;
        #pragma unroll
        for (int k = 0; k < 13; ++k) {
            int d = lane + 64 * k;
            float t = (d < DD_) ? vv[k] - mu : 0.f;
            s2 += t * t;
        }
        #pragma unroll
        for (int off = 32; off > 0; off >>= 1) s2 += __shfl_down(s2, off);
        s2 = __shfl(s2, 0);
        float rstd = rsqrtf(s2 / (float)DD_ + 1e-5f);
        #pragma unroll
        for (int k = 0; k < 13; ++k) {
            int d = lane + 64 * k;
            if (d < DD_)
                x2s[j * X2S_ + d] = f2bf((vv[k] - mu) * rstd * g2v[d] + bt2[d]);
        }
    }
    __syncthreads();

    // --- GCN1: H1 = X2 @ Wg1 (MFMA, M=16, K=KP_); wave w: f in [w*32,+32) ---
    {
        f32x4 acc[2] = {{}, {}};
        const u16* wp0 = Wg1T + (size_t)(wv * 32 + fr) * KP_ + qd * 8;
        const u16* wp1 = wp0 + (size_t)16 * KP_;
        bf16x8 bc0 = *(const bf16x8*)wp0;
        bf16x8 bc1 = *(const bf16x8*)wp1;
        for (int k0 = 0; k0 < KP_; k0 += 32) {
            bf16x8 bn0 = bc0, bn1 = bc1;
            if (k0 + 32 < KP_) {
                bn0 = *(const bf16x8*)(wp0 + k0 + 32);
                bn1 = *(const bf16x8*)(wp1 + k0 + 32);
            }
            bf16x8 af = *(const bf16x8*)&x2s[fr * X2S_ + k0 + qd * 8];
            acc[0] = __builtin_amdgcn_mfma_f32_16x16x32_bf16(af, bc0, acc[0], 0, 0, 0);
            acc[1] = __builtin_amdgcn_mfma_f32_16x16x32_bf16(af, bc1, acc[1], 0, 0, 0);
            bc0 = bn0; bc1 = bn1;
        }
        #pragma unroll
        for (int t = 0; t < 2; ++t)
            #pragma unroll
            for (int i = 0; i < 4; ++i)
                h1s[(qd * 4 + i) * 132 + wv * 32 + t * 16 + fr] = acc[t][i];
    }
    __syncthreads();   // x2s dead; g1s overlay now writable

    // --- G1 = relu(Adj @ H1 + bg1) -> bf16; zero pad rows 14,15 ---
    {
        const int f = tid & 127, jj = (tid >> 7) * 7;
        #pragma unroll
        for (int j = 0; j < 7; ++j) {
            float s = bg1[f];
            #pragma unroll
            for (int i = 0; i < NN_; ++i)
                s = fmaf(adj_s[(jj + j) * NN_ + i], h1s[i * 132 + f], s);
            g1s[(jj + j) * G1S_ + f] = f2bf(s > 0.f ? s : 0.f);
        }
        for (int k = tid; k < 2 * G1S_; k += 256) g1s[14 * G1S_ + k] = 0;
    }
    __syncthreads();

    // --- GCN2 (MFMA, K=128) + pool = relu(colw·H2 + bg2) ---
    {
        f32x4 acc[2] = {{}, {}};
        const u16* wp0 = Wg2T + (size_t)(wv * 32 + fr) * HID_ + qd * 8;
        const u16* wp1 = wp0 + (size_t)16 * HID_;
        bf16x8 bc0 = *(const bf16x8*)wp0;
        bf16x8 bc1 = *(const bf16x8*)wp1;
        for (int k0 = 0; k0 < HID_; k0 += 32) {
            bf16x8 bn0 = bc0, bn1 = bc1;
            if (k0 + 32 < HID_) {
                bn0 = *(const bf16x8*)(wp0 + k0 + 32);
                bn1 = *(const bf16x8*)(wp1 + k0 + 32);
            }
            bf16x8 af = *(const bf16x8*)&g1s[fr * G1S_ + k0 + qd * 8];
            acc[0] = __builtin_amdgcn_mfma_f32_16x16x32_bf16(af, bc0, acc[0], 0, 0, 0);
            acc[1] = __builtin_amdgcn_mfma_f32_16x16x32_bf16(af, bc1, acc[1], 0, 0, 0);
            bc0 = bn0; bc1 = bn1;
        }
        #pragma unroll
        for (int t = 0; t < 2; ++t) {
            float s = 0.f;
            #pragma unroll
            for (int i = 0; i < 4; ++i) s += colw_s[qd * 4 + i] * acc[t][i];
            s += __shfl_xor(s, 16);
            s += __shfl_xor(s, 32);
            if (qd == 0) {
                int f = wv * 32 + t * 16 + fr;
                float p = s + bg2[f];
                pool_s[f] = p > 0.f ? p : 0.f;
            }
        }
    }
    __syncthreads();

    // --- out = pool @ Wl + bl ---
    if (tid < CC_) {
        float s = bl[tid];
        #pragma unroll 8
        for (int f = 0; f < HID_; ++f)
            s = fmaf(pool_s[f], Wl[(size_t)f * CC_ + tid], s);
        out[(size_t)b * CC_ + tid] = s;
    }
}

extern "C" void kernel_launch(void* const* d_in, const int* in_sizes, int n_in,
                              void* d_out, int out_size, void* d_ws, size_t ws_size,
                              hipStream_t stream)
{
    const float* img  = (const float*)d_in[0];
    const float* word = (const float*)d_in[1];
    const int*   ei   = (const int*)d_in[2];
    const float* Wi   = (const float*)d_in[3];
    const float* bi   = (const float*)d_in[4];
    const float* Wo   = (const float*)d_in[5];
    const float* bo   = (const float*)d_in[6];
    const float* g1   = (const float*)d_in[7];
    const float* bt1  = (const float*)d_in[8];
    const float* g2   = (const float*)d_in[9];
    const float* bt2  = (const float*)d_in[10];
    const float* W1   = (const float*)d_in[11];
    const float* bf1  = (const float*)d_in[12];
    const float* W2   = (const float*)d_in[13];
    const float* bf2  = (const float*)d_in[14];
    const float* Wg1  = (const float*)d_in[15];
    const float* bg1  = (const float*)d_in[16];
    const float* Wg2  = (const float*)d_in[17];
    const float* bg2  = (const float*)d_in[18];
    const float* Wl   = (const float*)d_in[19];
    const float* bl   = (const float*)d_in[20];
    float* out = (float*)d_out;

    char* ws = (char*)d_ws;
    u16*   imgb = (u16*)  (ws + OFF_IMGB);
    u16*   Wib  = (u16*)  (ws + OFF_WIB);
    u16*   wordb= (u16*)  (ws + OFF_WORDB);
    u16*   WiTX = (u16*)  (ws + OFF_WITX);
    u16*   Gb   = (u16*)  (ws + OFF_GB);
    float* Ebuf = (float*)(ws + OFF_EBUF);
    u16*   AvoT = (u16*)  (ws + OFF_AVOT);
    u16*   Wob  = (u16*)  (ws + OFF_WOB);
    u16*   Hb   = (u16*)  (ws + OFF_HB);
    u16*   Pb   = (u16*)  (ws + OFF_PB);
    u16*   X1b  = (u16*)  (ws + OFF_X1B);
    u16*   Yb   = (u16*)  (ws + OFF_YB);
    u16*   W1T  = (u16*)  (ws + OFF_W1T);
    u16*   W2T  = (u16*)  (ws + OFF_W2T);
    u16*   Aqb  = (u16*)  (ws + OFF_AQB);
    u16*   Akb  = Aqb + AROWS_ * KP_;
    u16*   Avb  = Aqb + 2 * AROWS_ * KP_;
    u16*   Tvb  = (u16*)  (ws + OFF_TVB);
    float* co   = (float*)(ws + OFF_CO);
    float* Zb   = (float*)(ws + OFF_Z);
    float* Adj  = (float*)(ws + OFF_ADJ);
    u16*   Wg1T = (u16*)  (ws + OFF_WG1T);
    u16*   Wg2T = (u16*)  (ws + OFF_WG2T);

    const float scl = 1.0f / sqrtf((float)DD_);

    // --- one multi-cast launch: input casts + all K-pad zeroing ---
    {
        CPack p; p.n = 9;
        unsigned c = 0;
        auto seg = [&](int i, const float* s, int srs, u16* d, int drs,
                       int rows, int dcols, int scols) {
            p.d[i] = { s, d, srs, drs, dcols, scols };
            p.cum[i] = c; c += (unsigned)rows * dcols;
        };
        seg(0, img,        IMG_, imgb,  IMG_, B_,   IMG_, IMG_);
        seg(1, Wi,         DD_,  Wib,   IMG_, D3_,  IMG_, IMG_);
        seg(2, word,       TXT_, wordb, TXP_, NN_,  TXP_, TXT_);
        seg(3, Wi + IMG_,  DD_,  WiTX,  TXP_, D3_,  TXP_, TXT_);
        seg(4, Wo,         DD_,  Wob,   KP_,  DD_,  KP_,  DD_);
        seg(5, nullptr, 0, Aqb + DD_,                    KP_, 1038, 20, 0); // Aq + Tq rows
        seg(6, nullptr, 0, Aqb + AROWS_ * KP_ + DD_,     KP_, 1024, 20, 0);
        seg(7, nullptr, 0, Aqb + 2 * AROWS_ * KP_ + DD_, KP_, 1024, 20, 0);
        seg(8, nullptr, 0, Tvb + DD_,                    KP_, NN_,  20, 0); // Tvb pads
        p.cum[9] = c;
        kern_mcast<<<(c + 255) / 256, 256, 0, stream>>>(p);
    }
    kern_adj<<<1, 64, 0, stream>>>(ei, Adj);
    kern_castT32<<<dim3(26, 64), 256, 0, stream>>>(W1, FF_, W1T, KP_, DD_, FF_, KP_);
    kern_castT32<<<dim3(64, 26), 256, 0, stream>>>(W2, DD_, W2T, FF_, FF_, DD_, FF_);
    kern_castT32<<<dim3(26, 4), 256, 0, stream>>>(Wg1, HID_, Wg1T, KP_, DD_, HID_, KP_);
    kern_castT32<<<dim3(4, 4), 256, 0, stream>>>(Wg2, HID_, Wg2T, HID_, HID_, HID_, HID_);

    // --- Group1: T (epi 8: Tq->Aq rows, Tv->Tvb) || A-proj split-3 ---
    {
        GPack p; p.n = 2;
        p.d[0] = { wordb, WiTX, (float*)Tvb, Aqb, bi,
                   TXP_, TXP_, 0, 0, NN_, D3_, TXP_, 8, 20, 0, 0, 1.f };
        p.d[1] = { imgb, Wib, nullptr, Aqb, nullptr,
                   IMG_, IMG_, 0, 0, B_, D3_, IMG_, 4, 20, 1, 20, 1.f };
        gbgemm<<<20 + 160, 256, 0, stream>>>(p);
    }

    // --- Group2: S0+w (M=1038, raw) || AvoT = Wo@Av^T || co = Tv@Wo^T+bo ---
    {
        GPack p; p.n = 3;
        p.d[0] = { Aqb, Akb, Ebuf, nullptr, nullptr,
                   KP_, KP_, 1024, 0, 1024 + NN_, 1024, KP_, 0, 8, 0, 0, scl };
        p.d[1] = { Wob, Avb, nullptr, AvoT, nullptr,
                   KP_, KP_, 0, 1024, DD_, B_, KP_, 3, 8, 0, 72, 1.f };
        p.d[2] = { Tvb, Wob, co, nullptr, bo,
                   KP_, KP_, DD_, 0, NN_, DD_, KP_, 6, 7, 0, 128, 1.f };
        gbgemm<<<72 + 56 + 7, 256, 0, stream>>>(p);
    }

    // --- fused ew-exp + exp + G + Z ---
    kern_eG<<<1024, 256, 0, stream>>>(Ebuf, Gb, Zb);

    // --- Pb = (G @ Avo)/Z as bf16 ---
    bgemm<5><<<7 * 112, 256, 0, stream>>>(Gb, 1024, AvoT, 1024,
        BNR_, DD_, 1024, 1.f, nullptr, 0, Pb, DD_, Zb, 7, 1);

    // --- LN1 ---
    kern_ln1<<<BNR_, 256, 0, stream>>>(img, word, Pb, co, g1, bt1, X1b);

    // --- FFN: H = relu(X1@W1+b1); Yb = bf16(H@W2 + b2 + X1b) ---
    bgemm<1><<<16 * 112, 256, 0, stream>>>(X1b, KP_, W1T, KP_,
        BNR_, FF_, KP_, 1.f, nullptr, 0, Hb, FF_, bf1, 16, 1);
    bgemm<7><<<7 * 112, 256, 0, stream>>>(Hb, FF_, W2T, FF_,
        BNR_, DD_, FF_, 1.f, (float*)X1b, KP_, Yb, KP_, bf2, 7, 1);

    // --- fused LN2 + GCN1 + GCN2 + pool + linear ---
    kern_gcn<<<B_, 256, 0, stream>>>(Yb, g2, bt2, Wg1T, bg1, Wg2T, bg2,
                                     Wl, bl, Adj, out);
}

// Round 11
// 549.259 us; speedup vs baseline: 4.4441x; 1.0221x over previous
//
#include <hip/hip_runtime.h>
#include <math.h>

// Problem constants
#define B_    1024
#define IMG_  512
#define TXT_  300
#define NN_   14
#define FF_   2048
#define HID_  128
#define CC_   14
#define EE_   182
#define DD_   812
#define D3_   2436
#define BNR_  14336          // B_*NN_
#define KP_   832            // 812 padded to /32 (16B-aligned rows)
#define TXP_  320            // 300 padded to /32
#define AROWS_ 1152          // Aq/Ak/Av rows: 1024 data + 14 Tq + pad to tile mult

typedef __bf16 bf16x8 __attribute__((ext_vector_type(8)));
typedef float  f32x4  __attribute__((ext_vector_type(4)));
typedef unsigned short u16;

__device__ __forceinline__ u16 f2bf(float f) {
    union { float f; unsigned u; } v; v.f = f;
    unsigned r = v.u + 0x7FFFu + ((v.u >> 16) & 1u);   // RNE
    return (u16)(r >> 16);
}
__device__ __forceinline__ float bf2f(u16 h) {
    union { unsigned u; float f; } v; v.u = ((unsigned)h) << 16; return v.f;
}

// async global->LDS, 16B per lane. LDS dst = wave-uniform base + lane*16.
__device__ __forceinline__ void gload_lds16(const u16* g, u16* l) {
    __builtin_amdgcn_global_load_lds(
        (const __attribute__((address_space(1))) void*)g,
        (__attribute__((address_space(3))) void*)l, 16, 0, 0);
}

// ---------------------------------------------------------------------------
// Workspace layout (bytes), time-multiplexed overlays (audited vs launch
// timeline; garbage/NaN only reaches epilogue-masked rows/cols; K-pads of
// real rows always explicitly zeroed).
// ---------------------------------------------------------------------------
#define OFF_IMGB  0ULL              // bf16 [1024][512]
#define OFF_WIB   1048576ULL        // bf16 [2436][512]
#define OFF_WORDB 3543040ULL        // bf16 [128][320]
#define OFF_WITX  3624960ULL        // bf16 [2560][320]
#define OFF_GB    0ULL              // bf16 [14336][1024] (eG..P)
#define OFF_EBUF  29360128ULL       // f32  [1038][1024]  (S0..eG)
#define OFF_AVOT  33611776ULL       // bf16 [896][1024]   (mix2..P)
#define OFF_WOB   35446784ULL       // bf16 [896][832]    (mcast..mix2)
#define OFF_HB    0ULL              // bf16 [14336][2048] (FFN1..FFN2)
#define OFF_PB    58720256ULL       // bf16 [14336][812]  (P..ln1)
#define OFF_X1B   82001920ULL       // bf16 [14336][832]  (ln1..FFN2)
#define OFF_YB    105857024ULL      // bf16 [14336][832]  (FFN2..gcn)
#define OFF_W1T   129712128ULL      // bf16 [2048][832]   (mix2..FFN1)
#define OFF_W2T   133120000ULL      // bf16 [896][2048]   (mix2..FFN2)
#define OFF_AQB   152420352ULL      // bf16 3x[1152][832] (Aq|Ak|Av)
#define OFF_TVB   158307552ULL      // bf16 [128][832]
#define OFF_CO    158520544ULL      // f32  [14][812]
#define OFF_Z     158566016ULL      // f32  [14336]
#define OFF_ADJ   158623360ULL      // f32  [196 adj + 16 colw]
#define OFF_WG1T  158624384ULL      // bf16 [128][832]
#define OFF_WG2T  158837376ULL      // bf16 [128][128]

// ---------------------------------------------------------------------------
// Shared GEMM pipeline body: C[M,N] = scale * A[M,K] @ B^T (B stored [N][K]).
// 128x128 tile, BK=32, 4 waves (2x2 of 64x64), 16x16x32 MFMA, double-buffered
// global_load_lds staging. K%32==0; K-pads zeroed; buffers readable to
// 128-row multiples; M/N edges masked in epilogue. swiz=1: id%8 -> row-tile.
// epi 0: Cf=v. 1: Cb=bf16(relu(v+bias[cn])). 2: Cf=v+bias[cn]+bf2f(Cb).
// 3: Cb=bf16(v). 4: split-3 into [Aq|Ak|Av]. 5: Cb=bf16(v/bias[rm]).
// 6: Cf=v+bias[cn]. 7: Cb=bf16(v+bias[cn]+bf2f(((u16*)Cf)[rm*ldc+cn])).
// 8: T-split: cn<812 -> Cb[(1024+rm)*KP_+cn]=bf16(v+bias) (Tq into Aq rows);
//    cn>=1624 -> ((u16*)Cf)[rm*KP_+cn-1624]=bf16(v+bias) (Tv); middle dropped.
// ---------------------------------------------------------------------------
__device__ __forceinline__ void gemm_body(
    const u16* __restrict__ A, int lda,
    const u16* __restrict__ Bm, int ldb,
    int M, int N, int K, float scale,
    float* __restrict__ Cf, int ldc,
    u16* __restrict__ Cb, int ldcb,
    const float* __restrict__ bias,
    int nxt, int swiz, int epi, int id)
{
    __shared__ __align__(16) u16 As[2][128 * 32];
    __shared__ __align__(16) u16 Bs[2][128 * 32];
    const int tid = threadIdx.x;
    int bx, by;
    if (swiz) { int r8 = id & 7; int q = id >> 3; bx = q % nxt; by = (q / nxt) * 8 + r8; }
    else      { bx = id % nxt; by = id / nxt; }
    const int row0 = by * 128, col0 = bx * 128;
    const int lane = tid & 63, wv = tid >> 6;
    const int wm = (wv >> 1) * 64, wn = (wv & 1) * 64;
    const int fr = lane & 15, qd = lane >> 4;

    const int s_r0  = (wv * 64 + lane) >> 2;
    const int s_ko  = (lane & 3) * 8;
    const int s_b0  = (wv * 64) * 8;
    const u16* Arow0 = A  + (size_t)(row0 + s_r0) * lda + s_ko;
    const u16* Arow1 = A  + (size_t)(row0 + s_r0 + 64) * lda + s_ko;
    const u16* Brow0 = Bm + (size_t)(col0 + s_r0) * ldb + s_ko;
    const u16* Brow1 = Bm + (size_t)(col0 + s_r0 + 64) * ldb + s_ko;

    f32x4 acc[4][4] = {};

    const int T = K >> 5;
    gload_lds16(Arow0, &As[0][s_b0]);
    gload_lds16(Arow1, &As[0][s_b0 + 2048]);
    gload_lds16(Brow0, &Bs[0][s_b0]);
    gload_lds16(Brow1, &Bs[0][s_b0 + 2048]);

    for (int i = 0; i < T; ++i) {
        __syncthreads();
        const int cur = i & 1;
        if (i + 1 < T) {
            const int nb = cur ^ 1;
            const int ko = (i + 1) << 5;
            gload_lds16(Arow0 + ko, &As[nb][s_b0]);
            gload_lds16(Arow1 + ko, &As[nb][s_b0 + 2048]);
            gload_lds16(Brow0 + ko, &Bs[nb][s_b0]);
            gload_lds16(Brow1 + ko, &Bs[nb][s_b0 + 2048]);
        }
        bf16x8 af[4], bg[4];
        #pragma unroll
        for (int j = 0; j < 4; ++j) {
            af[j] = *(const bf16x8*)&As[cur][(wm + j * 16 + fr) * 32 + qd * 8];
            bg[j] = *(const bf16x8*)&Bs[cur][(wn + j * 16 + fr) * 32 + qd * 8];
        }
        #pragma unroll
        for (int mi = 0; mi < 4; ++mi)
            #pragma unroll
            for (int ni = 0; ni < 4; ++ni)
                acc[mi][ni] = __builtin_amdgcn_mfma_f32_16x16x32_bf16(
                    af[mi], bg[ni], acc[mi][ni], 0, 0, 0);
    }

    #pragma unroll
    for (int mi = 0; mi < 4; ++mi) {
        #pragma unroll
        for (int i = 0; i < 4; ++i) {
            int rm = row0 + wm + mi * 16 + qd * 4 + i;
            if (rm >= M) continue;
            #pragma unroll
            for (int ni = 0; ni < 4; ++ni) {
                int cn = col0 + wn + ni * 16 + fr;
                if (cn >= N) continue;
                float v = acc[mi][ni][i] * scale;
                if (epi == 0) Cf[(size_t)rm * ldc + cn] = v;
                else if (epi == 1) { v += bias[cn]; v = v > 0.f ? v : 0.f;
                                Cb[(size_t)rm * ldcb + cn] = f2bf(v); }
                else if (epi == 2) Cf[(size_t)rm * ldc + cn] =
                                v + bias[cn] + bf2f(Cb[(size_t)rm * ldcb + cn]);
                else if (epi == 3) Cb[(size_t)rm * ldcb + cn] = f2bf(v);
                else if (epi == 4) { int bs = cn / DD_, cc = cn - bs * DD_;
                                Cb[(size_t)bs * (AROWS_ * KP_) + (size_t)rm * KP_ + cc] = f2bf(v); }
                else if (epi == 5) { float invz = 1.0f / bias[rm];
                                Cb[(size_t)rm * ldcb + cn] = f2bf(v * invz); }
                else if (epi == 6) Cf[(size_t)rm * ldc + cn] = v + bias[cn];
                else if (epi == 7) { const u16* rx = (const u16*)Cf;
                                Cb[(size_t)rm * ldcb + cn] =
                                    f2bf(v + bias[cn] + bf2f(rx[(size_t)rm * ldc + cn])); }
                else if (epi == 8) {
                    float t = v + bias[cn];
                    if (cn < DD_) Cb[(size_t)(1024 + rm) * KP_ + cn] = f2bf(t);
                    else if (cn >= 2 * DD_)
                        ((u16*)Cf)[(size_t)rm * KP_ + (cn - 2 * DD_)] = f2bf(t);
                }
            }
        }
    }
}

template<int EPI>
__global__ __launch_bounds__(256, 4)
void bgemm(const u16* __restrict__ A, int lda,
           const u16* __restrict__ Bm, int ldb,
           int M, int N, int K, float scale,
           float* __restrict__ Cf, int ldc,
           u16* __restrict__ Cb, int ldcb,
           const float* __restrict__ bias,
           int nxt, int swiz)
{
    gemm_body(A, lda, Bm, ldb, M, N, K, scale, Cf, ldc, Cb, ldcb, bias,
              nxt, swiz, EPI, blockIdx.x);
}

// ---------------------------------------------------------------------------
// Mixed launch: grouped GEMMs + cast-transpose tiles + adjacency in ONE
// dispatch (graph stream is strictly serial; this fills the machine while
// small GEMM groups (135..180 blocks) would otherwise leave it >80% idle).
// gemm path uses gemm_body unchanged (32 KB LDS); transpose path its own
// 4.2 KB tile -> 36.2 KB total, still 4 blocks/CU.
// ---------------------------------------------------------------------------
struct GDesc {
    const u16* A; const u16* B; float* Cf; u16* Cb; const float* bias;
    int lda, ldb, ldc, ldcb, M, N, K, epi, nxt, swiz, blk0;
    float scale;
};
struct TDesc { const float* src; u16* dst; int srs, drs, rows, cols, padrows, rt, nblk; };
struct MPack { GDesc g[3]; TDesc t[2]; const int* ei; float* Adj; int ng, gtot, nt; };

// Coalesced LDS-tiled cast-transpose tile: dst[c][r] = (r<rows ? src[r][c] : 0)
__device__ __forceinline__ void castT_body(TDesc T, int id)
{
    __shared__ float t[32][33];
    const int bx = id % T.rt, by = id / T.rt;
    const int r0 = bx * 32, c0 = by * 32;
    const int tx = threadIdx.x & 31, ty = threadIdx.x >> 5;
    #pragma unroll
    for (int k = 0; k < 4; ++k) {
        int r = r0 + ty + k * 8, c = c0 + tx;
        t[ty + k * 8][tx] = (r < T.rows && c < T.cols) ? T.src[(size_t)r * T.srs + c] : 0.f;
    }
    __syncthreads();
    #pragma unroll
    for (int k = 0; k < 4; ++k) {
        int c = c0 + ty + k * 8, r = r0 + tx;
        if (c < T.cols && r < T.padrows)
            T.dst[(size_t)c * T.drs + r] = f2bf(t[tx][ty + k * 8]);
    }
}

// Dense 14x14 GCN adjacency (self-loops + symmetric norm) + column means
// colw[i] = mean_j Adj[j,i] ([14..15]=0 for 16-row MFMA). Serial, 1 thread.
__device__ __forceinline__ void adj_body(const int* __restrict__ ei, float* __restrict__ Adj)
{
    if (threadIdx.x != 0) return;
    float deg[NN_];
    for (int i = 0; i < NN_; ++i) deg[i] = 1.f;
    for (int e = 0; e < EE_; ++e) deg[ei[EE_ + e]] += 1.f;
    float dinv[NN_];
    for (int i = 0; i < NN_; ++i) dinv[i] = rsqrtf(deg[i]);
    float adj[NN_ * NN_];
    for (int t = 0; t < NN_ * NN_; ++t) adj[t] = 0.f;
    for (int e = 0; e < EE_; ++e) {
        int s = ei[e], d = ei[EE_ + e];
        adj[d * NN_ + s] += dinv[s] * dinv[d];
    }
    for (int i = 0; i < NN_; ++i) adj[i * NN_ + i] += dinv[i] * dinv[i];
    for (int t = 0; t < NN_ * NN_; ++t) Adj[t] = adj[t];
    for (int i = 0; i < 16; ++i) {
        float s = 0.f;
        if (i < NN_) for (int j = 0; j < NN_; ++j) s += adj[j * NN_ + i];
        Adj[NN_ * NN_ + i] = s / (float)NN_;
    }
}

__global__ __launch_bounds__(256, 4)
void kern_mix(MPack p)
{
    int id = blockIdx.x;
    if (id < p.gtot) {
        int si = 0;
        for (int s = 1; s < p.ng; ++s) if (id >= p.g[s].blk0) si = s;
        GDesc D = p.g[si];
        gemm_body(D.A, D.lda, D.B, D.ldb, D.M, D.N, D.K, D.scale,
                  D.Cf, D.ldc, D.Cb, D.ldcb, D.bias, D.nxt, D.swiz, D.epi,
                  id - D.blk0);
        return;
    }
    id -= p.gtot;
    for (int s = 0; s < p.nt; ++s) {
        if (id < p.t[s].nblk) { castT_body(p.t[s], id); return; }
        id -= p.t[s].nblk;
    }
    if (id == 0 && p.ei) adj_body(p.ei, p.Adj);
}

// Multi-segment fp32->bf16 cast (+ zero-fill segments with scols=0).
struct CDesc { const float* src; u16* dst; int srs, drs, dcols, scols; };
struct CPack { CDesc d[9]; unsigned cum[10]; int n; };

__global__ void kern_mcast(CPack p)
{
    unsigned idx = blockIdx.x * 256 + threadIdx.x;
    int si = -1;
    for (int s = 0; s < p.n; ++s)
        if (idx >= p.cum[s] && idx < p.cum[s + 1]) { si = s; break; }
    if (si < 0) return;
    CDesc D = p.d[si];
    unsigned k = idx - p.cum[si];
    int r = k / D.dcols, c = k - r * D.dcols;
    D.dst[(size_t)r * D.drs + c] =
        (c < D.scols) ? f2bf(D.src[(size_t)r * D.srs + c]) : (u16)0;
}

// Fused [ew rowmax+exp] + exp(S0) + G + Z. Block l: exps the 14 raw w rows
// into bf16 LDS (block-local, redundant, L2-served), then Gb/Z.
// S rows 0..1023 raw S0; rows 1024..1037 raw w.
__global__ __launch_bounds__(256) void kern_eG(const float* __restrict__ S,
    u16* __restrict__ Gb, float* __restrict__ Z)
{
    __shared__ float red[256];
    __shared__ u16 ews[NN_ * 1024];   // 28.7 KB
    const int l = blockIdx.x, tid = threadIdx.x;
    const int lane = tid & 63, wv = tid >> 6;

    const float* wraw = S + 1024 * 1024;
    for (int z = wv; z < NN_; z += 4) {
        const float* r = wraw + z * 1024;
        float vv[16], mx = -1e30f;
        #pragma unroll
        for (int j = 0; j < 16; ++j) { vv[j] = r[lane + 64 * j]; mx = fmaxf(mx, vv[j]); }
        #pragma unroll
        for (int off = 32; off > 0; off >>= 1) mx = fmaxf(mx, __shfl_down(mx, off));
        mx = __shfl(mx, 0);
        #pragma unroll
        for (int j = 0; j < 16; ++j)
            ews[z * 1024 + lane + 64 * j] = f2bf(expf(vv[j] - mx));
    }
    const float* row = S + (size_t)l * 1024;
    float m = -1e30f;
    #pragma unroll
    for (int k = 0; k < 4; ++k) m = fmaxf(m, row[tid + 256 * k]);
    red[tid] = m; __syncthreads();          // also publishes ews
    for (int s = 128; s > 0; s >>= 1) {
        if (tid < s) red[tid] = fmaxf(red[tid], red[tid + s]);
        __syncthreads();
    }
    m = red[0];
    float ev[16];
    #pragma unroll
    for (int j = 0; j < 16; ++j) ev[j] = expf(row[lane + 64 * j] - m);
    u16* gr = Gb + (size_t)l * NN_ * 1024;
    for (int z = wv; z < NN_; z += 4) {
        const u16* er = &ews[z * 1024];
        float s = 0.f;
        #pragma unroll
        for (int j = 0; j < 16; ++j) {
            float pv = ev[j] * bf2f(er[lane + 64 * j]);
            gr[(size_t)z * 1024 + lane + 64 * j] = f2bf(pv);
            s += pv;
        }
        #pragma unroll
        for (int off = 32; off > 0; off >>= 1) s += __shfl_down(s, off);
        if (lane == 0) Z[l * NN_ + z] = s;
    }
}

// x1 = LN1(node + Pb + co); Pb is bf16 attn-out already scaled by 1/Z.
__global__ __launch_bounds__(256) void kern_ln1(
    const float* __restrict__ img, const float* __restrict__ word,
    const u16* __restrict__ Pb,
    const float* __restrict__ co, const float* __restrict__ g,
    const float* __restrict__ bta, u16* __restrict__ Xb)
{
    __shared__ float buf[DD_];
    __shared__ float red[256];
    __shared__ float stats[2];
    int row = blockIdx.x;
    int b = row / NN_, n = row - b * NN_;
    const u16* pr = Pb + (size_t)row * DD_;
    const float* cr = co + n * DD_;
    float s = 0.f;
    for (int d = threadIdx.x; d < DD_; d += 256) {
        float v = (d < IMG_) ? img[(size_t)b * IMG_ + d] : word[n * TXT_ + d - IMG_];
        v += bf2f(pr[d]) + cr[d];
        buf[d] = v; s += v;
    }
    red[threadIdx.x] = s; __syncthreads();
    for (int t = 128; t > 0; t >>= 1) {
        if (threadIdx.x < t) red[threadIdx.x] += red[threadIdx.x + t];
        __syncthreads();
    }
    if (threadIdx.x == 0) stats[0] = red[0] / DD_;
    __syncthreads();
    float mu = stats[0], s2 = 0.f;
    for (int d = threadIdx.x; d < DD_; d += 256) { float t = buf[d] - mu; s2 += t * t; }
    red[threadIdx.x] = s2; __syncthreads();
    for (int t = 128; t > 0; t >>= 1) {
        if (threadIdx.x < t) red[threadIdx.x] += red[threadIdx.x + t];
        __syncthreads();
    }
    if (threadIdx.x == 0) stats[1] = rsqrtf(red[0] / DD_ + 1e-5f);
    __syncthreads();
    float rstd = stats[1];
    u16* xb = Xb + (size_t)row * KP_;
    for (int d = threadIdx.x; d < DD_; d += 256)
        xb[d] = f2bf((buf[d] - mu) * rstd * g[d] + bta[d]);
    for (int d = DD_ + threadIdx.x; d < KP_; d += 256) xb[d] = 0;
}

// ---------------------------------------------------------------------------
// Fused LN2 + GCN1 + GCN2 + mean-pool + linear. One block per image b.
// g1s OVERLAYS x2s (dead after GCN1 reads) -> 36.7 KB LDS -> 4 blocks/CU.
// B-operand loads rotate-prefetched to break the L2-latency chain.
// ---------------------------------------------------------------------------
#define X2S_ 840
#define G1S_ 136
__global__ __launch_bounds__(256, 4)
void kern_gcn(const u16* __restrict__ Yb,
              const float* __restrict__ g2v, const float* __restrict__ bt2,
              const u16* __restrict__ Wg1T, const float* __restrict__ bg1,
              const u16* __restrict__ Wg2T, const float* __restrict__ bg2,
              const float* __restrict__ Wl,  const float* __restrict__ bl,
              const float* __restrict__ AdjW, float* __restrict__ out)
{
    __shared__ __align__(16) u16 x2s[16 * X2S_];      // 26.9 KB; g1s overlays
    __shared__ __align__(16) float h1s[16 * 132];     // 8.4 KB
    __shared__ float adj_s[NN_ * NN_];
    __shared__ float colw_s[16];
    __shared__ float pool_s[HID_];
    u16* g1s = x2s;                                   // overlay (16*G1S_ u16)
    const int b = blockIdx.x, tid = threadIdx.x;
    const int lane = tid & 63, wv = tid >> 6;
    const int fr = lane & 15, qd = lane >> 4;

    if (tid < NN_ * NN_) adj_s[tid] = AdjW[tid];
    if (tid >= NN_ * NN_ && tid < NN_ * NN_ + 16) colw_s[tid - NN_ * NN_] = AdjW[tid];
    for (int k = tid; k < 2 * X2S_; k += 256) x2s[14 * X2S_ + k] = 0;
    for (int k = tid; k < 14 * (X2S_ - DD_); k += 256) {
        int j = k / (X2S_ - DD_), c = k - j * (X2S_ - DD_);
        x2s[j * X2S_ + DD_ + c] = 0;
    }

    // --- LN2 per node row ---
    for (int j = wv; j < NN_; j += 4) {
        const u16* yr = Yb + (size_t)(b * NN_ + j) * KP_;
        float vv[13], s = 0.f;
        #pragma unroll
        for (int k = 0; k < 13; ++k) {
            int d = lane + 64 * k;
            float v = (d < DD_) ? bf2f(yr[d]) : 0.f;
            vv[k] = v; s += v;
        }
        #pragma unroll
        for (int off = 32; off > 0; off >>= 1) s += __shfl_down(s, off);
        s = __shfl(s, 0);
        float mu = s / (float)DD_, s2 = 0.f;
        #pragma unroll
        for (int k = 0; k < 13; ++k) {
            int d = lane + 64 * k;
            float t = (d < DD_) ? vv[k] - mu : 0.f;
            s2 += t * t;
        }
        #pragma unroll
        for (int off = 32; off > 0; off >>= 1) s2 += __shfl_down(s2, off);
        s2 = __shfl(s2, 0);
        float rstd = rsqrtf(s2 / (float)DD_ + 1e-5f);
        #pragma unroll
        for (int k = 0; k < 13; ++k) {
            int d = lane + 64 * k;
            if (d < DD_)
                x2s[j * X2S_ + d] = f2bf((vv[k] - mu) * rstd * g2v[d] + bt2[d]);
        }
    }
    __syncthreads();

    // --- GCN1 (MFMA, M=16, K=KP_) ---
    {
        f32x4 acc[2] = {{}, {}};
        const u16* wp0 = Wg1T + (size_t)(wv * 32 + fr) * KP_ + qd * 8;
        const u16* wp1 = wp0 + (size_t)16 * KP_;
        bf16x8 bc0 = *(const bf16x8*)wp0;
        bf16x8 bc1 = *(const bf16x8*)wp1;
        for (int k0 = 0; k0 < KP_; k0 += 32) {
            bf16x8 bn0 = bc0, bn1 = bc1;
            if (k0 + 32 < KP_) {
                bn0 = *(const bf16x8*)(wp0 + k0 + 32);
                bn1 = *(const bf16x8*)(wp1 + k0 + 32);
            }
            bf16x8 af = *(const bf16x8*)&x2s[fr * X2S_ + k0 + qd * 8];
            acc[0] = __builtin_amdgcn_mfma_f32_16x16x32_bf16(af, bc0, acc[0], 0, 0, 0);
            acc[1] = __builtin_amdgcn_mfma_f32_16x16x32_bf16(af, bc1, acc[1], 0, 0, 0);
            bc0 = bn0; bc1 = bn1;
        }
        #pragma unroll
        for (int t = 0; t < 2; ++t)
            #pragma unroll
            for (int i = 0; i < 4; ++i)
                h1s[(qd * 4 + i) * 132 + wv * 32 + t * 16 + fr] = acc[t][i];
    }
    __syncthreads();   // x2s dead; g1s overlay now writable

    // --- G1 = relu(Adj @ H1 + bg1) -> bf16; zero pad rows 14,15 ---
    {
        const int f = tid & 127, jj = (tid >> 7) * 7;
        #pragma unroll
        for (int j = 0; j < 7; ++j) {
            float s = bg1[f];
            #pragma unroll
            for (int i = 0; i < NN_; ++i)
                s = fmaf(adj_s[(jj + j) * NN_ + i], h1s[i * 132 + f], s);
            g1s[(jj + j) * G1S_ + f] = f2bf(s > 0.f ? s : 0.f);
        }
        for (int k = tid; k < 2 * G1S_; k += 256) g1s[14 * G1S_ + k] = 0;
    }
    __syncthreads();

    // --- GCN2 (MFMA, K=128) + pool = relu(colw·H2 + bg2) ---
    {
        f32x4 acc[2] = {{}, {}};
        const u16* wp0 = Wg2T + (size_t)(wv * 32 + fr) * HID_ + qd * 8;
        const u16* wp1 = wp0 + (size_t)16 * HID_;
        bf16x8 bc0 = *(const bf16x8*)wp0;
        bf16x8 bc1 = *(const bf16x8*)wp1;
        for (int k0 = 0; k0 < HID_; k0 += 32) {
            bf16x8 bn0 = bc0, bn1 = bc1;
            if (k0 + 32 < HID_) {
                bn0 = *(const bf16x8*)(wp0 + k0 + 32);
                bn1 = *(const bf16x8*)(wp1 + k0 + 32);
            }
            bf16x8 af = *(const bf16x8*)&g1s[fr * G1S_ + k0 + qd * 8];
            acc[0] = __builtin_amdgcn_mfma_f32_16x16x32_bf16(af, bc0, acc[0], 0, 0, 0);
            acc[1] = __builtin_amdgcn_mfma_f32_16x16x32_bf16(af, bc1, acc[1], 0, 0, 0);
            bc0 = bn0; bc1 = bn1;
        }
        #pragma unroll
        for (int t = 0; t < 2; ++t) {
            float s = 0.f;
            #pragma unroll
            for (int i = 0; i < 4; ++i) s += colw_s[qd * 4 + i] * acc[t][i];
            s += __shfl_xor(s, 16);
            s += __shfl_xor(s, 32);
            if (qd == 0) {
                int f = wv * 32 + t * 16 + fr;
                float p = s + bg2[f];
                pool_s[f] = p > 0.f ? p : 0.f;
            }
        }
    }
    __syncthreads();

    // --- out = pool @ Wl + bl ---
    if (tid < CC_) {
        float s = bl[tid];
        #pragma unroll 8
        for (int f = 0; f < HID_; ++f)
            s = fmaf(pool_s[f], Wl[(size_t)f * CC_ + tid], s);
        out[(size_t)b * CC_ + tid] = s;
    }
}

extern "C" void kernel_launch(void* const* d_in, const int* in_sizes, int n_in,
                              void* d_out, int out_size, void* d_ws, size_t ws_size,
                              hipStream_t stream)
{
    const float* img  = (const float*)d_in[0];
    const float* word = (const float*)d_in[1];
    const int*   ei   = (const int*)d_in[2];
    const float* Wi   = (const float*)d_in[3];
    const float* bi   = (const float*)d_in[4];
    const float* Wo   = (const float*)d_in[5];
    const float* bo   = (const float*)d_in[6];
    const float* g1   = (const float*)d_in[7];
    const float* bt1  = (const float*)d_in[8];
    const float* g2   = (const float*)d_in[9];
    const float* bt2  = (const float*)d_in[10];
    const float* W1   = (const float*)d_in[11];
    const float* bf1  = (const float*)d_in[12];
    const float* W2   = (const float*)d_in[13];
    const float* bf2  = (const float*)d_in[14];
    const float* Wg1  = (const float*)d_in[15];
    const float* bg1  = (const float*)d_in[16];
    const float* Wg2  = (const float*)d_in[17];
    const float* bg2  = (const float*)d_in[18];
    const float* Wl   = (const float*)d_in[19];
    const float* bl   = (const float*)d_in[20];
    float* out = (float*)d_out;

    char* ws = (char*)d_ws;
    u16*   imgb = (u16*)  (ws + OFF_IMGB);
    u16*   Wib  = (u16*)  (ws + OFF_WIB);
    u16*   wordb= (u16*)  (ws + OFF_WORDB);
    u16*   WiTX = (u16*)  (ws + OFF_WITX);
    u16*   Gb   = (u16*)  (ws + OFF_GB);
    float* Ebuf = (float*)(ws + OFF_EBUF);
    u16*   AvoT = (u16*)  (ws + OFF_AVOT);
    u16*   Wob  = (u16*)  (ws + OFF_WOB);
    u16*   Hb   = (u16*)  (ws + OFF_HB);
    u16*   Pb   = (u16*)  (ws + OFF_PB);
    u16*   X1b  = (u16*)  (ws + OFF_X1B);
    u16*   Yb   = (u16*)  (ws + OFF_YB);
    u16*   W1T  = (u16*)  (ws + OFF_W1T);
    u16*   W2T  = (u16*)  (ws + OFF_W2T);
    u16*   Aqb  = (u16*)  (ws + OFF_AQB);
    u16*   Akb  = Aqb + AROWS_ * KP_;
    u16*   Avb  = Aqb + 2 * AROWS_ * KP_;
    u16*   Tvb  = (u16*)  (ws + OFF_TVB);
    float* co   = (float*)(ws + OFF_CO);
    float* Zb   = (float*)(ws + OFF_Z);
    float* Adj  = (float*)(ws + OFF_ADJ);
    u16*   Wg1T = (u16*)  (ws + OFF_WG1T);
    u16*   Wg2T = (u16*)  (ws + OFF_WG2T);

    const float scl = 1.0f / sqrtf((float)DD_);

    // --- launch 1: multi-cast (input casts + all K-pad zeroing) ---
    {
        CPack p; p.n = 9;
        unsigned c = 0;
        auto seg = [&](int i, const float* s, int srs, u16* d, int drs,
                       int rows, int dcols, int scols) {
            p.d[i] = { s, d, srs, drs, dcols, scols };
            p.cum[i] = c; c += (unsigned)rows * dcols;
        };
        seg(0, img,        IMG_, imgb,  IMG_, B_,   IMG_, IMG_);
        seg(1, Wi,         DD_,  Wib,   IMG_, D3_,  IMG_, IMG_);
        seg(2, word,       TXT_, wordb, TXP_, NN_,  TXP_, TXT_);
        seg(3, Wi + IMG_,  DD_,  WiTX,  TXP_, D3_,  TXP_, TXT_);
        seg(4, Wo,         DD_,  Wob,   KP_,  DD_,  KP_,  DD_);
        seg(5, nullptr, 0, Aqb + DD_,                    KP_, 1038, 20, 0); // Aq + Tq rows
        seg(6, nullptr, 0, Aqb + AROWS_ * KP_ + DD_,     KP_, 1024, 20, 0);
        seg(7, nullptr, 0, Aqb + 2 * AROWS_ * KP_ + DD_, KP_, 1024, 20, 0);
        seg(8, nullptr, 0, Tvb + DD_,                    KP_, NN_,  20, 0); // Tvb pads
        p.cum[9] = c;
        kern_mcast<<<(c + 255) / 256, 256, 0, stream>>>(p);
    }

    // --- launch 2 (mix1): T epi8 + A-proj  ||  Wg1T/Wg2T transposes || adj ---
    {
        MPack p{};
        p.ng = 2; p.gtot = 180;
        p.g[0] = { wordb, WiTX, (float*)Tvb, Aqb, bi,
                   TXP_, TXP_, 0, 0, NN_, D3_, TXP_, 8, 20, 0, 0, 1.f };
        p.g[1] = { imgb, Wib, nullptr, Aqb, nullptr,
                   IMG_, IMG_, 0, 0, B_, D3_, IMG_, 4, 20, 1, 20, 1.f };
        p.nt = 2;
        p.t[0] = { Wg1, Wg1T, HID_, KP_,  DD_,  HID_, KP_,  26, 26 * 4 };
        p.t[1] = { Wg2, Wg2T, HID_, HID_, HID_, HID_, HID_, 4,  4 * 4 };
        p.ei = ei; p.Adj = Adj;
        kern_mix<<<180 + 104 + 16 + 1, 256, 0, stream>>>(p);
    }

    // --- launch 3 (mix2): S0+w || AvoT || co  ||  W1T/W2T transposes ---
    {
        MPack p{};
        p.ng = 3; p.gtot = 135;
        p.g[0] = { Aqb, Akb, Ebuf, nullptr, nullptr,
                   KP_, KP_, 1024, 0, 1024 + NN_, 1024, KP_, 0, 8, 0, 0, scl };
        p.g[1] = { Wob, Avb, nullptr, AvoT, nullptr,
                   KP_, KP_, 0, 1024, DD_, B_, KP_, 3, 8, 0, 72, 1.f };
        p.g[2] = { Tvb, Wob, co, nullptr, bo,
                   KP_, KP_, DD_, 0, NN_, DD_, KP_, 6, 7, 0, 128, 1.f };
        p.nt = 2;
        p.t[0] = { W1, W1T, FF_, KP_, DD_, FF_, KP_, 26, 26 * 64 };
        p.t[1] = { W2, W2T, DD_, FF_, FF_, DD_, FF_, 64, 64 * 26 };
        p.ei = nullptr; p.Adj = nullptr;
        kern_mix<<<135 + 1664 + 1664, 256, 0, stream>>>(p);
    }

    // --- launch 4: fused ew-exp + exp + G + Z ---
    kern_eG<<<1024, 256, 0, stream>>>(Ebuf, Gb, Zb);

    // --- launch 5: Pb = (G @ Avo)/Z as bf16 ---
    bgemm<5><<<7 * 112, 256, 0, stream>>>(Gb, 1024, AvoT, 1024,
        BNR_, DD_, 1024, 1.f, nullptr, 0, Pb, DD_, Zb, 7, 1);

    // --- launch 6: LN1 ---
    kern_ln1<<<BNR_, 256, 0, stream>>>(img, word, Pb, co, g1, bt1, X1b);

    // --- launches 7,8: FFN ---
    bgemm<1><<<16 * 112, 256, 0, stream>>>(X1b, KP_, W1T, KP_,
        BNR_, FF_, KP_, 1.f, nullptr, 0, Hb, FF_, bf1, 16, 1);
    bgemm<7><<<7 * 112, 256, 0, stream>>>(Hb, FF_, W2T, FF_,
        BNR_, DD_, FF_, 1.f, (float*)X1b, KP_, Yb, KP_, bf2, 7, 1);

    // --- launch 9: fused LN2 + GCN1 + GCN2 + pool + linear ---
    kern_gcn<<<B_, 256, 0, stream>>>(Yb, g2, bt2, Wg1T, bg1, Wg2T, bg2,
                                     Wl, bl, Adj, out);
}

// Round 12
// 532.444 us; speedup vs baseline: 4.5844x; 1.0316x over previous
//
#include <hip/hip_runtime.h>
#include <math.h>

// Problem constants
#define B_    1024
#define IMG_  512
#define TXT_  300
#define NN_   14
#define FF_   2048
#define HID_  128
#define CC_   14
#define EE_   182
#define DD_   812
#define D3_   2436
#define BNR_  14336          // B_*NN_
#define KP_   832            // 812 padded to /32 (16B-aligned rows)
#define TXP_  320            // 300 padded to /32
#define AROWS_ 1152          // Aq/Ak/Av rows: 1024 data + 14 Tq + pad to tile mult

typedef __bf16 bf16x8 __attribute__((ext_vector_type(8)));
typedef float  f32x4  __attribute__((ext_vector_type(4)));
typedef unsigned short u16;

__device__ __forceinline__ u16 f2bf(float f) {
    union { float f; unsigned u; } v; v.f = f;
    unsigned r = v.u + 0x7FFFu + ((v.u >> 16) & 1u);   // RNE
    return (u16)(r >> 16);
}
__device__ __forceinline__ float bf2f(u16 h) {
    union { unsigned u; float f; } v; v.u = ((unsigned)h) << 16; return v.f;
}

// async global->LDS, 16B per lane. LDS dst = wave-uniform base + lane*16.
__device__ __forceinline__ void gload_lds16(const u16* g, u16* l) {
    __builtin_amdgcn_global_load_lds(
        (const __attribute__((address_space(1))) void*)g,
        (__attribute__((address_space(3))) void*)l, 16, 0, 0);
}

// ---------------------------------------------------------------------------
// Workspace layout (bytes), time-multiplexed overlays (audited vs launch
// timeline; garbage/NaN only reaches epilogue-masked rows/cols; K-pads of
// real rows always explicitly zeroed).
// ---------------------------------------------------------------------------
#define OFF_IMGB  0ULL              // bf16 [1024][512]
#define OFF_WIB   1048576ULL        // bf16 [2436][512]
#define OFF_WORDB 3543040ULL        // bf16 [128][320]
#define OFF_WITX  3624960ULL        // bf16 [2560][320]
#define OFF_GB    0ULL              // bf16 [14336][1024] (eG..P)
#define OFF_EBUF  29360128ULL       // f32  [1038][1024]  (S0..eG)
#define OFF_AVOT  33611776ULL       // bf16 [896][1024]   (mix2..P)
#define OFF_WOB   35446784ULL       // bf16 [896][832]    (mcast..mix2)
#define OFF_HB    0ULL              // bf16 [14336][2048] (FFN1..FFN2)
#define OFF_PB    58720256ULL       // bf16 [14336][812]  (P..ln1)
#define OFF_X1B   82001920ULL       // bf16 [14336][832]  (ln1..FFN2)
#define OFF_YB    105857024ULL      // bf16 [14336][832]  (FFN2..gcn)
#define OFF_W1T   129712128ULL      // bf16 [2048][832]   (mix2..FFN1)
#define OFF_W2T   133120000ULL      // bf16 [896][2048]   (mix2..FFN2)
#define OFF_AQB   152420352ULL      // bf16 3x[1152][832] (Aq|Ak|Av)
#define OFF_TVB   158307552ULL      // bf16 [128][832]
#define OFF_CO    158520544ULL      // f32  [14][812]
#define OFF_Z     158566016ULL      // f32  [14336]
#define OFF_ADJ   158623360ULL      // f32  [196 adj + 16 colw]
#define OFF_WG1T  158624384ULL      // bf16 [128][832]
#define OFF_WG2T  158837376ULL      // bf16 [128][128]

// ---------------------------------------------------------------------------
// Shared GEMM pipeline body, ROUND-12 geometry: 128x128 tile, BK=32,
// EIGHT waves (4x2 grid of 32x64 per wave), 512 threads. acc/wave = 2x4
// f32x4 = 32 AGPR (was 64) -> ~72 unified regs -> 6 waves/SIMD -> 3 blocks
// x 8 waves = 24 waves/CU (75% occupancy; round-6 evidence says these
// skinny-K GEMMs are occupancy-bound). Staging: 512 lanes cover each
// 128x32 tile in ONE gload per operand per iter. Double-buffered.
// Requirements unchanged: K%32==0, K-pads zeroed on BOTH operands,
// buffers readable to 128-row multiples, M/N edge-masked epilogue.
// swiz=1: id%8 -> row-tile (XCD L2 reuse).
// epi 0: Cf=v. 1: Cb=bf16(relu(v+bias[cn])). 2: Cf=v+bias[cn]+bf2f(Cb).
// 3: Cb=bf16(v). 4: split-3 into [Aq|Ak|Av]. 5: Cb=bf16(v/bias[rm]).
// 6: Cf=v+bias[cn]. 7: Cb=bf16(v+bias[cn]+bf2f(((u16*)Cf)[rm*ldc+cn])).
// 8: T-split: cn<812 -> Cb[(1024+rm)*KP_+cn]; cn>=1624 -> ((u16*)Cf)[rm*KP_+cn-1624].
// ---------------------------------------------------------------------------
__device__ __forceinline__ void gemm_body(
    const u16* __restrict__ A, int lda,
    const u16* __restrict__ Bm, int ldb,
    int M, int N, int K, float scale,
    float* __restrict__ Cf, int ldc,
    u16* __restrict__ Cb, int ldcb,
    const float* __restrict__ bias,
    int nxt, int swiz, int epi, int id)
{
    __shared__ __align__(16) u16 As[2][128 * 32];
    __shared__ __align__(16) u16 Bs[2][128 * 32];
    const int tid = threadIdx.x;
    int bx, by;
    if (swiz) { int r8 = id & 7; int q = id >> 3; bx = q % nxt; by = (q / nxt) * 8 + r8; }
    else      { bx = id % nxt; by = id / nxt; }
    const int row0 = by * 128, col0 = bx * 128;
    const int lane = tid & 63, wv = tid >> 6;          // wv 0..7
    const int wm = (wv >> 1) * 32, wn = (wv & 1) * 64; // wave = 32x64
    const int fr = lane & 15, qd = lane >> 4;

    // staging: thread t loads row t>>2, k-offset (t&3)*8 of each 128x32 tile.
    // LDS dst wave-uniform base wv*512 u16 (+ lane*16B per HW).
    const int s_row = tid >> 2;
    const int s_ko  = (tid & 3) * 8;
    const int s_b0  = wv * 512;
    const u16* Arow = A  + (size_t)(row0 + s_row) * lda + s_ko;
    const u16* Brow = Bm + (size_t)(col0 + s_row) * ldb + s_ko;

    f32x4 acc[2][4] = {};

    const int T = K >> 5;
    gload_lds16(Arow, &As[0][s_b0]);
    gload_lds16(Brow, &Bs[0][s_b0]);

    for (int i = 0; i < T; ++i) {
        __syncthreads();   // drains tile-i loads (issued one compute-phase ago)
        const int cur = i & 1;
        if (i + 1 < T) {
            const int ko = (i + 1) << 5;
            gload_lds16(Arow + ko, &As[cur ^ 1][s_b0]);
            gload_lds16(Brow + ko, &Bs[cur ^ 1][s_b0]);
        }
        bf16x8 af[2], bg[4];
        #pragma unroll
        for (int j = 0; j < 2; ++j)
            af[j] = *(const bf16x8*)&As[cur][(wm + j * 16 + fr) * 32 + qd * 8];
        #pragma unroll
        for (int j = 0; j < 4; ++j)
            bg[j] = *(const bf16x8*)&Bs[cur][(wn + j * 16 + fr) * 32 + qd * 8];
        #pragma unroll
        for (int mi = 0; mi < 2; ++mi)
            #pragma unroll
            for (int ni = 0; ni < 4; ++ni)
                acc[mi][ni] = __builtin_amdgcn_mfma_f32_16x16x32_bf16(
                    af[mi], bg[ni], acc[mi][ni], 0, 0, 0);
    }

    #pragma unroll
    for (int mi = 0; mi < 2; ++mi) {
        #pragma unroll
        for (int i = 0; i < 4; ++i) {
            int rm = row0 + wm + mi * 16 + qd * 4 + i;
            if (rm >= M) continue;
            #pragma unroll
            for (int ni = 0; ni < 4; ++ni) {
                int cn = col0 + wn + ni * 16 + fr;
                if (cn >= N) continue;
                float v = acc[mi][ni][i] * scale;
                if (epi == 0) Cf[(size_t)rm * ldc + cn] = v;
                else if (epi == 1) { v += bias[cn]; v = v > 0.f ? v : 0.f;
                                Cb[(size_t)rm * ldcb + cn] = f2bf(v); }
                else if (epi == 2) Cf[(size_t)rm * ldc + cn] =
                                v + bias[cn] + bf2f(Cb[(size_t)rm * ldcb + cn]);
                else if (epi == 3) Cb[(size_t)rm * ldcb + cn] = f2bf(v);
                else if (epi == 4) { int bs = cn / DD_, cc = cn - bs * DD_;
                                Cb[(size_t)bs * (AROWS_ * KP_) + (size_t)rm * KP_ + cc] = f2bf(v); }
                else if (epi == 5) { float invz = 1.0f / bias[rm];
                                Cb[(size_t)rm * ldcb + cn] = f2bf(v * invz); }
                else if (epi == 6) Cf[(size_t)rm * ldc + cn] = v + bias[cn];
                else if (epi == 7) { const u16* rx = (const u16*)Cf;
                                Cb[(size_t)rm * ldcb + cn] =
                                    f2bf(v + bias[cn] + bf2f(rx[(size_t)rm * ldc + cn])); }
                else if (epi == 8) {
                    float t = v + bias[cn];
                    if (cn < DD_) Cb[(size_t)(1024 + rm) * KP_ + cn] = f2bf(t);
                    else if (cn >= 2 * DD_)
                        ((u16*)Cf)[(size_t)rm * KP_ + (cn - 2 * DD_)] = f2bf(t);
                }
            }
        }
    }
}

template<int EPI>
__global__ __launch_bounds__(512, 6)
void bgemm(const u16* __restrict__ A, int lda,
           const u16* __restrict__ Bm, int ldb,
           int M, int N, int K, float scale,
           float* __restrict__ Cf, int ldc,
           u16* __restrict__ Cb, int ldcb,
           const float* __restrict__ bias,
           int nxt, int swiz)
{
    gemm_body(A, lda, Bm, ldb, M, N, K, scale, Cf, ldc, Cb, ldcb, bias,
              nxt, swiz, EPI, blockIdx.x);
}

// ---------------------------------------------------------------------------
// Mixed launch: grouped GEMMs + cast-transpose tiles + adjacency in ONE
// dispatch. gemm path = gemm_body (512-thread geometry); transpose path
// its own 4.2 KB tile.
// ---------------------------------------------------------------------------
struct GDesc {
    const u16* A; const u16* B; float* Cf; u16* Cb; const float* bias;
    int lda, ldb, ldc, ldcb, M, N, K, epi, nxt, swiz, blk0;
    float scale;
};
struct TDesc { const float* src; u16* dst; int srs, drs, rows, cols, padrows, rt, nblk; };
struct MPack { GDesc g[3]; TDesc t[2]; const int* ei; float* Adj; int ng, gtot, nt; };

// Coalesced LDS-tiled cast-transpose tile (512 threads: 32x16, 2 rows each).
__device__ __forceinline__ void castT_body(TDesc T, int id)
{
    __shared__ float t[32][33];
    const int bx = id % T.rt, by = id / T.rt;
    const int r0 = bx * 32, c0 = by * 32;
    const int tx = threadIdx.x & 31, ty = threadIdx.x >> 5;   // ty 0..15
    #pragma unroll
    for (int k = 0; k < 2; ++k) {
        int r = r0 + ty + k * 16, c = c0 + tx;
        t[ty + k * 16][tx] = (r < T.rows && c < T.cols) ? T.src[(size_t)r * T.srs + c] : 0.f;
    }
    __syncthreads();
    #pragma unroll
    for (int k = 0; k < 2; ++k) {
        int c = c0 + ty + k * 16, r = r0 + tx;
        if (c < T.cols && r < T.padrows)
            T.dst[(size_t)c * T.drs + r] = f2bf(t[tx][ty + k * 16]);
    }
}

// Dense 14x14 GCN adjacency + column means (serial, 1 thread).
__device__ __forceinline__ void adj_body(const int* __restrict__ ei, float* __restrict__ Adj)
{
    if (threadIdx.x != 0) return;
    float deg[NN_];
    for (int i = 0; i < NN_; ++i) deg[i] = 1.f;
    for (int e = 0; e < EE_; ++e) deg[ei[EE_ + e]] += 1.f;
    float dinv[NN_];
    for (int i = 0; i < NN_; ++i) dinv[i] = rsqrtf(deg[i]);
    float adj[NN_ * NN_];
    for (int t = 0; t < NN_ * NN_; ++t) adj[t] = 0.f;
    for (int e = 0; e < EE_; ++e) {
        int s = ei[e], d = ei[EE_ + e];
        adj[d * NN_ + s] += dinv[s] * dinv[d];
    }
    for (int i = 0; i < NN_; ++i) adj[i * NN_ + i] += dinv[i] * dinv[i];
    for (int t = 0; t < NN_ * NN_; ++t) Adj[t] = adj[t];
    for (int i = 0; i < 16; ++i) {
        float s = 0.f;
        if (i < NN_) for (int j = 0; j < NN_; ++j) s += adj[j * NN_ + i];
        Adj[NN_ * NN_ + i] = s / (float)NN_;
    }
}

__global__ __launch_bounds__(512, 6)
void kern_mix(MPack p)
{
    int id = blockIdx.x;
    if (id < p.gtot) {
        int si = 0;
        for (int s = 1; s < p.ng; ++s) if (id >= p.g[s].blk0) si = s;
        GDesc D = p.g[si];
        gemm_body(D.A, D.lda, D.B, D.ldb, D.M, D.N, D.K, D.scale,
                  D.Cf, D.ldc, D.Cb, D.ldcb, D.bias, D.nxt, D.swiz, D.epi,
                  id - D.blk0);
        return;
    }
    id -= p.gtot;
    for (int s = 0; s < p.nt; ++s) {
        if (id < p.t[s].nblk) { castT_body(p.t[s], id); return; }
        id -= p.t[s].nblk;
    }
    if (id == 0 && p.ei) adj_body(p.ei, p.Adj);
}

// Multi-segment fp32->bf16 cast (+ zero-fill segments with scols=0).
struct CDesc { const float* src; u16* dst; int srs, drs, dcols, scols; };
struct CPack { CDesc d[9]; unsigned cum[10]; int n; };

__global__ void kern_mcast(CPack p)
{
    unsigned idx = blockIdx.x * 256 + threadIdx.x;
    int si = -1;
    for (int s = 0; s < p.n; ++s)
        if (idx >= p.cum[s] && idx < p.cum[s + 1]) { si = s; break; }
    if (si < 0) return;
    CDesc D = p.d[si];
    unsigned k = idx - p.cum[si];
    int r = k / D.dcols, c = k - r * D.dcols;
    D.dst[(size_t)r * D.drs + c] =
        (c < D.scols) ? f2bf(D.src[(size_t)r * D.srs + c]) : (u16)0;
}

// Fused [ew rowmax+exp] + exp(S0) + G + Z.
__global__ __launch_bounds__(256) void kern_eG(const float* __restrict__ S,
    u16* __restrict__ Gb, float* __restrict__ Z)
{
    __shared__ float red[256];
    __shared__ u16 ews[NN_ * 1024];   // 28.7 KB
    const int l = blockIdx.x, tid = threadIdx.x;
    const int lane = tid & 63, wv = tid >> 6;

    const float* wraw = S + 1024 * 1024;
    for (int z = wv; z < NN_; z += 4) {
        const float* r = wraw + z * 1024;
        float vv[16], mx = -1e30f;
        #pragma unroll
        for (int j = 0; j < 16; ++j) { vv[j] = r[lane + 64 * j]; mx = fmaxf(mx, vv[j]); }
        #pragma unroll
        for (int off = 32; off > 0; off >>= 1) mx = fmaxf(mx, __shfl_down(mx, off));
        mx = __shfl(mx, 0);
        #pragma unroll
        for (int j = 0; j < 16; ++j)
            ews[z * 1024 + lane + 64 * j] = f2bf(expf(vv[j] - mx));
    }
    const float* row = S + (size_t)l * 1024;
    float m = -1e30f;
    #pragma unroll
    for (int k = 0; k < 4; ++k) m = fmaxf(m, row[tid + 256 * k]);
    red[tid] = m; __syncthreads();          // also publishes ews
    for (int s = 128; s > 0; s >>= 1) {
        if (tid < s) red[tid] = fmaxf(red[tid], red[tid + s]);
        __syncthreads();
    }
    m = red[0];
    float ev[16];
    #pragma unroll
    for (int j = 0; j < 16; ++j) ev[j] = expf(row[lane + 64 * j] - m);
    u16* gr = Gb + (size_t)l * NN_ * 1024;
    for (int z = wv; z < NN_; z += 4) {
        const u16* er = &ews[z * 1024];
        float s = 0.f;
        #pragma unroll
        for (int j = 0; j < 16; ++j) {
            float pv = ev[j] * bf2f(er[lane + 64 * j]);
            gr[(size_t)z * 1024 + lane + 64 * j] = f2bf(pv);
            s += pv;
        }
        #pragma unroll
        for (int off = 32; off > 0; off >>= 1) s += __shfl_down(s, off);
        if (lane == 0) Z[l * NN_ + z] = s;
    }
}

// x1 = LN1(node + Pb + co); Pb is bf16 attn-out already scaled by 1/Z.
__global__ __launch_bounds__(256) void kern_ln1(
    const float* __restrict__ img, const float* __restrict__ word,
    const u16* __restrict__ Pb,
    const float* __restrict__ co, const float* __restrict__ g,
    const float* __restrict__ bta, u16* __restrict__ Xb)
{
    __shared__ float buf[DD_];
    __shared__ float red[256];
    __shared__ float stats[2];
    int row = blockIdx.x;
    int b = row / NN_, n = row - b * NN_;
    const u16* pr = Pb + (size_t)row * DD_;
    const float* cr = co + n * DD_;
    float s = 0.f;
    for (int d = threadIdx.x; d < DD_; d += 256) {
        float v = (d < IMG_) ? img[(size_t)b * IMG_ + d] : word[n * TXT_ + d - IMG_];
        v += bf2f(pr[d]) + cr[d];
        buf[d] = v; s += v;
    }
    red[threadIdx.x] = s; __syncthreads();
    for (int t = 128; t > 0; t >>= 1) {
        if (threadIdx.x < t) red[threadIdx.x] += red[threadIdx.x + t];
        __syncthreads();
    }
    if (threadIdx.x == 0) stats[0] = red[0] / DD_;
    __syncthreads();
    float mu = stats[0], s2 = 0.f;
    for (int d = threadIdx.x; d < DD_; d += 256) { float t = buf[d] - mu; s2 += t * t; }
    red[threadIdx.x] = s2; __syncthreads();
    for (int t = 128; t > 0; t >>= 1) {
        if (threadIdx.x < t) red[threadIdx.x] += red[threadIdx.x + t];
        __syncthreads();
    }
    if (threadIdx.x == 0) stats[1] = rsqrtf(red[0] / DD_ + 1e-5f);
    __syncthreads();
    float rstd = stats[1];
    u16* xb = Xb + (size_t)row * KP_;
    for (int d = threadIdx.x; d < DD_; d += 256)
        xb[d] = f2bf((buf[d] - mu) * rstd * g[d] + bta[d]);
    for (int d = DD_ + threadIdx.x; d < KP_; d += 256) xb[d] = 0;
}

// ---------------------------------------------------------------------------
// Fused LN2 + GCN1 + GCN2 + mean-pool + linear. One block per image b.
// ---------------------------------------------------------------------------
#define X2S_ 840
#define G1S_ 136
__global__ __launch_bounds__(256, 4)
void kern_gcn(const u16* __restrict__ Yb,
              const float* __restrict__ g2v, const float* __restrict__ bt2,
              const u16* __restrict__ Wg1T, const float* __restrict__ bg1,
              const u16* __restrict__ Wg2T, const float* __restrict__ bg2,
              const float* __restrict__ Wl,  const float* __restrict__ bl,
              const float* __restrict__ AdjW, float* __restrict__ out)
{
    __shared__ __align__(16) u16 x2s[16 * X2S_];      // 26.9 KB; g1s overlays
    __shared__ __align__(16) float h1s[16 * 132];     // 8.4 KB
    __shared__ float adj_s[NN_ * NN_];
    __shared__ float colw_s[16];
    __shared__ float pool_s[HID_];
    u16* g1s = x2s;                                   // overlay (16*G1S_ u16)
    const int b = blockIdx.x, tid = threadIdx.x;
    const int lane = tid & 63, wv = tid >> 6;
    const int fr = lane & 15, qd = lane >> 4;

    if (tid < NN_ * NN_) adj_s[tid] = AdjW[tid];
    if (tid >= NN_ * NN_ && tid < NN_ * NN_ + 16) colw_s[tid - NN_ * NN_] = AdjW[tid];
    for (int k = tid; k < 2 * X2S_; k += 256) x2s[14 * X2S_ + k] = 0;
    for (int k = tid; k < 14 * (X2S_ - DD_); k += 256) {
        int j = k / (X2S_ - DD_), c = k - j * (X2S_ - DD_);
        x2s[j * X2S_ + DD_ + c] = 0;
    }

    // --- LN2 per node row ---
    for (int j = wv; j < NN_; j += 4) {
        const u16* yr = Yb + (size_t)(b * NN_ + j) * KP_;
        float vv[13], s = 0.f;
        #pragma unroll
        for (int k = 0; k < 13; ++k) {
            int d = lane + 64 * k;
            float v = (d < DD_) ? bf2f(yr[d]) : 0.f;
            vv[k] = v; s += v;
        }
        #pragma unroll
        for (int off = 32; off > 0; off >>= 1) s += __shfl_down(s, off);
        s = __shfl(s, 0);
        float mu = s / (float)DD_, s2 = 0.f;
        #pragma unroll
        for (int k = 0; k < 13; ++k) {
            int d = lane + 64 * k;
            float t = (d < DD_) ? vv[k] - mu : 0.f;
            s2 += t * t;
        }
        #pragma unroll
        for (int off = 32; off > 0; off >>= 1) s2 += __shfl_down(s2, off);
        s2 = __shfl(s2, 0);
        float rstd = rsqrtf(s2 / (float)DD_ + 1e-5f);
        #pragma unroll
        for (int k = 0; k < 13; ++k) {
            int d = lane + 64 * k;
            if (d < DD_)
                x2s[j * X2S_ + d] = f2bf((vv[k] - mu) * rstd * g2v[d] + bt2[d]);
        }
    }
    __syncthreads();

    // --- GCN1 (MFMA, M=16, K=KP_) ---
    {
        f32x4 acc[2] = {{}, {}};
        const u16* wp0 = Wg1T + (size_t)(wv * 32 + fr) * KP_ + qd * 8;
        const u16* wp1 = wp0 + (size_t)16 * KP_;
        bf16x8 bc0 = *(const bf16x8*)wp0;
        bf16x8 bc1 = *(const bf16x8*)wp1;
        for (int k0 = 0; k0 < KP_; k0 += 32) {
            bf16x8 bn0 = bc0, bn1 = bc1;
            if (k0 + 32 < KP_) {
                bn0 = *(const bf16x8*)(wp0 + k0 + 32);
                bn1 = *(const bf16x8*)(wp1 + k0 + 32);
            }
            bf16x8 af = *(const bf16x8*)&x2s[fr * X2S_ + k0 + qd * 8];
            acc[0] = __builtin_amdgcn_mfma_f32_16x16x32_bf16(af, bc0, acc[0], 0, 0, 0);
            acc[1] = __builtin_amdgcn_mfma_f32_16x16x32_bf16(af, bc1, acc[1], 0, 0, 0);
            bc0 = bn0; bc1 = bn1;
        }
        #pragma unroll
        for (int t = 0; t < 2; ++t)
            #pragma unroll
            for (int i = 0; i < 4; ++i)
                h1s[(qd * 4 + i) * 132 + wv * 32 + t * 16 + fr] = acc[t][i];
    }
    __syncthreads();   // x2s dead; g1s overlay now writable

    // --- G1 = relu(Adj @ H1 + bg1) -> bf16; zero pad rows 14,15 ---
    {
        const int f = tid & 127, jj = (tid >> 7) * 7;
        #pragma unroll
        for (int j = 0; j < 7; ++j) {
            float s = bg1[f];
            #pragma unroll
            for (int i = 0; i < NN_; ++i)
                s = fmaf(adj_s[(jj + j) * NN_ + i], h1s[i * 132 + f], s);
            g1s[(jj + j) * G1S_ + f] = f2bf(s > 0.f ? s : 0.f);
        }
        for (int k = tid; k < 2 * G1S_; k += 256) g1s[14 * G1S_ + k] = 0;
    }
    __syncthreads();

    // --- GCN2 (MFMA, K=128) + pool = relu(colw·H2 + bg2) ---
    {
        f32x4 acc[2] = {{}, {}};
        const u16* wp0 = Wg2T + (size_t)(wv * 32 + fr) * HID_ + qd * 8;
        const u16* wp1 = wp0 + (size_t)16 * HID_;
        bf16x8 bc0 = *(const bf16x8*)wp0;
        bf16x8 bc1 = *(const bf16x8*)wp1;
        for (int k0 = 0; k0 < HID_; k0 += 32) {
            bf16x8 bn0 = bc0, bn1 = bc1;
            if (k0 + 32 < HID_) {
                bn0 = *(const bf16x8*)(wp0 + k0 + 32);
                bn1 = *(const bf16x8*)(wp1 + k0 + 32);
            }
            bf16x8 af = *(const bf16x8*)&g1s[fr * G1S_ + k0 + qd * 8];
            acc[0] = __builtin_amdgcn_mfma_f32_16x16x32_bf16(af, bc0, acc[0], 0, 0, 0);
            acc[1] = __builtin_amdgcn_mfma_f32_16x16x32_bf16(af, bc1, acc[1], 0, 0, 0);
            bc0 = bn0; bc1 = bn1;
        }
        #pragma unroll
        for (int t = 0; t < 2; ++t) {
            float s = 0.f;
            #pragma unroll
            for (int i = 0; i < 4; ++i) s += colw_s[qd * 4 + i] * acc[t][i];
            s += __shfl_xor(s, 16);
            s += __shfl_xor(s, 32);
            if (qd == 0) {
                int f = wv * 32 + t * 16 + fr;
                float p = s + bg2[f];
                pool_s[f] = p > 0.f ? p : 0.f;
            }
        }
    }
    __syncthreads();

    // --- out = pool @ Wl + bl ---
    if (tid < CC_) {
        float s = bl[tid];
        #pragma unroll 8
        for (int f = 0; f < HID_; ++f)
            s = fmaf(pool_s[f], Wl[(size_t)f * CC_ + tid], s);
        out[(size_t)b * CC_ + tid] = s;
    }
}

extern "C" void kernel_launch(void* const* d_in, const int* in_sizes, int n_in,
                              void* d_out, int out_size, void* d_ws, size_t ws_size,
                              hipStream_t stream)
{
    const float* img  = (const float*)d_in[0];
    const float* word = (const float*)d_in[1];
    const int*   ei   = (const int*)d_in[2];
    const float* Wi   = (const float*)d_in[3];
    const float* bi   = (const float*)d_in[4];
    const float* Wo   = (const float*)d_in[5];
    const float* bo   = (const float*)d_in[6];
    const float* g1   = (const float*)d_in[7];
    const float* bt1  = (const float*)d_in[8];
    const float* g2   = (const float*)d_in[9];
    const float* bt2  = (const float*)d_in[10];
    const float* W1   = (const float*)d_in[11];
    const float* bf1  = (const float*)d_in[12];
    const float* W2   = (const float*)d_in[13];
    const float* bf2  = (const float*)d_in[14];
    const float* Wg1  = (const float*)d_in[15];
    const float* bg1  = (const float*)d_in[16];
    const float* Wg2  = (const float*)d_in[17];
    const float* bg2  = (const float*)d_in[18];
    const float* Wl   = (const float*)d_in[19];
    const float* bl   = (const float*)d_in[20];
    float* out = (float*)d_out;

    char* ws = (char*)d_ws;
    u16*   imgb = (u16*)  (ws + OFF_IMGB);
    u16*   Wib  = (u16*)  (ws + OFF_WIB);
    u16*   wordb= (u16*)  (ws + OFF_WORDB);
    u16*   WiTX = (u16*)  (ws + OFF_WITX);
    u16*   Gb   = (u16*)  (ws + OFF_GB);
    float* Ebuf = (float*)(ws + OFF_EBUF);
    u16*   AvoT = (u16*)  (ws + OFF_AVOT);
    u16*   Wob  = (u16*)  (ws + OFF_WOB);
    u16*   Hb   = (u16*)  (ws + OFF_HB);
    u16*   Pb   = (u16*)  (ws + OFF_PB);
    u16*   X1b  = (u16*)  (ws + OFF_X1B);
    u16*   Yb   = (u16*)  (ws + OFF_YB);
    u16*   W1T  = (u16*)  (ws + OFF_W1T);
    u16*   W2T  = (u16*)  (ws + OFF_W2T);
    u16*   Aqb  = (u16*)  (ws + OFF_AQB);
    u16*   Akb  = Aqb + AROWS_ * KP_;
    u16*   Avb  = Aqb + 2 * AROWS_ * KP_;
    u16*   Tvb  = (u16*)  (ws + OFF_TVB);
    float* co   = (float*)(ws + OFF_CO);
    float* Zb   = (float*)(ws + OFF_Z);
    float* Adj  = (float*)(ws + OFF_ADJ);
    u16*   Wg1T = (u16*)  (ws + OFF_WG1T);
    u16*   Wg2T = (u16*)  (ws + OFF_WG2T);

    const float scl = 1.0f / sqrtf((float)DD_);

    // --- launch 1: multi-cast (input casts + all K-pad zeroing) ---
    {
        CPack p; p.n = 9;
        unsigned c = 0;
        auto seg = [&](int i, const float* s, int srs, u16* d, int drs,
                       int rows, int dcols, int scols) {
            p.d[i] = { s, d, srs, drs, dcols, scols };
            p.cum[i] = c; c += (unsigned)rows * dcols;
        };
        seg(0, img,        IMG_, imgb,  IMG_, B_,   IMG_, IMG_);
        seg(1, Wi,         DD_,  Wib,   IMG_, D3_,  IMG_, IMG_);
        seg(2, word,       TXT_, wordb, TXP_, NN_,  TXP_, TXT_);
        seg(3, Wi + IMG_,  DD_,  WiTX,  TXP_, D3_,  TXP_, TXT_);
        seg(4, Wo,         DD_,  Wob,   KP_,  DD_,  KP_,  DD_);
        seg(5, nullptr, 0, Aqb + DD_,                    KP_, 1038, 20, 0); // Aq + Tq rows
        seg(6, nullptr, 0, Aqb + AROWS_ * KP_ + DD_,     KP_, 1024, 20, 0);
        seg(7, nullptr, 0, Aqb + 2 * AROWS_ * KP_ + DD_, KP_, 1024, 20, 0);
        seg(8, nullptr, 0, Tvb + DD_,                    KP_, NN_,  20, 0); // Tvb pads
        p.cum[9] = c;
        kern_mcast<<<(c + 255) / 256, 256, 0, stream>>>(p);
    }

    // --- launch 2 (mix1): T epi8 + A-proj || Wg1T/Wg2T transposes || adj ---
    {
        MPack p{};
        p.ng = 2; p.gtot = 180;
        p.g[0] = { wordb, WiTX, (float*)Tvb, Aqb, bi,
                   TXP_, TXP_, 0, 0, NN_, D3_, TXP_, 8, 20, 0, 0, 1.f };
        p.g[1] = { imgb, Wib, nullptr, Aqb, nullptr,
                   IMG_, IMG_, 0, 0, B_, D3_, IMG_, 4, 20, 1, 20, 1.f };
        p.nt = 2;
        p.t[0] = { Wg1, Wg1T, HID_, KP_,  DD_,  HID_, KP_,  26, 26 * 4 };
        p.t[1] = { Wg2, Wg2T, HID_, HID_, HID_, HID_, HID_, 4,  4 * 4 };
        p.ei = ei; p.Adj = Adj;
        kern_mix<<<180 + 104 + 16 + 1, 512, 0, stream>>>(p);
    }

    // --- launch 3 (mix2): S0+w || AvoT || co  ||  W1T/W2T transposes ---
    {
        MPack p{};
        p.ng = 3; p.gtot = 135;
        p.g[0] = { Aqb, Akb, Ebuf, nullptr, nullptr,
                   KP_, KP_, 1024, 0, 1024 + NN_, 1024, KP_, 0, 8, 0, 0, scl };
        p.g[1] = { Wob, Avb, nullptr, AvoT, nullptr,
                   KP_, KP_, 0, 1024, DD_, B_, KP_, 3, 8, 0, 72, 1.f };
        p.g[2] = { Tvb, Wob, co, nullptr, bo,
                   KP_, KP_, DD_, 0, NN_, DD_, KP_, 6, 7, 0, 128, 1.f };
        p.nt = 2;
        p.t[0] = { W1, W1T, FF_, KP_, DD_, FF_, KP_, 26, 26 * 64 };
        p.t[1] = { W2, W2T, DD_, FF_, FF_, DD_, FF_, 64, 64 * 26 };
        p.ei = nullptr; p.Adj = nullptr;
        kern_mix<<<135 + 1664 + 1664, 512, 0, stream>>>(p);
    }

    // --- launch 4: fused ew-exp + exp + G + Z ---
    kern_eG<<<1024, 256, 0, stream>>>(Ebuf, Gb, Zb);

    // --- launch 5: Pb = (G @ Avo)/Z as bf16 ---
    bgemm<5><<<7 * 112, 512, 0, stream>>>(Gb, 1024, AvoT, 1024,
        BNR_, DD_, 1024, 1.f, nullptr, 0, Pb, DD_, Zb, 7, 1);

    // --- launch 6: LN1 ---
    kern_ln1<<<BNR_, 256, 0, stream>>>(img, word, Pb, co, g1, bt1, X1b);

    // --- launches 7,8: FFN ---
    bgemm<1><<<16 * 112, 512, 0, stream>>>(X1b, KP_, W1T, KP_,
        BNR_, FF_, KP_, 1.f, nullptr, 0, Hb, FF_, bf1, 16, 1);
    bgemm<7><<<7 * 112, 512, 0, stream>>>(Hb, FF_, W2T, FF_,
        BNR_, DD_, FF_, 1.f, (float*)X1b, KP_, Yb, KP_, bf2, 7, 1);

    // --- launch 9: fused LN2 + GCN1 + GCN2 + pool + linear ---
    kern_gcn<<<B_, 256, 0, stream>>>(Yb, g2, bt2, Wg1T, bg1, Wg2T, bg2,
                                     Wl, bl, Adj, out);
}

// Round 13
// 456.726 us; speedup vs baseline: 5.3445x; 1.1658x over previous
//
#include <hip/hip_runtime.h>
#include <math.h>

// Problem constants
#define B_    1024
#define IMG_  512
#define TXT_  300
#define NN_   14
#define FF_   2048
#define HID_  128
#define CC_   14
#define EE_   182
#define DD_   812
#define D3_   2436
#define BNR_  14336          // B_*NN_
#define KP_   832            // 812 padded to /32 (16B-aligned rows)
#define TXP_  320            // 300 padded to /32
#define AROWS_ 1152          // Aq/Ak/Av rows: 1024 data + 14 Tq + pad to tile mult

typedef __bf16 bf16x8 __attribute__((ext_vector_type(8)));
typedef float  f32x4  __attribute__((ext_vector_type(4)));
typedef unsigned short u16;

__device__ __forceinline__ u16 f2bf(float f) {
    union { float f; unsigned u; } v; v.f = f;
    unsigned r = v.u + 0x7FFFu + ((v.u >> 16) & 1u);   // RNE
    return (u16)(r >> 16);
}
__device__ __forceinline__ float bf2f(u16 h) {
    union { unsigned u; float f; } v; v.u = ((unsigned)h) << 16; return v.f;
}

// async global->LDS, 16B per lane. LDS dst = wave-uniform base + lane*16.
__device__ __forceinline__ void gload_lds16(const u16* g, u16* l) {
    __builtin_amdgcn_global_load_lds(
        (const __attribute__((address_space(1))) void*)g,
        (__attribute__((address_space(3))) void*)l, 16, 0, 0);
}

// ---------------------------------------------------------------------------
// Workspace layout (bytes), time-multiplexed overlays (audited vs launch
// timeline; garbage/NaN only reaches epilogue-masked rows/cols; K-pads of
// real rows always explicitly zeroed).
// ---------------------------------------------------------------------------
#define OFF_IMGB  0ULL              // bf16 [1024][512]
#define OFF_WIB   1048576ULL        // bf16 [2436][512]
#define OFF_WORDB 3543040ULL        // bf16 [128][320]
#define OFF_WITX  3624960ULL        // bf16 [2560][320]
#define OFF_GB    0ULL              // bf16 [14336][1024] (eG..P)
#define OFF_EBUF  29360128ULL       // f32  [1038][1024]  (S0..eG)
#define OFF_AVOT  33611776ULL       // bf16 [896][1024]   (mix2..P)
#define OFF_WOB   35446784ULL       // bf16 [896][832]    (mcast..mix2)
#define OFF_HB    0ULL              // bf16 [14336][2048] (FFN1..FFN2)
#define OFF_PB    58720256ULL       // bf16 [14336][812]  (P..ln1)
#define OFF_X1B   82001920ULL       // bf16 [14336][832]  (ln1..FFN2)
#define OFF_YB    105857024ULL      // bf16 [14336][832]  (FFN2..gcn)
#define OFF_W1T   129712128ULL      // bf16 [2048][832]   (mix2..FFN1)
#define OFF_W2T   133120000ULL      // bf16 [896][2048]   (mix2..FFN2)
#define OFF_AQB   152420352ULL      // bf16 3x[1152][832] (Aq|Ak|Av)
#define OFF_TVB   158307552ULL      // bf16 [128][832]
#define OFF_CO    158520544ULL      // f32  [14][812]
#define OFF_Z     158566016ULL      // f32  [14336]
#define OFF_ADJ   158623360ULL      // f32  [196 adj + 16 colw]
#define OFF_WG1T  158624384ULL      // bf16 [128][832]
#define OFF_WG2T  158837376ULL      // bf16 [128][128]

// ---------------------------------------------------------------------------
// 4-wave GEMM body (round-11 proven: FFN1 ~96 µs): 128x128 tile, BK=32,
// 256 threads, 2x2 waves of 64x64, 64 AGPR acc, double-buffered
// global_load_lds. Used by the big standalone bgemm launches.
// epi 0: Cf=v. 1: Cb=bf16(relu(v+bias[cn])). 2: Cf=v+bias[cn]+bf2f(Cb).
// 3: Cb=bf16(v). 4: split-3 into [Aq|Ak|Av]. 5: Cb=bf16(v/bias[rm]).
// 6: Cf=v+bias[cn]. 7: Cb=bf16(v+bias[cn]+bf2f(((u16*)Cf)[rm*ldc+cn])).
// 8: T-split: cn<812 -> Cb[(1024+rm)*KP_+cn]; cn>=1624 -> ((u16*)Cf)[rm*KP_+cn-1624].
// ---------------------------------------------------------------------------
__device__ __forceinline__ void gemm_epi(
    float v, int rm, int cn, int epi,
    float* __restrict__ Cf, int ldc, u16* __restrict__ Cb, int ldcb,
    const float* __restrict__ bias)
{
    if (epi == 0) Cf[(size_t)rm * ldc + cn] = v;
    else if (epi == 1) { v += bias[cn]; v = v > 0.f ? v : 0.f;
                    Cb[(size_t)rm * ldcb + cn] = f2bf(v); }
    else if (epi == 2) Cf[(size_t)rm * ldc + cn] =
                    v + bias[cn] + bf2f(Cb[(size_t)rm * ldcb + cn]);
    else if (epi == 3) Cb[(size_t)rm * ldcb + cn] = f2bf(v);
    else if (epi == 4) { int bs = cn / DD_, cc = cn - bs * DD_;
                    Cb[(size_t)bs * (AROWS_ * KP_) + (size_t)rm * KP_ + cc] = f2bf(v); }
    else if (epi == 5) { float invz = 1.0f / bias[rm];
                    Cb[(size_t)rm * ldcb + cn] = f2bf(v * invz); }
    else if (epi == 6) Cf[(size_t)rm * ldc + cn] = v + bias[cn];
    else if (epi == 7) { const u16* rx = (const u16*)Cf;
                    Cb[(size_t)rm * ldcb + cn] =
                        f2bf(v + bias[cn] + bf2f(rx[(size_t)rm * ldc + cn])); }
    else if (epi == 8) {
        float t = v + bias[cn];
        if (cn < DD_) Cb[(size_t)(1024 + rm) * KP_ + cn] = f2bf(t);
        else if (cn >= 2 * DD_)
            ((u16*)Cf)[(size_t)rm * KP_ + (cn - 2 * DD_)] = f2bf(t);
    }
}

__device__ __forceinline__ void gemm_body4(
    const u16* __restrict__ A, int lda,
    const u16* __restrict__ Bm, int ldb,
    int M, int N, int K, float scale,
    float* __restrict__ Cf, int ldc,
    u16* __restrict__ Cb, int ldcb,
    const float* __restrict__ bias,
    int nxt, int swiz, int epi, int id)
{
    __shared__ __align__(16) u16 As[2][128 * 32];
    __shared__ __align__(16) u16 Bs[2][128 * 32];
    const int tid = threadIdx.x;
    int bx, by;
    if (swiz) { int r8 = id & 7; int q = id >> 3; bx = q % nxt; by = (q / nxt) * 8 + r8; }
    else      { bx = id % nxt; by = id / nxt; }
    const int row0 = by * 128, col0 = bx * 128;
    const int lane = tid & 63, wv = tid >> 6;
    const int wm = (wv >> 1) * 64, wn = (wv & 1) * 64;
    const int fr = lane & 15, qd = lane >> 4;

    const int s_r0  = (wv * 64 + lane) >> 2;
    const int s_ko  = (lane & 3) * 8;
    const int s_b0  = (wv * 64) * 8;
    const u16* Arow0 = A  + (size_t)(row0 + s_r0) * lda + s_ko;
    const u16* Arow1 = A  + (size_t)(row0 + s_r0 + 64) * lda + s_ko;
    const u16* Brow0 = Bm + (size_t)(col0 + s_r0) * ldb + s_ko;
    const u16* Brow1 = Bm + (size_t)(col0 + s_r0 + 64) * ldb + s_ko;

    f32x4 acc[4][4] = {};

    const int T = K >> 5;
    gload_lds16(Arow0, &As[0][s_b0]);
    gload_lds16(Arow1, &As[0][s_b0 + 2048]);
    gload_lds16(Brow0, &Bs[0][s_b0]);
    gload_lds16(Brow1, &Bs[0][s_b0 + 2048]);

    for (int i = 0; i < T; ++i) {
        __syncthreads();
        const int cur = i & 1;
        if (i + 1 < T) {
            const int nb = cur ^ 1;
            const int ko = (i + 1) << 5;
            gload_lds16(Arow0 + ko, &As[nb][s_b0]);
            gload_lds16(Arow1 + ko, &As[nb][s_b0 + 2048]);
            gload_lds16(Brow0 + ko, &Bs[nb][s_b0]);
            gload_lds16(Brow1 + ko, &Bs[nb][s_b0 + 2048]);
        }
        bf16x8 af[4], bg[4];
        #pragma unroll
        for (int j = 0; j < 4; ++j) {
            af[j] = *(const bf16x8*)&As[cur][(wm + j * 16 + fr) * 32 + qd * 8];
            bg[j] = *(const bf16x8*)&Bs[cur][(wn + j * 16 + fr) * 32 + qd * 8];
        }
        #pragma unroll
        for (int mi = 0; mi < 4; ++mi)
            #pragma unroll
            for (int ni = 0; ni < 4; ++ni)
                acc[mi][ni] = __builtin_amdgcn_mfma_f32_16x16x32_bf16(
                    af[mi], bg[ni], acc[mi][ni], 0, 0, 0);
    }

    #pragma unroll
    for (int mi = 0; mi < 4; ++mi) {
        #pragma unroll
        for (int i = 0; i < 4; ++i) {
            int rm = row0 + wm + mi * 16 + qd * 4 + i;
            if (rm >= M) continue;
            #pragma unroll
            for (int ni = 0; ni < 4; ++ni) {
                int cn = col0 + wn + ni * 16 + fr;
                if (cn >= N) continue;
                gemm_epi(acc[mi][ni][i] * scale, rm, cn, epi, Cf, ldc, Cb, ldcb, bias);
            }
        }
    }
}

// 8-wave 512-thread body (round-12) — used ONLY inside kern_mix (small GEMMs).
__device__ __forceinline__ void gemm_body8(
    const u16* __restrict__ A, int lda,
    const u16* __restrict__ Bm, int ldb,
    int M, int N, int K, float scale,
    float* __restrict__ Cf, int ldc,
    u16* __restrict__ Cb, int ldcb,
    const float* __restrict__ bias,
    int nxt, int swiz, int epi, int id)
{
    __shared__ __align__(16) u16 As[2][128 * 32];
    __shared__ __align__(16) u16 Bs[2][128 * 32];
    const int tid = threadIdx.x;
    int bx, by;
    if (swiz) { int r8 = id & 7; int q = id >> 3; bx = q % nxt; by = (q / nxt) * 8 + r8; }
    else      { bx = id % nxt; by = id / nxt; }
    const int row0 = by * 128, col0 = bx * 128;
    const int lane = tid & 63, wv = tid >> 6;          // wv 0..7
    const int wm = (wv >> 1) * 32, wn = (wv & 1) * 64; // wave = 32x64
    const int fr = lane & 15, qd = lane >> 4;

    const int s_b0  = wv * 512;
    const int s_row = tid >> 2;
    const int s_ko  = (tid & 3) * 8;
    const u16* Arow = A  + (size_t)(row0 + s_row) * lda + s_ko;
    const u16* Brow = Bm + (size_t)(col0 + s_row) * ldb + s_ko;

    f32x4 acc[2][4] = {};

    const int T = K >> 5;
    gload_lds16(Arow, &As[0][s_b0]);
    gload_lds16(Brow, &Bs[0][s_b0]);

    for (int i = 0; i < T; ++i) {
        __syncthreads();
        const int cur = i & 1;
        if (i + 1 < T) {
            const int ko = (i + 1) << 5;
            gload_lds16(Arow + ko, &As[cur ^ 1][s_b0]);
            gload_lds16(Brow + ko, &Bs[cur ^ 1][s_b0]);
        }
        bf16x8 af[2], bg[4];
        #pragma unroll
        for (int j = 0; j < 2; ++j)
            af[j] = *(const bf16x8*)&As[cur][(wm + j * 16 + fr) * 32 + qd * 8];
        #pragma unroll
        for (int j = 0; j < 4; ++j)
            bg[j] = *(const bf16x8*)&Bs[cur][(wn + j * 16 + fr) * 32 + qd * 8];
        #pragma unroll
        for (int mi = 0; mi < 2; ++mi)
            #pragma unroll
            for (int ni = 0; ni < 4; ++ni)
                acc[mi][ni] = __builtin_amdgcn_mfma_f32_16x16x32_bf16(
                    af[mi], bg[ni], acc[mi][ni], 0, 0, 0);
    }

    #pragma unroll
    for (int mi = 0; mi < 2; ++mi) {
        #pragma unroll
        for (int i = 0; i < 4; ++i) {
            int rm = row0 + wm + mi * 16 + qd * 4 + i;
            if (rm >= M) continue;
            #pragma unroll
            for (int ni = 0; ni < 4; ++ni) {
                int cn = col0 + wn + ni * 16 + fr;
                if (cn >= N) continue;
                gemm_epi(acc[mi][ni][i] * scale, rm, cn, epi, Cf, ldc, Cb, ldcb, bias);
            }
        }
    }
}

template<int EPI>
__global__ __launch_bounds__(256, 4)
void bgemm(const u16* __restrict__ A, int lda,
           const u16* __restrict__ Bm, int ldb,
           int M, int N, int K, float scale,
           float* __restrict__ Cf, int ldc,
           u16* __restrict__ Cb, int ldcb,
           const float* __restrict__ bias,
           int nxt, int swiz)
{
    gemm_body4(A, lda, Bm, ldb, M, N, K, scale, Cf, ldc, Cb, ldcb, bias,
               nxt, swiz, EPI, blockIdx.x);
}

// ---------------------------------------------------------------------------
// Mixed launch: grouped small GEMMs + cast-transpose tiles + PARALLEL
// adjacency in one 512-thread dispatch. (Round-12 counters: serial adj_body
// = 119 µs tail at VALUBusy 0.016% — one wave crawling dependent loads.)
// ---------------------------------------------------------------------------
struct GDesc {
    const u16* A; const u16* B; float* Cf; u16* Cb; const float* bias;
    int lda, ldb, ldc, ldcb, M, N, K, epi, nxt, swiz, blk0;
    float scale;
};
struct TDesc { const float* src; u16* dst; int srs, drs, rows, cols, padrows, rt, nblk; };
struct MPack { GDesc g[3]; TDesc t[2]; const int* ei; float* Adj; int ng, gtot, nt; };

// Coalesced LDS-tiled cast-transpose tile (512 threads: 32x16, 2 rows each).
__device__ __forceinline__ void castT_body(TDesc T, int id)
{
    __shared__ float t[32][33];
    const int bx = id % T.rt, by = id / T.rt;
    const int r0 = bx * 32, c0 = by * 32;
    const int tx = threadIdx.x & 31, ty = threadIdx.x >> 5;   // ty 0..15
    #pragma unroll
    for (int k = 0; k < 2; ++k) {
        int r = r0 + ty + k * 16, c = c0 + tx;
        t[ty + k * 16][tx] = (r < T.rows && c < T.cols) ? T.src[(size_t)r * T.srs + c] : 0.f;
    }
    __syncthreads();
    #pragma unroll
    for (int k = 0; k < 2; ++k) {
        int c = c0 + ty + k * 16, r = r0 + tx;
        if (c < T.cols && r < T.padrows)
            T.dst[(size_t)c * T.drs + r] = f2bf(t[tx][ty + k * 16]);
    }
}

// PARALLEL dense 14x14 GCN adjacency + colw: edges distributed across
// threads, LDS atomics for deg/adj (182 edges, coalesced loads). Entire
// block participates (entered block-uniformly).
__device__ __forceinline__ void adj_body(const int* __restrict__ ei, float* __restrict__ Adj)
{
    __shared__ float degS[NN_], dinvS[NN_], adjS[NN_ * NN_];
    const int tid = threadIdx.x;
    if (tid < NN_) degS[tid] = 1.f;
    if (tid < NN_ * NN_) adjS[tid] = 0.f;
    __syncthreads();
    int s = 0, d = 0;
    if (tid < EE_) { s = ei[tid]; d = ei[EE_ + tid]; atomicAdd(&degS[d], 1.f); }
    __syncthreads();
    if (tid < NN_) dinvS[tid] = rsqrtf(degS[tid]);
    __syncthreads();
    if (tid < EE_) atomicAdd(&adjS[d * NN_ + s], dinvS[s] * dinvS[d]);
    if (tid < NN_) atomicAdd(&adjS[tid * NN_ + tid], dinvS[tid] * dinvS[tid]);
    __syncthreads();
    if (tid < NN_ * NN_) Adj[tid] = adjS[tid];
    if (tid < 16) {
        float sum = 0.f;
        if (tid < NN_)
            for (int j = 0; j < NN_; ++j) sum += adjS[j * NN_ + tid];
        Adj[NN_ * NN_ + tid] = sum / (float)NN_;
    }
}

__global__ __launch_bounds__(512, 6)
void kern_mix(MPack p)
{
    int id = blockIdx.x;
    if (id < p.gtot) {
        int si = 0;
        for (int s = 1; s < p.ng; ++s) if (id >= p.g[s].blk0) si = s;
        GDesc D = p.g[si];
        gemm_body8(D.A, D.lda, D.B, D.ldb, D.M, D.N, D.K, D.scale,
                   D.Cf, D.ldc, D.Cb, D.ldcb, D.bias, D.nxt, D.swiz, D.epi,
                   id - D.blk0);
        return;
    }
    id -= p.gtot;
    for (int s = 0; s < p.nt; ++s) {
        if (id < p.t[s].nblk) { castT_body(p.t[s], id); return; }
        id -= p.t[s].nblk;
    }
    if (id == 0 && p.ei) adj_body(p.ei, p.Adj);
}

// Multi-segment fp32->bf16 cast (+ zero-fill segments with scols=0).
struct CDesc { const float* src; u16* dst; int srs, drs, dcols, scols; };
struct CPack { CDesc d[9]; unsigned cum[10]; int n; };

__global__ void kern_mcast(CPack p)
{
    unsigned idx = blockIdx.x * 256 + threadIdx.x;
    int si = -1;
    for (int s = 0; s < p.n; ++s)
        if (idx >= p.cum[s] && idx < p.cum[s + 1]) { si = s; break; }
    if (si < 0) return;
    CDesc D = p.d[si];
    unsigned k = idx - p.cum[si];
    int r = k / D.dcols, c = k - r * D.dcols;
    D.dst[(size_t)r * D.drs + c] =
        (c < D.scols) ? f2bf(D.src[(size_t)r * D.srs + c]) : (u16)0;
}

// Fused [ew rowmax+exp] + exp(S0) + G + Z.
__global__ __launch_bounds__(256) void kern_eG(const float* __restrict__ S,
    u16* __restrict__ Gb, float* __restrict__ Z)
{
    __shared__ float red[256];
    __shared__ u16 ews[NN_ * 1024];   // 28.7 KB
    const int l = blockIdx.x, tid = threadIdx.x;
    const int lane = tid & 63, wv = tid >> 6;

    const float* wraw = S + 1024 * 1024;
    for (int z = wv; z < NN_; z += 4) {
        const float* r = wraw + z * 1024;
        float vv[16], mx = -1e30f;
        #pragma unroll
        for (int j = 0; j < 16; ++j) { vv[j] = r[lane + 64 * j]; mx = fmaxf(mx, vv[j]); }
        #pragma unroll
        for (int off = 32; off > 0; off >>= 1) mx = fmaxf(mx, __shfl_down(mx, off));
        mx = __shfl(mx, 0);
        #pragma unroll
        for (int j = 0; j < 16; ++j)
            ews[z * 1024 + lane + 64 * j] = f2bf(expf(vv[j] - mx));
    }
    const float* row = S + (size_t)l * 1024;
    float m = -1e30f;
    #pragma unroll
    for (int k = 0; k < 4; ++k) m = fmaxf(m, row[tid + 256 * k]);
    red[tid] = m; __syncthreads();          // also publishes ews
    for (int s = 128; s > 0; s >>= 1) {
        if (tid < s) red[tid] = fmaxf(red[tid], red[tid + s]);
        __syncthreads();
    }
    m = red[0];
    float ev[16];
    #pragma unroll
    for (int j = 0; j < 16; ++j) ev[j] = expf(row[lane + 64 * j] - m);
    u16* gr = Gb + (size_t)l * NN_ * 1024;
    for (int z = wv; z < NN_; z += 4) {
        const u16* er = &ews[z * 1024];
        float s = 0.f;
        #pragma unroll
        for (int j = 0; j < 16; ++j) {
            float pv = ev[j] * bf2f(er[lane + 64 * j]);
            gr[(size_t)z * 1024 + lane + 64 * j] = f2bf(pv);
            s += pv;
        }
        #pragma unroll
        for (int off = 32; off > 0; off >>= 1) s += __shfl_down(s, off);
        if (lane == 0) Z[l * NN_ + z] = s;
    }
}

// x1 = LN1(node + Pb + co); Pb is bf16 attn-out already scaled by 1/Z.
__global__ __launch_bounds__(256) void kern_ln1(
    const float* __restrict__ img, const float* __restrict__ word,
    const u16* __restrict__ Pb,
    const float* __restrict__ co, const float* __restrict__ g,
    const float* __restrict__ bta, u16* __restrict__ Xb)
{
    __shared__ float buf[DD_];
    __shared__ float red[256];
    __shared__ float stats[2];
    int row = blockIdx.x;
    int b = row / NN_, n = row - b * NN_;
    const u16* pr = Pb + (size_t)row * DD_;
    const float* cr = co + n * DD_;
    float s = 0.f;
    for (int d = threadIdx.x; d < DD_; d += 256) {
        float v = (d < IMG_) ? img[(size_t)b * IMG_ + d] : word[n * TXT_ + d - IMG_];
        v += bf2f(pr[d]) + cr[d];
        buf[d] = v; s += v;
    }
    red[threadIdx.x] = s; __syncthreads();
    for (int t = 128; t > 0; t >>= 1) {
        if (threadIdx.x < t) red[threadIdx.x] += red[threadIdx.x + t];
        __syncthreads();
    }
    if (threadIdx.x == 0) stats[0] = red[0] / DD_;
    __syncthreads();
    float mu = stats[0], s2 = 0.f;
    for (int d = threadIdx.x; d < DD_; d += 256) { float t = buf[d] - mu; s2 += t * t; }
    red[threadIdx.x] = s2; __syncthreads();
    for (int t = 128; t > 0; t >>= 1) {
        if (threadIdx.x < t) red[threadIdx.x] += red[threadIdx.x + t];
        __syncthreads();
    }
    if (threadIdx.x == 0) stats[1] = rsqrtf(red[0] / DD_ + 1e-5f);
    __syncthreads();
    float rstd = stats[1];
    u16* xb = Xb + (size_t)row * KP_;
    for (int d = threadIdx.x; d < DD_; d += 256)
        xb[d] = f2bf((buf[d] - mu) * rstd * g[d] + bta[d]);
    for (int d = DD_ + threadIdx.x; d < KP_; d += 256) xb[d] = 0;
}

// ---------------------------------------------------------------------------
// Fused LN2 + GCN1 + GCN2 + mean-pool + linear. One block per image b.
// ---------------------------------------------------------------------------
#define X2S_ 840
#define G1S_ 136
__global__ __launch_bounds__(256, 4)
void kern_gcn(const u16* __restrict__ Yb,
              const float* __restrict__ g2v, const float* __restrict__ bt2,
              const u16* __restrict__ Wg1T, const float* __restrict__ bg1,
              const u16* __restrict__ Wg2T, const float* __restrict__ bg2,
              const float* __restrict__ Wl,  const float* __restrict__ bl,
              const float* __restrict__ AdjW, float* __restrict__ out)
{
    __shared__ __align__(16) u16 x2s[16 * X2S_];      // 26.9 KB; g1s overlays
    __shared__ __align__(16) float h1s[16 * 132];     // 8.4 KB
    __shared__ float adj_s[NN_ * NN_];
    __shared__ float colw_s[16];
    __shared__ float pool_s[HID_];
    u16* g1s = x2s;                                   // overlay (16*G1S_ u16)
    const int b = blockIdx.x, tid = threadIdx.x;
    const int lane = tid & 63, wv = tid >> 6;
    const int fr = lane & 15, qd = lane >> 4;

    if (tid < NN_ * NN_) adj_s[tid] = AdjW[tid];
    if (tid >= NN_ * NN_ && tid < NN_ * NN_ + 16) colw_s[tid - NN_ * NN_] = AdjW[tid];
    for (int k = tid; k < 2 * X2S_; k += 256) x2s[14 * X2S_ + k] = 0;
    for (int k = tid; k < 14 * (X2S_ - DD_); k += 256) {
        int j = k / (X2S_ - DD_), c = k - j * (X2S_ - DD_);
        x2s[j * X2S_ + DD_ + c] = 0;
    }

    // --- LN2 per node row ---
    for (int j = wv; j < NN_; j += 4) {
        const u16* yr = Yb + (size_t)(b * NN_ + j) * KP_;
        float vv[13], s = 0.f;
        #pragma unroll
        for (int k = 0; k < 13; ++k) {
            int d = lane + 64 * k;
            float v = (d < DD_) ? bf2f(yr[d]) : 0.f;
            vv[k] = v; s += v;
        }
        #pragma unroll
        for (int off = 32; off > 0; off >>= 1) s += __shfl_down(s, off);
        s = __shfl(s, 0);
        float mu = s / (float)DD_, s2 = 0.f;
        #pragma unroll
        for (int k = 0; k < 13; ++k) {
            int d = lane + 64 * k;
            float t = (d < DD_) ? vv[k] - mu : 0.f;
            s2 += t * t;
        }
        #pragma unroll
        for (int off = 32; off > 0; off >>= 1) s2 += __shfl_down(s2, off);
        s2 = __shfl(s2, 0);
        float rstd = rsqrtf(s2 / (float)DD_ + 1e-5f);
        #pragma unroll
        for (int k = 0; k < 13; ++k) {
            int d = lane + 64 * k;
            if (d < DD_)
                x2s[j * X2S_ + d] = f2bf((vv[k] - mu) * rstd * g2v[d] + bt2[d]);
        }
    }
    __syncthreads();

    // --- GCN1 (MFMA, M=16, K=KP_) ---
    {
        f32x4 acc[2] = {{}, {}};
        const u16* wp0 = Wg1T + (size_t)(wv * 32 + fr) * KP_ + qd * 8;
        const u16* wp1 = wp0 + (size_t)16 * KP_;
        bf16x8 bc0 = *(const bf16x8*)wp0;
        bf16x8 bc1 = *(const bf16x8*)wp1;
        for (int k0 = 0; k0 < KP_; k0 += 32) {
            bf16x8 bn0 = bc0, bn1 = bc1;
            if (k0 + 32 < KP_) {
                bn0 = *(const bf16x8*)(wp0 + k0 + 32);
                bn1 = *(const bf16x8*)(wp1 + k0 + 32);
            }
            bf16x8 af = *(const bf16x8*)&x2s[fr * X2S_ + k0 + qd * 8];
            acc[0] = __builtin_amdgcn_mfma_f32_16x16x32_bf16(af, bc0, acc[0], 0, 0, 0);
            acc[1] = __builtin_amdgcn_mfma_f32_16x16x32_bf16(af, bc1, acc[1], 0, 0, 0);
            bc0 = bn0; bc1 = bn1;
        }
        #pragma unroll
        for (int t = 0; t < 2; ++t)
            #pragma unroll
            for (int i = 0; i < 4; ++i)
                h1s[(qd * 4 + i) * 132 + wv * 32 + t * 16 + fr] = acc[t][i];
    }
    __syncthreads();   // x2s dead; g1s overlay now writable

    // --- G1 = relu(Adj @ H1 + bg1) -> bf16; zero pad rows 14,15 ---
    {
        const int f = tid & 127, jj = (tid >> 7) * 7;
        #pragma unroll
        for (int j = 0; j < 7; ++j) {
            float s = bg1[f];
            #pragma unroll
            for (int i = 0; i < NN_; ++i)
                s = fmaf(adj_s[(jj + j) * NN_ + i], h1s[i * 132 + f], s);
            g1s[(jj + j) * G1S_ + f] = f2bf(s > 0.f ? s : 0.f);
        }
        for (int k = tid; k < 2 * G1S_; k += 256) g1s[14 * G1S_ + k] = 0;
    }
    __syncthreads();

    // --- GCN2 (MFMA, K=128) + pool = relu(colw·H2 + bg2) ---
    {
        f32x4 acc[2] = {{}, {}};
        const u16* wp0 = Wg2T + (size_t)(wv * 32 + fr) * HID_ + qd * 8;
        const u16* wp1 = wp0 + (size_t)16 * HID_;
        bf16x8 bc0 = *(const bf16x8*)wp0;
        bf16x8 bc1 = *(const bf16x8*)wp1;
        for (int k0 = 0; k0 < HID_; k0 += 32) {
            bf16x8 bn0 = bc0, bn1 = bc1;
            if (k0 + 32 < HID_) {
                bn0 = *(const bf16x8*)(wp0 + k0 + 32);
                bn1 = *(const bf16x8*)(wp1 + k0 + 32);
            }
            bf16x8 af = *(const bf16x8*)&g1s[fr * G1S_ + k0 + qd * 8];
            acc[0] = __builtin_amdgcn_mfma_f32_16x16x32_bf16(af, bc0, acc[0], 0, 0, 0);
            acc[1] = __builtin_amdgcn_mfma_f32_16x16x32_bf16(af, bc1, acc[1], 0, 0, 0);
            bc0 = bn0; bc1 = bn1;
        }
        #pragma unroll
        for (int t = 0; t < 2; ++t) {
            float s = 0.f;
            #pragma unroll
            for (int i = 0; i < 4; ++i) s += colw_s[qd * 4 + i] * acc[t][i];
            s += __shfl_xor(s, 16);
            s += __shfl_xor(s, 32);
            if (qd == 0) {
                int f = wv * 32 + t * 16 + fr;
                float p = s + bg2[f];
                pool_s[f] = p > 0.f ? p : 0.f;
            }
        }
    }
    __syncthreads();

    // --- out = pool @ Wl + bl ---
    if (tid < CC_) {
        float s = bl[tid];
        #pragma unroll 8
        for (int f = 0; f < HID_; ++f)
            s = fmaf(pool_s[f], Wl[(size_t)f * CC_ + tid], s);
        out[(size_t)b * CC_ + tid] = s;
    }
}

extern "C" void kernel_launch(void* const* d_in, const int* in_sizes, int n_in,
                              void* d_out, int out_size, void* d_ws, size_t ws_size,
                              hipStream_t stream)
{
    const float* img  = (const float*)d_in[0];
    const float* word = (const float*)d_in[1];
    const int*   ei   = (const int*)d_in[2];
    const float* Wi   = (const float*)d_in[3];
    const float* bi   = (const float*)d_in[4];
    const float* Wo   = (const float*)d_in[5];
    const float* bo   = (const float*)d_in[6];
    const float* g1   = (const float*)d_in[7];
    const float* bt1  = (const float*)d_in[8];
    const float* g2   = (const float*)d_in[9];
    const float* bt2  = (const float*)d_in[10];
    const float* W1   = (const float*)d_in[11];
    const float* bf1  = (const float*)d_in[12];
    const float* W2   = (const float*)d_in[13];
    const float* bf2  = (const float*)d_in[14];
    const float* Wg1  = (const float*)d_in[15];
    const float* bg1  = (const float*)d_in[16];
    const float* Wg2  = (const float*)d_in[17];
    const float* bg2  = (const float*)d_in[18];
    const float* Wl   = (const float*)d_in[19];
    const float* bl   = (const float*)d_in[20];
    float* out = (float*)d_out;

    char* ws = (char*)d_ws;
    u16*   imgb = (u16*)  (ws + OFF_IMGB);
    u16*   Wib  = (u16*)  (ws + OFF_WIB);
    u16*   wordb= (u16*)  (ws + OFF_WORDB);
    u16*   WiTX = (u16*)  (ws + OFF_WITX);
    u16*   Gb   = (u16*)  (ws + OFF_GB);
    float* Ebuf = (float*)(ws + OFF_EBUF);
    u16*   AvoT = (u16*)  (ws + OFF_AVOT);
    u16*   Wob  = (u16*)  (ws + OFF_WOB);
    u16*   Hb   = (u16*)  (ws + OFF_HB);
    u16*   Pb   = (u16*)  (ws + OFF_PB);
    u16*   X1b  = (u16*)  (ws + OFF_X1B);
    u16*   Yb   = (u16*)  (ws + OFF_YB);
    u16*   W1T  = (u16*)  (ws + OFF_W1T);
    u16*   W2T  = (u16*)  (ws + OFF_W2T);
    u16*   Aqb  = (u16*)  (ws + OFF_AQB);
    u16*   Akb  = Aqb + AROWS_ * KP_;
    u16*   Avb  = Aqb + 2 * AROWS_ * KP_;
    u16*   Tvb  = (u16*)  (ws + OFF_TVB);
    float* co   = (float*)(ws + OFF_CO);
    float* Zb   = (float*)(ws + OFF_Z);
    float* Adj  = (float*)(ws + OFF_ADJ);
    u16*   Wg1T = (u16*)  (ws + OFF_WG1T);
    u16*   Wg2T = (u16*)  (ws + OFF_WG2T);

    const float scl = 1.0f / sqrtf((float)DD_);

    // --- launch 1: multi-cast (input casts + all K-pad zeroing) ---
    {
        CPack p; p.n = 9;
        unsigned c = 0;
        auto seg = [&](int i, const float* s, int srs, u16* d, int drs,
                       int rows, int dcols, int scols) {
            p.d[i] = { s, d, srs, drs, dcols, scols };
            p.cum[i] = c; c += (unsigned)rows * dcols;
        };
        seg(0, img,        IMG_, imgb,  IMG_, B_,   IMG_, IMG_);
        seg(1, Wi,         DD_,  Wib,   IMG_, D3_,  IMG_, IMG_);
        seg(2, word,       TXT_, wordb, TXP_, NN_,  TXP_, TXT_);
        seg(3, Wi + IMG_,  DD_,  WiTX,  TXP_, D3_,  TXP_, TXT_);
        seg(4, Wo,         DD_,  Wob,   KP_,  DD_,  KP_,  DD_);
        seg(5, nullptr, 0, Aqb + DD_,                    KP_, 1038, 20, 0); // Aq + Tq rows
        seg(6, nullptr, 0, Aqb + AROWS_ * KP_ + DD_,     KP_, 1024, 20, 0);
        seg(7, nullptr, 0, Aqb + 2 * AROWS_ * KP_ + DD_, KP_, 1024, 20, 0);
        seg(8, nullptr, 0, Tvb + DD_,                    KP_, NN_,  20, 0); // Tvb pads
        p.cum[9] = c;
        kern_mcast<<<(c + 255) / 256, 256, 0, stream>>>(p);
    }

    // --- launch 2 (mix1): T epi8 + A-proj || Wg1T/Wg2T transposes || adj ---
    {
        MPack p{};
        p.ng = 2; p.gtot = 180;
        p.g[0] = { wordb, WiTX, (float*)Tvb, Aqb, bi,
                   TXP_, TXP_, 0, 0, NN_, D3_, TXP_, 8, 20, 0, 0, 1.f };
        p.g[1] = { imgb, Wib, nullptr, Aqb, nullptr,
                   IMG_, IMG_, 0, 0, B_, D3_, IMG_, 4, 20, 1, 20, 1.f };
        p.nt = 2;
        p.t[0] = { Wg1, Wg1T, HID_, KP_,  DD_,  HID_, KP_,  26, 26 * 4 };
        p.t[1] = { Wg2, Wg2T, HID_, HID_, HID_, HID_, HID_, 4,  4 * 4 };
        p.ei = ei; p.Adj = Adj;
        kern_mix<<<180 + 104 + 16 + 1, 512, 0, stream>>>(p);
    }

    // --- launch 3 (mix2): S0+w || AvoT || co  ||  W1T/W2T transposes ---
    {
        MPack p{};
        p.ng = 3; p.gtot = 135;
        p.g[0] = { Aqb, Akb, Ebuf, nullptr, nullptr,
                   KP_, KP_, 1024, 0, 1024 + NN_, 1024, KP_, 0, 8, 0, 0, scl };
        p.g[1] = { Wob, Avb, nullptr, AvoT, nullptr,
                   KP_, KP_, 0, 1024, DD_, B_, KP_, 3, 8, 0, 72, 1.f };
        p.g[2] = { Tvb, Wob, co, nullptr, bo,
                   KP_, KP_, DD_, 0, NN_, DD_, KP_, 6, 7, 0, 128, 1.f };
        p.nt = 2;
        p.t[0] = { W1, W1T, FF_, KP_, DD_, FF_, KP_, 26, 26 * 64 };
        p.t[1] = { W2, W2T, DD_, FF_, FF_, DD_, FF_, 64, 64 * 26 };
        p.ei = nullptr; p.Adj = nullptr;
        kern_mix<<<135 + 1664 + 1664, 512, 0, stream>>>(p);
    }

    // --- launch 4: fused ew-exp + exp + G + Z ---
    kern_eG<<<1024, 256, 0, stream>>>(Ebuf, Gb, Zb);

    // --- launch 5: Pb = (G @ Avo)/Z as bf16 (4-wave body) ---
    bgemm<5><<<7 * 112, 256, 0, stream>>>(Gb, 1024, AvoT, 1024,
        BNR_, DD_, 1024, 1.f, nullptr, 0, Pb, DD_, Zb, 7, 1);

    // --- launch 6: LN1 ---
    kern_ln1<<<BNR_, 256, 0, stream>>>(img, word, Pb, co, g1, bt1, X1b);

    // --- launches 7,8: FFN (4-wave body — round-11 proven 96 µs) ---
    bgemm<1><<<16 * 112, 256, 0, stream>>>(X1b, KP_, W1T, KP_,
        BNR_, FF_, KP_, 1.f, nullptr, 0, Hb, FF_, bf1, 16, 1);
    bgemm<7><<<7 * 112, 256, 0, stream>>>(Hb, FF_, W2T, FF_,
        BNR_, DD_, FF_, 1.f, (float*)X1b, KP_, Yb, KP_, bf2, 7, 1);

    // --- launch 9: fused LN2 + GCN1 + GCN2 + pool + linear ---
    kern_gcn<<<B_, 256, 0, stream>>>(Yb, g2, bt2, Wg1T, bg1, Wg2T, bg2,
                                     Wl, bl, Adj, out);
}